// Round 3
// baseline (1249.696 us; speedup 1.0000x reference)
//
#include <hip/hip_runtime.h>

// ---------------------------------------------------------------------------
// Nystrom attention: split-bf16 (hi/lo, 3xMFMA) everywhere.
// R8: fused persistent pinv — zinit + 6x4 Newton-Schulz stages + t2 in ONE
// ordinary kernel launch (256 blocks, 1-2/CU). Sync = per-group (8-block)
// software barriers: device-scope atomics + __threadfence (no cooperative
// API — R7 showed hipLaunchCooperativeKernel dies under this harness).
// Groups are XCD-affine (bid&7 = xcd); each group owns one batch-head z and
// only touches its own z-slices, so groups need no cross-sync. t2T planes
// now live in the group's own dead Y1T z-slice (stride 65536) to avoid the
// cross-group ZT0 aliasing race.
// B=4, N=4096, DIM=512, H=8, DH=64, M=256, l=16, 6 pinv iters, conv K=33.
// ---------------------------------------------------------------------------

typedef __attribute__((ext_vector_type(8))) short bf16x8;
typedef __attribute__((ext_vector_type(4))) float f32x4;

// workspace layout (float units)
constexpr size_t O_XP  = 0;          // Xh/Xl planes; later zA,zB,Y2T; later oh fp32
constexpr size_t O_QP  = 8388608;    // q planes (hi/lo)
constexpr size_t O_KP  = 16777216;   // k planes; later pinv T-planes; later OH planes
constexpr size_t O_VT  = 25165824;   // vT planes
constexpr size_t O_QL  = 33554432;   // qland fp32
constexpr size_t O_KL  = 34078720;   // kland fp32
constexpr size_t O_QLP = 34603008;   // qland planes
constexpr size_t O_KLP = 35127296;   // kland planes
constexpr size_t O_A2  = 35651584;   // attn2 fp32
constexpr size_t O_T1  = 37748736;
constexpr size_t O_RS3 = 38273024;
constexpr size_t O_SCAL= 38281216;
constexpr size_t O_T2  = 38281232;   // (unused fp32 t2, kept for layout)
constexpr size_t O_WQT = 38805520;
constexpr size_t O_WOT = 39591952;
constexpr size_t O_BAR = 39854096;   // 2048 uints of barrier state
constexpr size_t O_END = 39856144;   // ~159.4 MB

// ---------------------------------------------------------------------------
__device__ __forceinline__ void split2(float x, unsigned short& h,
                                       unsigned short& l) {
    unsigned u  = __float_as_uint(x);
    unsigned hb = (u + 0x7FFFu + ((u >> 16) & 1u)) & 0xFFFF0000u;  // RNE hi
    h = (unsigned short)(hb >> 16);
    float d = x - __uint_as_float(hb);
    l = (unsigned short)(__float_as_uint(d) >> 16);
}

__device__ __forceinline__ float b2f(unsigned short s) {
    return __uint_as_float((unsigned)s << 16);
}

__device__ __forceinline__ f32x4 mfma3(bf16x8 ah, bf16x8 al, bf16x8 bh,
                                       bf16x8 bl, f32x4 c) {
    c = __builtin_amdgcn_mfma_f32_16x16x32_bf16(ah, bh, c, 0, 0, 0);
    c = __builtin_amdgcn_mfma_f32_16x16x32_bf16(ah, bl, c, 0, 0, 0);
    c = __builtin_amdgcn_mfma_f32_16x16x32_bf16(al, bh, c, 0, 0, 0);
    return c;
}

// split a float4 into hi/lo planes, write packed uint2 at H[off], L[off]
__device__ __forceinline__ void stage_split4(float4 av, unsigned short* H,
                                             unsigned short* L, int off) {
    unsigned short h0, h1, h2, h3, l0, l1, l2, l3;
    split2(av.x, h0, l0); split2(av.y, h1, l1);
    split2(av.z, h2, l2); split2(av.w, h3, l3);
    uint2 ph, pl;
    ph.x = (unsigned)h0 | ((unsigned)h1 << 16);
    ph.y = (unsigned)h2 | ((unsigned)h3 << 16);
    pl.x = (unsigned)l0 | ((unsigned)l1 << 16);
    pl.y = (unsigned)l2 | ((unsigned)l3 << 16);
    *(uint2*)&H[off] = ph;
    *(uint2*)&L[off] = pl;
}

// ---------------------------------------------------------------------------
// per-group (8-block) software barrier: count + generation, device-scope
// atomics; __threadfence release/acquire for cross-block data visibility.
// ---------------------------------------------------------------------------
__device__ __forceinline__ void gbar(unsigned* cnt, unsigned* gen) {
    __syncthreads();
    if (threadIdx.x == 0) {
        __threadfence();                      // release prior writes
        unsigned g0 = atomicAdd(gen, 0u);
        if (atomicAdd(cnt, 1u) == 7u) {
            atomicExch(cnt, 0u);
            __threadfence();
            atomicAdd(gen, 1u);               // open next generation
        } else {
            while (atomicAdd(gen, 0u) == g0) __builtin_amdgcn_s_sleep(16);
        }
        __threadfence();                      // acquire
    }
    __syncthreads();
}

// ---------------------------------------------------------------------------
// X -> split planes (one-time)
// ---------------------------------------------------------------------------
__global__ void xsplit(const float* __restrict__ X,
                       unsigned short* __restrict__ Xh,
                       unsigned short* __restrict__ Xl) {
    int idx = blockIdx.x * 256 + threadIdx.x;
    float4 v = *(const float4*)(X + (size_t)idx * 4);
    stage_split4(v, Xh, Xl, idx * 4);
}

// ---------------------------------------------------------------------------
// pinv GEMM stage (device fn), 64x128 tile: C = alpha*(A@B) + beta*A_elem.
// A fp32 (split in-register); B = transposed bf16 planes BT[n][k].
// All pointers pre-offset to this z. 256 threads.
// ---------------------------------------------------------------------------
template <int EPI, bool WF32, bool WT>
__device__ __forceinline__ void pinv_stage(
    const float* __restrict__ Ab, int lda,
    const unsigned short* __restrict__ BhB,
    const unsigned short* __restrict__ BlB, int ldbt,
    float* __restrict__ Cb, int ldc,
    unsigned short* __restrict__ CThB, unsigned short* __restrict__ CTlB,
    int ldct, int K, float alpha, float beta, int m0, int n0,
    unsigned short* Ah, unsigned short* Al,
    unsigned short* Bh, unsigned short* Bl) {
    const int t = threadIdx.x;
    const int wave = t >> 6, lane = t & 63, lm = lane & 15, lq = lane >> 4;

    f32x4 acc[8];
#pragma unroll
    for (int j = 0; j < 8; ++j) acc[j] = (f32x4){0.f, 0.f, 0.f, 0.f};

    for (int kt = 0; kt < K; kt += 32) {
#pragma unroll
        for (int r = 0; r < 2; ++r) {
            int id = t + r * 256, row = id >> 3, k4 = (id & 7) * 4;
            float4 av = *(const float4*)(Ab + (size_t)(m0 + row) * lda + kt + k4);
            stage_split4(av, Ah, Al, row * 40 + k4);
        }
#pragma unroll
        for (int r = 0; r < 2; ++r) {
            int id = t + r * 256, row = id >> 2, ko = (id & 3) * 8;
            *(uint4*)&Bh[row * 40 + ko] =
                *(const uint4*)(BhB + (size_t)(n0 + row) * ldbt + kt + ko);
            *(uint4*)&Bl[row * 40 + ko] =
                *(const uint4*)(BlB + (size_t)(n0 + row) * ldbt + kt + ko);
        }
        __syncthreads();
        bf16x8 ah = *(const bf16x8*)&Ah[(wave * 16 + lm) * 40 + lq * 8];
        bf16x8 al = *(const bf16x8*)&Al[(wave * 16 + lm) * 40 + lq * 8];
#pragma unroll
        for (int j = 0; j < 8; ++j) {
            bf16x8 bh = *(const bf16x8*)&Bh[(j * 16 + lm) * 40 + lq * 8];
            bf16x8 bl = *(const bf16x8*)&Bl[(j * 16 + lm) * 40 + lq * 8];
            acc[j] = mfma3(ah, al, bh, bl, acc[j]);
        }
        __syncthreads();
    }

    const int r0 = m0 + wave * 16 + lq * 4;
#pragma unroll
    for (int j = 0; j < 8; ++j) {
        int c = n0 + j * 16 + lm;
        float vals[4] = {acc[j][0], acc[j][1], acc[j][2], acc[j][3]};
        if (EPI == 1) {
#pragma unroll
            for (int e = 0; e < 4; ++e)
                vals[e] = alpha * vals[e] + beta * Ab[(size_t)(r0 + e) * lda + c];
        }
        if (WF32) {
#pragma unroll
            for (int e = 0; e < 4; ++e)
                Cb[(size_t)(r0 + e) * ldc + c] = vals[e];
        }
        if (WT) {
            unsigned short hh[4], ll[4];
#pragma unroll
            for (int e = 0; e < 4; ++e) split2(vals[e], hh[e], ll[e]);
            uint2 ph, pl;
            ph.x = (unsigned)hh[0] | ((unsigned)hh[1] << 16);
            ph.y = (unsigned)hh[2] | ((unsigned)hh[3] << 16);
            pl.x = (unsigned)ll[0] | ((unsigned)ll[1] << 16);
            pl.y = (unsigned)ll[2] | ((unsigned)ll[3] << 16);
            *(uint2*)&CThB[(size_t)c * ldct + r0] = ph;
            *(uint2*)&CTlB[(size_t)c * ldct + r0] = pl;
        }
    }
}

// fp32 64x64 micro-kernel (used by attn2 gemm and fused t2 stage)
__device__ __forceinline__ void mt16(const float* As, const float* Bs,
                                     int ty4, int tx4, float (&acc)[4][4]) {
#pragma unroll
    for (int kk = 0; kk < 16; ++kk) {
        float4 a4 = *(const float4*)(As + kk * 68 + ty4);
        float4 b4 = *(const float4*)(Bs + kk * 68 + tx4);
        float aa[4] = {a4.x, a4.y, a4.z, a4.w};
        float bb[4] = {b4.x, b4.y, b4.z, b4.w};
#pragma unroll
        for (int u = 0; u < 4; ++u)
#pragma unroll
            for (int w = 0; w < 4; ++w)
                acc[u][w] += aa[u] * bb[w];
    }
}

// ---------------------------------------------------------------------------
// Persistent fused pinv: zinit -> 6x{xz,Y1,Y2,z'} -> t2.  256 blocks, 256
// threads.  Group = 8 blocks sharing one z (XCD-affine); per-group barriers.
// t2^T planes written into the group's own (dead) Y1T z-slice.
// ---------------------------------------------------------------------------
__global__ __launch_bounds__(256) void pinv_coop(
    const float* __restrict__ attn2, const float* __restrict__ scal,
    float* __restrict__ zA, float* __restrict__ zB,
    unsigned short* __restrict__ ZT0h, unsigned short* __restrict__ ZT0l,
    unsigned short* __restrict__ ZT1h, unsigned short* __restrict__ ZT1l,
    unsigned short* __restrict__ XZTh, unsigned short* __restrict__ XZTl,
    unsigned short* __restrict__ Y1Th, unsigned short* __restrict__ Y1Tl,
    unsigned short* __restrict__ Y2Th, unsigned short* __restrict__ Y2Tl,
    const float* __restrict__ t1, const float* __restrict__ rs3,
    unsigned* __restrict__ bars) {
    __shared__ __align__(16) unsigned short SH[15360];   // 30720 B
    unsigned short* Ah = SH;
    unsigned short* Al = SH + 2560;
    unsigned short* Bh = SH + 5120;
    unsigned short* Bl = SH + 10240;
    const int t = threadIdx.x;
    const int bid = blockIdx.x;
    // XCD-affine group mapping: consecutive bids round-robin XCDs.
    const int xcd = bid & 7, slot = bid >> 3;
    const int z = xcd * 4 + (slot >> 3);       // group id == batch-head
    const int inner = slot & 7;
    const int m0 = (inner >> 1) * 64;
    const int n0 = (inner & 1) * 128;
    const size_t zo = (size_t)z * 65536;
    unsigned* cnt = bars + z * 64;
    unsigned* gen = bars + z * 64 + 1;

    // ---- stage 0: zinit (z0 = attn2^T / denom; emit ZT0 planes) ----
    {
        float denom = scal[0] * scal[1] + 1e-8f;
        int base = inner * 8192;
#pragma unroll
        for (int i = 0; i < 32; ++i) {
            int li = base + i * 256 + t;           // [0,65536) within z
            int r = li >> 8, c = li & 255;
            float v = attn2[zo + li] / denom;
            zA[zo + ((size_t)c << 8) + r] = v;
            unsigned short h, l;
            split2(v, h, l);
            ZT0h[zo + li] = h;
            ZT0l[zo + li] = l;
        }
    }
    gbar(cnt, gen);

    // ---- 6 Newton-Schulz iterations, 4 GEMM stages each ----
    for (int it = 0; it < 6; ++it) {
        float* zc  = (it & 1) ? zB : zA;
        float* xzf = (it & 1) ? zA : zB;
        unsigned short* zch = (it & 1) ? ZT1h : ZT0h;
        unsigned short* zcl = (it & 1) ? ZT1l : ZT0l;
        unsigned short* znh = (it & 1) ? ZT0h : ZT1h;
        unsigned short* znl = (it & 1) ? ZT0l : ZT1l;

        // xz = attn2 @ z
        pinv_stage<0, true, true>(attn2 + zo, 256, zch + zo, zcl + zo, 256,
                                  xzf + zo, 256, XZTh + zo, XZTl + zo, 256,
                                  256, 0.f, 0.f, m0, n0, Ah, Al, Bh, Bl);
        gbar(cnt, gen);
        // Y1 = -xz@xz + 7*xz
        pinv_stage<1, false, true>(xzf + zo, 256, XZTh + zo, XZTl + zo, 256,
                                   (float*)nullptr, 256, Y1Th + zo, Y1Tl + zo,
                                   256, 256, -1.f, 7.f, m0, n0, Ah, Al, Bh, Bl);
        gbar(cnt, gen);
        // Y2 = -xz@Y1 + 15*xz
        pinv_stage<1, false, true>(xzf + zo, 256, Y1Th + zo, Y1Tl + zo, 256,
                                   (float*)nullptr, 256, Y2Th + zo, Y2Tl + zo,
                                   256, 256, -1.f, 15.f, m0, n0, Ah, Al, Bh, Bl);
        gbar(cnt, gen);
        // z' = -0.25*z@Y2 + 3.25*z
        pinv_stage<1, true, true>(zc + zo, 256, Y2Th + zo, Y2Tl + zo, 256,
                                  xzf + zo, 256, znh + zo, znl + zo, 256,
                                  256, -0.25f, 3.25f, m0, n0, Ah, Al, Bh, Bl);
        gbar(cnt, gen);
    }

    // ---- final stage: t2 = zfin @ (t1 / rs3); planes into own Y1T slice ----
    // zfin = zA (6 iterations -> even).  4 active blocks per group (n0==0).
    if (n0 == 0) {
        float* As = (float*)SH;               // 16*68 floats = 4352 B
        float* Bs = (float*)(SH + 2176);      // next 4352 B
        const float* Ab = zA + zo;
        const float* Bb = t1 + (size_t)z * 16384;
        const int tx4 = (t & 15) * 4;
        const int ty4 = (t >> 4) * 4;
        const int ar  = t >> 2, ak = (t & 3) * 4;
        const int bkr = t >> 4, bc4 = (t & 15) * 4;
        float acc[4][4] = {};
        for (int kt = 0; kt < 256; kt += 16) {
            float4 av = *(const float4*)(Ab + (size_t)(m0 + ar) * 256 + kt + ak);
            float4 bv = *(const float4*)(Bb + (size_t)(kt + bkr) * 64 + bc4);
            float rr = 1.0f / rs3[z * 256 + kt + bkr];
            bv.x *= rr; bv.y *= rr; bv.z *= rr; bv.w *= rr;
            As[(ak + 0) * 68 + ar] = av.x;
            As[(ak + 1) * 68 + ar] = av.y;
            As[(ak + 2) * 68 + ar] = av.z;
            As[(ak + 3) * 68 + ar] = av.w;
            *(float4*)(Bs + bkr * 68 + bc4) = bv;
            __syncthreads();
            mt16(As, Bs, ty4, tx4, acc);
            __syncthreads();
        }
        unsigned short* th = Y1Th + zo;       // t2^T planes, per-z stride 65536
        unsigned short* tl = Y1Tl + zo;
#pragma unroll
        for (int w = 0; w < 4; ++w) {
            unsigned short hh[4], ll[4];
#pragma unroll
            for (int u = 0; u < 4; ++u) split2(acc[u][w], hh[u], ll[u]);
            uint2 ph, pl;
            ph.x = (unsigned)hh[0] | ((unsigned)hh[1] << 16);
            ph.y = (unsigned)hh[2] | ((unsigned)hh[3] << 16);
            pl.x = (unsigned)ll[0] | ((unsigned)ll[1] << 16);
            pl.y = (unsigned)ll[2] | ((unsigned)ll[3] << 16);
            size_t off = (size_t)(tx4 + w) * 256 + m0 + ty4;
            *(uint2*)&th[off] = ph;
            *(uint2*)&tl[off] = pl;
        }
    }
}

// ---------------------------------------------------------------------------
// qkv MFMA GEMM: X planes [16384,512] @ w_qkv planes; emits q/k planes
// ([bh][n][d], q scaled 0.125) and vT planes [bh][dh][4096]. grid (12,128).
// ---------------------------------------------------------------------------
__global__ __launch_bounds__(256) void mfma_qkv(
    const unsigned short* __restrict__ Xh_, const unsigned short* __restrict__ Xl_,
    const unsigned short* __restrict__ WTh, const unsigned short* __restrict__ WTl,
    unsigned short* __restrict__ qh, unsigned short* __restrict__ ql,
    unsigned short* __restrict__ kh, unsigned short* __restrict__ kl,
    unsigned short* __restrict__ vTh, unsigned short* __restrict__ vTl) {
    __shared__ unsigned short Ah[128 * 40], Al[128 * 40];
    __shared__ unsigned short Bh[128 * 40], Bl[128 * 40];
    const int t = threadIdx.x;
    const int wave = t >> 6, lane = t & 63, lm = lane & 15, lq = lane >> 4;
    // XCD-aware bijective swizzle: nwg=1536, 1536/8=192 per XCD
    int orig = blockIdx.y * 12 + blockIdx.x;
    int wg = (orig & 7) * 192 + (orig >> 3);
    const int m0 = (wg / 12) * 128, n0 = (wg % 12) * 128;
    const int mb = (wave >> 1) * 64, nb = (wave & 1) * 64;
    f32x4 acc[4][4];
#pragma unroll
    for (int i = 0; i < 4; ++i)
#pragma unroll
        for (int j = 0; j < 4; ++j) acc[i][j] = (f32x4){0.f, 0.f, 0.f, 0.f};

    for (int kt = 0; kt < 512; kt += 32) {
#pragma unroll
        for (int r = 0; r < 2; ++r) {
            int id = t + r * 256, row = id >> 2, ko = (id & 3) * 8;
            *(uint4*)&Ah[row * 40 + ko] =
                *(const uint4*)(Xh_ + (size_t)(m0 + row) * 512 + kt + ko);
            *(uint4*)&Al[row * 40 + ko] =
                *(const uint4*)(Xl_ + (size_t)(m0 + row) * 512 + kt + ko);
        }
#pragma unroll
        for (int r = 0; r < 2; ++r) {
            int id = t + r * 256, row = id >> 2, ko = (id & 3) * 8;
            *(uint4*)&Bh[row * 40 + ko] =
                *(const uint4*)(WTh + (size_t)(n0 + row) * 512 + kt + ko);
            *(uint4*)&Bl[row * 40 + ko] =
                *(const uint4*)(WTl + (size_t)(n0 + row) * 512 + kt + ko);
        }
        __syncthreads();
        bf16x8 ah[4], al[4], bh[4], bl[4];
#pragma unroll
        for (int i = 0; i < 4; ++i) {
            ah[i] = *(const bf16x8*)&Ah[(mb + i * 16 + lm) * 40 + lq * 8];
            al[i] = *(const bf16x8*)&Al[(mb + i * 16 + lm) * 40 + lq * 8];
        }
#pragma unroll
        for (int j = 0; j < 4; ++j) {
            bh[j] = *(const bf16x8*)&Bh[(nb + j * 16 + lm) * 40 + lq * 8];
            bl[j] = *(const bf16x8*)&Bl[(nb + j * 16 + lm) * 40 + lq * 8];
        }
#pragma unroll
        for (int i = 0; i < 4; ++i)
#pragma unroll
            for (int j = 0; j < 4; ++j)
                acc[i][j] = mfma3(ah[i], al[i], bh[j], bl[j], acc[i][j]);
        __syncthreads();
    }
#pragma unroll
    for (int i = 0; i < 4; ++i)
#pragma unroll
        for (int j = 0; j < 4; ++j) {
            int r0 = m0 + mb + i * 16 + lq * 4;
            int c  = n0 + nb + j * 16 + lm;
            int which = c >> 9, h = (c >> 6) & 7, d = c & 63;
            int b = r0 >> 12, nbase = r0 & 4095;
            if (which == 2) {
                unsigned short hh[4], ll[4];
#pragma unroll
                for (int e = 0; e < 4; ++e) split2(acc[i][j][e], hh[e], ll[e]);
                uint2 ph, pl;
                ph.x = (unsigned)hh[0] | ((unsigned)hh[1] << 16);
                ph.y = (unsigned)hh[2] | ((unsigned)hh[3] << 16);
                pl.x = (unsigned)ll[0] | ((unsigned)ll[1] << 16);
                pl.y = (unsigned)ll[2] | ((unsigned)ll[3] << 16);
                size_t off = ((size_t)(b * 8 + h) * 64 + d) * 4096 + nbase;
                *(uint2*)&vTh[off] = ph;
                *(uint2*)&vTl[off] = pl;
            } else {
                unsigned short* Ph = which ? kh : qh;
                unsigned short* Pl = which ? kl : ql;
                float sc = which ? 1.0f : 0.125f;
#pragma unroll
                for (int e = 0; e < 4; ++e) {
                    unsigned short hh, ll;
                    split2(acc[i][j][e] * sc, hh, ll);
                    size_t off = (size_t)(b * 8 + h) * 262144 +
                                 (size_t)(nbase + e) * 64 + d;
                    Ph[off] = hh;
                    Pl[off] = ll;
                }
            }
        }
}

// ---------------------------------------------------------------------------
// final MFMA GEMM: out[16384,512] = OH planes (gathered) @ w_out planes.
// grid (4,128).
// ---------------------------------------------------------------------------
__global__ __launch_bounds__(256) void mfma_final(
    const unsigned short* __restrict__ OHh, const unsigned short* __restrict__ OHl,
    const unsigned short* __restrict__ WTh, const unsigned short* __restrict__ WTl,
    float* __restrict__ out) {
    __shared__ unsigned short Ah[128 * 40], Al[128 * 40];
    __shared__ unsigned short Bh[128 * 40], Bl[128 * 40];
    const int t = threadIdx.x;
    const int wave = t >> 6, lane = t & 63, lm = lane & 15, lq = lane >> 4;
    // XCD-aware bijective swizzle: nwg=512, 512/8=64 per XCD
    int orig = blockIdx.y * 4 + blockIdx.x;
    int wg = (orig & 7) * 64 + (orig >> 3);
    const int m0 = (wg >> 2) * 128, n0 = (wg & 3) * 128;
    const int mb = (wave >> 1) * 64, nb = (wave & 1) * 64;
    f32x4 acc[4][4];
#pragma unroll
    for (int i = 0; i < 4; ++i)
#pragma unroll
        for (int j = 0; j < 4; ++j) acc[i][j] = (f32x4){0.f, 0.f, 0.f, 0.f};

    for (int kt = 0; kt < 512; kt += 32) {
#pragma unroll
        for (int r = 0; r < 2; ++r) {
            int id = t + r * 256, row = id >> 2, ko = (id & 3) * 8;
            int gr = m0 + row, b = gr >> 12, n = gr & 4095;
            int kk = kt + ko;
            size_t off = (size_t)(b * 8 + (kk >> 6)) * 262144 +
                         (size_t)n * 64 + (kk & 63);
            *(uint4*)&Ah[row * 40 + ko] = *(const uint4*)(OHh + off);
            *(uint4*)&Al[row * 40 + ko] = *(const uint4*)(OHl + off);
        }
#pragma unroll
        for (int r = 0; r < 2; ++r) {
            int id = t + r * 256, row = id >> 2, ko = (id & 3) * 8;
            *(uint4*)&Bh[row * 40 + ko] =
                *(const uint4*)(WTh + (size_t)(n0 + row) * 512 + kt + ko);
            *(uint4*)&Bl[row * 40 + ko] =
                *(const uint4*)(WTl + (size_t)(n0 + row) * 512 + kt + ko);
        }
        __syncthreads();
        bf16x8 ah[4], al[4], bh[4], bl[4];
#pragma unroll
        for (int i = 0; i < 4; ++i) {
            ah[i] = *(const bf16x8*)&Ah[(mb + i * 16 + lm) * 40 + lq * 8];
            al[i] = *(const bf16x8*)&Al[(mb + i * 16 + lm) * 40 + lq * 8];
        }
#pragma unroll
        for (int j = 0; j < 4; ++j) {
            bh[j] = *(const bf16x8*)&Bh[(nb + j * 16 + lm) * 40 + lq * 8];
            bl[j] = *(const bf16x8*)&Bl[(nb + j * 16 + lm) * 40 + lq * 8];
        }
#pragma unroll
        for (int i = 0; i < 4; ++i)
#pragma unroll
            for (int j = 0; j < 4; ++j)
                acc[i][j] = mfma3(ah[i], al[i], bh[j], bl[j], acc[i][j]);
        __syncthreads();
    }
#pragma unroll
    for (int i = 0; i < 4; ++i)
#pragma unroll
        for (int j = 0; j < 4; ++j) {
            int r0 = m0 + mb + i * 16 + lq * 4;
            int c  = n0 + nb + j * 16 + lm;
#pragma unroll
            for (int e = 0; e < 4; ++e)
                out[(size_t)(r0 + e) * 512 + c] = acc[i][j][e];
        }
}

// ---------------------------------------------------------------------------
// F3 MFMA: t1 += exp(qland@k^T)@v, rs3 += rowsums. All operands pre-split
// planes (copy staging). grid (8, 4, 32).
// ---------------------------------------------------------------------------
__global__ __launch_bounds__(256) void attn3v_mfma(
    const unsigned short* __restrict__ qlh, const unsigned short* __restrict__ qll,
    const unsigned short* __restrict__ kh_, const unsigned short* __restrict__ kl_,
    const unsigned short* __restrict__ vTh, const unsigned short* __restrict__ vTl,
    float* __restrict__ t1, float* __restrict__ rs3) {
    __shared__ unsigned short Qh[4608], Ql[4608];
    __shared__ unsigned short Kh[4608], Kl[4608];
    __shared__ unsigned short Eh[4608], El[4608];
    const int t = threadIdx.x;
    const int wave = t >> 6, lane = t & 63, lm = lane & 15, lq = lane >> 4;
    const int bz = blockIdx.z, m0 = blockIdx.y * 64, c0 = blockIdx.x * 8;
    const unsigned short* qhb = qlh + (size_t)bz * 16384;
    const unsigned short* qlb = qll + (size_t)bz * 16384;
    const unsigned short* khb = kh_ + (size_t)bz * 262144;
    const unsigned short* klb = kl_ + (size_t)bz * 262144;
    const unsigned short* vhb = vTh + (size_t)bz * 262144;
    const unsigned short* vlb = vTl + (size_t)bz * 262144;
#pragma unroll
    for (int r = 0; r < 2; ++r) {
        int id = t + r * 256, row = id >> 3, ko = (id & 7) * 8;
        *(uint4*)&Qh[row * 72 + ko] =
            *(const uint4*)(qhb + (size_t)(m0 + row) * 64 + ko);
        *(uint4*)&Ql[row * 72 + ko] =
            *(const uint4*)(qlb + (size_t)(m0 + row) * 64 + ko);
    }
    f32x4 acc[4];
#pragma unroll
    for (int j = 0; j < 4; ++j) acc[j] = (f32x4){0.f, 0.f, 0.f, 0.f};
    float rsum[4] = {0.f, 0.f, 0.f, 0.f};
    __syncthreads();

    for (int c = c0; c < c0 + 8; ++c) {
        const int tok0 = c * 64;
#pragma unroll
        for (int r = 0; r < 2; ++r) {
            int id = t + r * 256, row = id >> 3, ko = (id & 7) * 8;
            *(uint4*)&Kh[row * 72 + ko] =
                *(const uint4*)(khb + (size_t)(tok0 + row) * 64 + ko);
            *(uint4*)&Kl[row * 72 + ko] =
                *(const uint4*)(klb + (size_t)(tok0 + row) * 64 + ko);
        }
        __syncthreads();
        bf16x8 a0  = *(const bf16x8*)&Qh[(wave * 16 + lm) * 72 + lq * 8];
        bf16x8 a0l = *(const bf16x8*)&Ql[(wave * 16 + lm) * 72 + lq * 8];
        bf16x8 a1  = *(const bf16x8*)&Qh[(wave * 16 + lm) * 72 + 32 + lq * 8];
        bf16x8 a1l = *(const bf16x8*)&Ql[(wave * 16 + lm) * 72 + 32 + lq * 8];
        f32x4 s[4];
#pragma unroll
        for (int j = 0; j < 4; ++j) s[j] = (f32x4){0.f, 0.f, 0.f, 0.f};
#pragma unroll
        for (int j = 0; j < 4; ++j) {
            bf16x8 b0  = *(const bf16x8*)&Kh[(j * 16 + lm) * 72 + lq * 8];
            bf16x8 b0l = *(const bf16x8*)&Kl[(j * 16 + lm) * 72 + lq * 8];
            bf16x8 b1  = *(const bf16x8*)&Kh[(j * 16 + lm) * 72 + 32 + lq * 8];
            bf16x8 b1l = *(const bf16x8*)&Kl[(j * 16 + lm) * 72 + 32 + lq * 8];
            s[j] = mfma3(a0, a0l, b0, b0l, s[j]);
            s[j] = mfma3(a1, a1l, b1, b1l, s[j]);
        }
        __syncthreads();
#pragma unroll
        for (int j = 0; j < 4; ++j)
#pragma unroll
            for (int e = 0; e < 4; ++e) {
                float ev = __expf(s[j][e]);
                rsum[e] += ev;
                unsigned short h, l;
                split2(ev, h, l);
                int off = (wave * 16 + lq * 4 + e) * 72 + j * 16 + lm;
                Eh[off] = h;
                El[off] = l;
            }
#pragma unroll
        for (int r = 0; r < 2; ++r) {
            int id = t + r * 256, dh = id >> 3, t8 = (id & 7) * 8;
            *(uint4*)&Kh[dh * 72 + t8] =
                *(const uint4*)(vhb + (size_t)dh * 4096 + tok0 + t8);
            *(uint4*)&Kl[dh * 72 + t8] =
                *(const uint4*)(vlb + (size_t)dh * 4096 + tok0 + t8);
        }
        __syncthreads();
        bf16x8 e0  = *(const bf16x8*)&Eh[(wave * 16 + lm) * 72 + lq * 8];
        bf16x8 e0l = *(const bf16x8*)&El[(wave * 16 + lm) * 72 + lq * 8];
        bf16x8 e1  = *(const bf16x8*)&Eh[(wave * 16 + lm) * 72 + 32 + lq * 8];
        bf16x8 e1l = *(const bf16x8*)&El[(wave * 16 + lm) * 72 + 32 + lq * 8];
#pragma unroll
        for (int j = 0; j < 4; ++j) {
            bf16x8 v0  = *(const bf16x8*)&Kh[(j * 16 + lm) * 72 + lq * 8];
            bf16x8 v0l = *(const bf16x8*)&Kl[(j * 16 + lm) * 72 + lq * 8];
            bf16x8 v1  = *(const bf16x8*)&Kh[(j * 16 + lm) * 72 + 32 + lq * 8];
            bf16x8 v1l = *(const bf16x8*)&Kl[(j * 16 + lm) * 72 + 32 + lq * 8];
            acc[j] = mfma3(e0, e0l, v0, v0l, acc[j]);
            acc[j] = mfma3(e1, e1l, v1, v1l, acc[j]);
        }
        __syncthreads();
    }
    float* t1b = t1 + (size_t)bz * 16384;
#pragma unroll
    for (int j = 0; j < 4; ++j)
#pragma unroll
        for (int e = 0; e < 4; ++e)
            atomicAdd(t1b + (size_t)(m0 + wave * 16 + lq * 4 + e) * 64 +
                          j * 16 + lm,
                      acc[j][e]);
#pragma unroll
    for (int e = 0; e < 4; ++e) {
        float vs = rsum[e];
        for (int mm = 1; mm < 16; mm <<= 1) vs += __shfl_xor(vs, mm);
        if (lm == 0)
            atomicAdd(rs3 + bz * 256 + m0 + wave * 16 + lq * 4 + e, vs);
    }
}

// ---------------------------------------------------------------------------
// F1 MFMA: oh = softmax(q@kland^T) @ t2 (normalized). q/kland from planes.
// t2 planes at per-z stride 65536 (Y1T slices). grid (64, 32).
// ---------------------------------------------------------------------------
__global__ __launch_bounds__(256) void attn1t2_mfma(
    const unsigned short* __restrict__ qh_, const unsigned short* __restrict__ ql_,
    const unsigned short* __restrict__ klh, const unsigned short* __restrict__ kll,
    const unsigned short* __restrict__ t2Th,
    const unsigned short* __restrict__ t2Tl, float* __restrict__ oh) {
    __shared__ unsigned short Qh[4608], Ql[4608];
    __shared__ unsigned short Kh[4608], Kl[4608];
    __shared__ unsigned short Eh[4608], El[4608];
    const int t = threadIdx.x;
    const int wave = t >> 6, lane = t & 63, lm = lane & 15, lq = lane >> 4;
    const int bz = blockIdx.y, m0 = blockIdx.x * 64;
    const unsigned short* qhb = qh_ + (size_t)bz * 262144;
    const unsigned short* qlb = ql_ + (size_t)bz * 262144;
    const unsigned short* khb = klh + (size_t)bz * 16384;
    const unsigned short* klb = kll + (size_t)bz * 16384;
    const unsigned short* t2h = t2Th + (size_t)bz * 65536;
    const unsigned short* t2l = t2Tl + (size_t)bz * 65536;
#pragma unroll
    for (int r = 0; r < 2; ++r) {
        int id = t + r * 256, row = id >> 3, ko = (id & 7) * 8;
        *(uint4*)&Qh[row * 72 + ko] =
            *(const uint4*)(qhb + (size_t)(m0 + row) * 64 + ko);
        *(uint4*)&Ql[row * 72 + ko] =
            *(const uint4*)(qlb + (size_t)(m0 + row) * 64 + ko);
    }
    f32x4 acc[4];
#pragma unroll
    for (int j = 0; j < 4; ++j) acc[j] = (f32x4){0.f, 0.f, 0.f, 0.f};
    float rsum[4] = {0.f, 0.f, 0.f, 0.f};
    __syncthreads();

    for (int lc = 0; lc < 4; ++lc) {
        const int l0 = lc * 64;
#pragma unroll
        for (int r = 0; r < 2; ++r) {
            int id = t + r * 256, row = id >> 3, ko = (id & 7) * 8;
            *(uint4*)&Kh[row * 72 + ko] =
                *(const uint4*)(khb + (size_t)(l0 + row) * 64 + ko);
            *(uint4*)&Kl[row * 72 + ko] =
                *(const uint4*)(klb + (size_t)(l0 + row) * 64 + ko);
        }
        __syncthreads();
        bf16x8 a0  = *(const bf16x8*)&Qh[(wave * 16 + lm) * 72 + lq * 8];
        bf16x8 a0l = *(const bf16x8*)&Ql[(wave * 16 + lm) * 72 + lq * 8];
        bf16x8 a1  = *(const bf16x8*)&Qh[(wave * 16 + lm) * 72 + 32 + lq * 8];
        bf16x8 a1l = *(const bf16x8*)&Ql[(wave * 16 + lm) * 72 + 32 + lq * 8];
        f32x4 s[4];
#pragma unroll
        for (int j = 0; j < 4; ++j) s[j] = (f32x4){0.f, 0.f, 0.f, 0.f};
#pragma unroll
        for (int j = 0; j < 4; ++j) {
            bf16x8 b0  = *(const bf16x8*)&Kh[(j * 16 + lm) * 72 + lq * 8];
            bf16x8 b0l = *(const bf16x8*)&Kl[(j * 16 + lm) * 72 + lq * 8];
            bf16x8 b1  = *(const bf16x8*)&Kh[(j * 16 + lm) * 72 + 32 + lq * 8];
            bf16x8 b1l = *(const bf16x8*)&Kl[(j * 16 + lm) * 72 + 32 + lq * 8];
            s[j] = mfma3(a0, a0l, b0, b0l, s[j]);
            s[j] = mfma3(a1, a1l, b1, b1l, s[j]);
        }
        __syncthreads();
#pragma unroll
        for (int j = 0; j < 4; ++j)
#pragma unroll
            for (int e = 0; e < 4; ++e) {
                float ev = __expf(s[j][e]);
                rsum[e] += ev;
                unsigned short h, l;
                split2(ev, h, l);
                int off = (wave * 16 + lq * 4 + e) * 72 + j * 16 + lm;
                Eh[off] = h;
                El[off] = l;
            }
#pragma unroll
        for (int r = 0; r < 2; ++r) {
            int id = t + r * 256, dh = id >> 3, t8 = (id & 7) * 8;
            *(uint4*)&Kh[dh * 72 + t8] =
                *(const uint4*)(t2h + (size_t)dh * 256 + l0 + t8);
            *(uint4*)&Kl[dh * 72 + t8] =
                *(const uint4*)(t2l + (size_t)dh * 256 + l0 + t8);
        }
        __syncthreads();
        bf16x8 e0  = *(const bf16x8*)&Eh[(wave * 16 + lm) * 72 + lq * 8];
        bf16x8 e0l = *(const bf16x8*)&El[(wave * 16 + lm) * 72 + lq * 8];
        bf16x8 e1  = *(const bf16x8*)&Eh[(wave * 16 + lm) * 72 + 32 + lq * 8];
        bf16x8 e1l = *(const bf16x8*)&El[(wave * 16 + lm) * 72 + 32 + lq * 8];
#pragma unroll
        for (int j = 0; j < 4; ++j) {
            bf16x8 v0  = *(const bf16x8*)&Kh[(j * 16 + lm) * 72 + lq * 8];
            bf16x8 v0l = *(const bf16x8*)&Kl[(j * 16 + lm) * 72 + lq * 8];
            bf16x8 v1  = *(const bf16x8*)&Kh[(j * 16 + lm) * 72 + 32 + lq * 8];
            bf16x8 v1l = *(const bf16x8*)&Kl[(j * 16 + lm) * 72 + 32 + lq * 8];
            acc[j] = mfma3(e0, e0l, v0, v0l, acc[j]);
            acc[j] = mfma3(e1, e1l, v1, v1l, acc[j]);
        }
        __syncthreads();
    }
    float rinv[4];
#pragma unroll
    for (int e = 0; e < 4; ++e) {
        float vs = rsum[e];
        for (int mm = 1; mm < 16; mm <<= 1) vs += __shfl_xor(vs, mm);
        rinv[e] = 1.0f / vs;
    }
    float* ohb = oh + (size_t)bz * 262144;
#pragma unroll
    for (int j = 0; j < 4; ++j)
#pragma unroll
        for (int e = 0; e < 4; ++e)
            ohb[(size_t)(m0 + wave * 16 + lq * 4 + e) * 64 + j * 16 + lm] =
                acc[j][e] * rinv[e];
}

// ---------------------------------------------------------------------------
// weight transpose+split: W[512][N] -> planes T[N][512]
// ---------------------------------------------------------------------------
__global__ void wtrans(const float* __restrict__ W, int N,
                       unsigned short* __restrict__ Th,
                       unsigned short* __restrict__ Tl) {
    int idx = blockIdx.x * 256 + threadIdx.x;
    int n = idx >> 9, kk = idx & 511;
    float x = W[(size_t)kk * N + n];
    unsigned short h, l;
    split2(x, h, l);
    Th[idx] = h;
    Tl[idx] = l;
}

// ---------------------------------------------------------------------------
// fp32 gemm for attn2 (TRANSB path only)
// ---------------------------------------------------------------------------
template <bool TRANSB>
__global__ __launch_bounds__(256) void gemm_bk(
    const float* __restrict__ A, int saA, int lda,
    const float* __restrict__ B, int sbB, int ldb,
    float* __restrict__ C, int scC, int ldc, int K) {
    __shared__ float As[16 * 68];
    __shared__ float Bs[16 * 68];
    const int t  = threadIdx.x;
    const int z  = blockIdx.z;
    const int m0 = blockIdx.y * 64;
    const int n0 = blockIdx.x * 64;
    const float* Ab = A + (size_t)z * saA;
    const float* Bb = B + (size_t)z * sbB;
    float*       Cb = C + (size_t)z * scC;
    const int tx4 = (t & 15) * 4;
    const int ty4 = (t >> 4) * 4;
    const int ar  = t >> 2, ak = (t & 3) * 4;
    float acc[4][4] = {};
    for (int kt = 0; kt < K; kt += 16) {
        float4 av = *(const float4*)(Ab + (size_t)(m0 + ar) * lda + kt + ak);
        float4 bv = *(const float4*)(Bb + (size_t)(n0 + ar) * ldb + kt + ak);
        As[(ak + 0) * 68 + ar] = av.x;
        As[(ak + 1) * 68 + ar] = av.y;
        As[(ak + 2) * 68 + ar] = av.z;
        As[(ak + 3) * 68 + ar] = av.w;
        Bs[(ak + 0) * 68 + ar] = bv.x;
        Bs[(ak + 1) * 68 + ar] = bv.y;
        Bs[(ak + 2) * 68 + ar] = bv.z;
        Bs[(ak + 3) * 68 + ar] = bv.w;
        __syncthreads();
        mt16(As, Bs, ty4, tx4, acc);
        __syncthreads();
    }
#pragma unroll
    for (int u = 0; u < 4; ++u) {
        int row = m0 + ty4 + u;
        *(float4*)(Cb + (size_t)row * ldc + n0 + tx4) =
            make_float4(acc[u][0], acc[u][1], acc[u][2], acc[u][3]);
    }
}

// ---------------------------------------------------------------------------
// small kernels
// ---------------------------------------------------------------------------
__global__ void zero_f(float* __restrict__ p, int n) {
    int i = blockIdx.x * 256 + threadIdx.x;
    if (i < n) p[i] = 0.f;
}

// landmark mean from split planes; emits fp32 + split planes
__global__ void landmark_mean_p(const unsigned short* __restrict__ sh,
                                const unsigned short* __restrict__ sl,
                                float* __restrict__ dst,
                                unsigned short* __restrict__ dh,
                                unsigned short* __restrict__ dl) {
    int o = blockIdx.x * 256 + threadIdx.x;
    int d = o & 63, m = (o >> 6) & 255, bh = o >> 14;
    size_t base = (size_t)bh * 262144 + (size_t)m * 1024 + d;
    float acc = 0.f;
#pragma unroll
    for (int j = 0; j < 16; ++j)
        acc += b2f(sh[base + j * 64]) + b2f(sl[base + j * 64]);
    float v = acc * (1.0f / 16.0f);
    dst[o] = v;
    unsigned short h, l;
    split2(v, h, l);
    dh[o] = h;
    dl[o] = l;
}

__global__ void softmax_rows(float* __restrict__ a) {
    __shared__ float red[256];
    int row = blockIdx.x, t = threadIdx.x;
    float v = a[(size_t)row * 256 + t];
    red[t] = v;
    __syncthreads();
    for (int s = 128; s > 0; s >>= 1) {
        if (t < s) red[t] = fmaxf(red[t], red[t + s]);
        __syncthreads();
    }
    float mx = red[0];
    __syncthreads();
    float e = __expf(v - mx);
    red[t] = e;
    __syncthreads();
    for (int s = 128; s > 0; s >>= 1) {
        if (t < s) red[t] += red[t + s];
        __syncthreads();
    }
    a[(size_t)row * 256 + t] = e / red[0];
}

__global__ __launch_bounds__(256) void scalar_prep(const float* __restrict__ a,
                                                   float* __restrict__ scal) {
    __shared__ float red[256];
    int bh = blockIdx.x, t = threadIdx.x;
    const float* ab = a + (size_t)bh * 65536;
    float cs = 0.f;
    for (int i = 0; i < 256; ++i) cs += ab[i * 256 + t];
    red[t] = cs;
    __syncthreads();
    for (int s = 128; s > 0; s >>= 1) {
        if (t < s) red[t] = fmaxf(red[t], red[t + s]);
        __syncthreads();
    }
    float mcol = red[0];
    __syncthreads();
    float rs = 0.f;
    for (int j = 0; j < 256; ++j) rs += ab[t * 256 + j];
    red[t] = rs;
    __syncthreads();
    for (int s = 128; s > 0; s >>= 1) {
        if (t < s) red[t] = fmaxf(red[t], red[t + s]);
        __syncthreads();
    }
    if (t == 0) {
        atomicMax((unsigned int*)&scal[0], __float_as_uint(mcol));
        atomicMax((unsigned int*)&scal[1], __float_as_uint(red[0]));
    }
}

// ---------------------------------------------------------------------------
// LDS-tiled depthwise conv reading vT planes; emits OH planes (oh + conv).
// grid (32 tiles, 32 bh). Each block: 128 tokens x 64 dh; 160-token window.
// ---------------------------------------------------------------------------
__global__ __launch_bounds__(256) void conv_tiled(
    const float* __restrict__ ohin, const unsigned short* __restrict__ vTh,
    const unsigned short* __restrict__ vTl, const float* __restrict__ wres,
    unsigned short* __restrict__ OHh, unsigned short* __restrict__ OHl) {
    __shared__ float Vs[160 * 65];
    __shared__ float Ws[33];
    const int t = threadIdx.x;
    const int bh = blockIdx.y;
    const int n0 = blockIdx.x * 128;
    const int h = bh & 7;
    if (t < 33) Ws[t] = wres[h * 33 + t];
    const unsigned short* vhb = vTh + (size_t)bh * 262144;
    const unsigned short* vlb = vTl + (size_t)bh * 262144;
#pragma unroll
    for (int r = 0; r < 5; ++r) {
        int id = t + r * 256;               // 0..1279: 64 dh x 20 chunks of 8
        int d = id / 20, ch = id - d * 20;
        int n = n0 - 16 + ch * 8;
        uint4 h4 = make_uint4(0u, 0u, 0u, 0u);
        uint4 l4 = make_uint4(0u, 0u, 0u, 0u);
        if ((unsigned)n < 4096u) {
            h4 = *(const uint4*)(vhb + (size_t)d * 4096 + n);
            l4 = *(const uint4*)(vlb + (size_t)d * 4096 + n);
        }
        const unsigned short* hp = (const unsigned short*)&h4;
        const unsigned short* lp = (const unsigned short*)&l4;
        int row0 = ch * 8;
#pragma unroll
        for (int i = 0; i < 8; ++i)
            Vs[(row0 + i) * 65 + d] = b2f(hp[i]) + b2f(lp[i]);
    }
    __syncthreads();
    const int d = t & 63;
    const int g0 = (t >> 6) * 32;
    const float* ohb = ohin + (size_t)bh * 262144 + (size_t)n0 * 64;
    unsigned short* Hh = OHh + (size_t)bh * 262144 + (size_t)n0 * 64;
    unsigned short* Hl = OHl + (size_t)bh * 262144 + (size_t)n0 * 64;
    float w[33];
#pragma unroll
    for (int j = 0; j < 33; ++j) w[j] = Vs[(g0 + j) * 65 + d];
#pragma unroll
    for (int i = 0; i < 32; ++i) {
        float acc = ohb[(size_t)(g0 + i) * 64 + d];
#pragma unroll
        for (int tt = 0; tt < 33; ++tt) acc += w[tt] * Ws[tt];
        unsigned short hh, ll;
        split2(acc, hh, ll);
        Hh[(size_t)(g0 + i) * 64 + d] = hh;
        Hl[(size_t)(g0 + i) * 64 + d] = ll;
        if (i < 31) {
#pragma unroll
            for (int j = 0; j < 32; ++j) w[j] = w[j + 1];
            w[32] = Vs[(g0 + i + 33) * 65 + d];
        }
    }
}

// ---------------------------------------------------------------------------
extern "C" void kernel_launch(void* const* d_in, const int* in_sizes, int n_in,
                              void* d_out, int out_size, void* d_ws, size_t ws_size,
                              hipStream_t stream) {
    const float* x     = (const float*)d_in[0];
    const float* w_qkv = (const float*)d_in[1];
    const float* w_out = (const float*)d_in[2];
    const float* w_res = (const float*)d_in[3];
    float* out = (float*)d_out;
    float* ws  = (float*)d_ws;

    // planes (ushort units)
    unsigned short* Xh  = (unsigned short*)(ws + O_XP);
    unsigned short* Xl  = Xh + 8388608;
    unsigned short* qh  = (unsigned short*)(ws + O_QP);
    unsigned short* ql  = qh + 8388608;
    unsigned short* kh  = (unsigned short*)(ws + O_KP);
    unsigned short* kl  = kh + 8388608;
    unsigned short* vTh = (unsigned short*)(ws + O_VT);
    unsigned short* vTl = vTh + 8388608;
    unsigned short* qlh = (unsigned short*)(ws + O_QLP);
    unsigned short* qll = qlh + 524288;
    unsigned short* klh = (unsigned short*)(ws + O_KLP);
    unsigned short* kll = klh + 524288;

    float* qland = ws + O_QL;
    float* kland = ws + O_KL;
    float* attn2 = ws + O_A2;
    float* t1    = ws + O_T1;
    float* rs3   = ws + O_RS3;
    float* scal  = ws + O_SCAL;

    // pinv-phase aliases (k planes region is dead after attn3v)
    unsigned short* PB   = (unsigned short*)(ws + O_KP);
    unsigned short* ZT0h = PB;
    unsigned short* ZT0l = PB + 2097152;
    unsigned short* ZT1h = PB + 4194304;
    unsigned short* ZT1l = PB + 6291456;
    unsigned short* XZTh = PB + 8388608;
    unsigned short* XZTl = PB + 10485760;
    unsigned short* Y1Th = PB + 12582912;
    unsigned short* Y1Tl = PB + 14680064;
    // X-plane region is dead after qkv: hosts zA/zB + Y2T, later oh fp32
    float* zA = ws + O_XP;
    float* zB = zA + 2097152;
    unsigned short* Y2Th = (unsigned short*)(ws + O_XP + 4194304);
    unsigned short* Y2Tl = Y2Th + 2097152;
    // post-pinv aliases
    float* ohf = ws + O_XP;               // zA/zB/Y2T dead
    unsigned short* OHh = PB;             // ZT/XZT dead after attn1t2
    unsigned short* OHl = PB + 8388608;
    unsigned* bars = (unsigned*)(ws + O_BAR);

    unsigned short* WQTh = (unsigned short*)(ws + O_WQT);
    unsigned short* WQTl = WQTh + 786432;
    unsigned short* WOTh = (unsigned short*)(ws + O_WOT);
    unsigned short* WOTl = WOTh + 262144;

    zero_f<<<2081, 256, 0, stream>>>(t1, 532496);   // t1+rs3+scal
    zero_f<<<8, 256, 0, stream>>>((float*)bars, 2048);
    wtrans<<<3072, 256, 0, stream>>>(w_qkv, 1536, WQTh, WQTl);
    wtrans<<<1024, 256, 0, stream>>>(w_out, 512, WOTh, WOTl);
    xsplit<<<8192, 256, 0, stream>>>(x, Xh, Xl);

    mfma_qkv<<<dim3(12, 128), 256, 0, stream>>>(Xh, Xl, WQTh, WQTl,
                                                qh, ql, kh, kl, vTh, vTl);

    landmark_mean_p<<<2048, 256, 0, stream>>>(qh, ql, qland, qlh, qll);
    landmark_mean_p<<<2048, 256, 0, stream>>>(kh, kl, kland, klh, kll);

    gemm_bk<true><<<dim3(4, 4, 32), 256, 0, stream>>>(
        qland, 16384, 64, kland, 16384, 64, attn2, 65536, 256, 64);
    softmax_rows<<<8192, 256, 0, stream>>>(attn2);
    scalar_prep<<<32, 256, 0, stream>>>(attn2, scal);

    // F3 before pinv (k and vT planes consumed here; k planes die here)
    attn3v_mfma<<<dim3(8, 4, 32), 256, 0, stream>>>(qlh, qll, kh, kl,
                                                    vTh, vTl, t1, rs3);

    // Fused persistent pinv: zinit + 6x4 stages + t2, one ordinary launch.
    pinv_coop<<<256, 256, 0, stream>>>(attn2, scal, zA, zB,
                                       ZT0h, ZT0l, ZT1h, ZT1l,
                                       XZTh, XZTl, Y1Th, Y1Tl,
                                       Y2Th, Y2Tl, t1, rs3, bars);

    // F1: oh = softmax(q@kland^T)@t2 -> ohf; t2 planes live in Y1T slices
    attn1t2_mfma<<<dim3(64, 32), 256, 0, stream>>>(qh, ql, klh, kll,
                                                   Y1Th, Y1Tl, ohf);

    // OH planes = oh + depthwise conv(v), from vT planes
    conv_tiled<<<dim3(32, 32), 256, 0, stream>>>(ohf, vTh, vTl, w_res,
                                                 OHh, OHl);

    mfma_final<<<dim3(4, 128), 256, 0, stream>>>(OHh, OHl, WOTh, WOTl, out);

    (void)in_sizes; (void)n_in; (void)out_size; (void)ws_size;
}

// Round 4
// 841.295 us; speedup vs baseline: 1.4854x; 1.4854x over previous
//
#include <hip/hip_runtime.h>

// ---------------------------------------------------------------------------
// Nystrom attention: split-bf16 (hi/lo, 3xMFMA) everywhere.
// R9: multi-launch pinv with ALL-PLANE operands. Every pinv stage reads A
// (normal-layout planes) and B (transposed planes) as pure uint4 copies —
// no split2 VALU in the K-loop, no fp32 z/xz round-trips. attn2 pre-split
// once; zinit emits z0 planes only; iter-1 xz folds 1/denom into alpha so
// B(iter1) = a2 planes directly. 64x64 tiles (512 blocks, 2/CU).
// Persistent/coop pinv abandoned (R7/R8: barrier fence cost ~30us each).
// B=4, N=4096, DIM=512, H=8, DH=64, M=256, l=16, 6 pinv iters, conv K=33.
// ---------------------------------------------------------------------------

typedef __attribute__((ext_vector_type(8))) short bf16x8;
typedef __attribute__((ext_vector_type(4))) float f32x4;

// workspace layout (float units)
constexpr size_t O_XP  = 0;          // Xh/Xl planes; later ZN/ZT/Y2T planes; later oh fp32
constexpr size_t O_QP  = 8388608;    // q planes (hi/lo)
constexpr size_t O_KP  = 16777216;   // k planes; later A2P/XZN/XZT/Y1T; later t2T; later OH planes
constexpr size_t O_VT  = 25165824;   // vT planes
constexpr size_t O_QL  = 33554432;   // qland fp32
constexpr size_t O_KL  = 34078720;   // kland fp32
constexpr size_t O_QLP = 34603008;   // qland planes
constexpr size_t O_KLP = 35127296;   // kland planes
constexpr size_t O_A2  = 35651584;   // attn2 fp32
constexpr size_t O_T1  = 37748736;
constexpr size_t O_RS3 = 38273024;
constexpr size_t O_SCAL= 38281216;
constexpr size_t O_T2  = 38281232;   // fp32 t2
constexpr size_t O_WQT = 38805520;
constexpr size_t O_WOT = 39591952;
constexpr size_t O_END = 39854096;   // ~159.4 MB

// ---------------------------------------------------------------------------
__device__ __forceinline__ void split2(float x, unsigned short& h,
                                       unsigned short& l) {
    unsigned u  = __float_as_uint(x);
    unsigned hb = (u + 0x7FFFu + ((u >> 16) & 1u)) & 0xFFFF0000u;  // RNE hi
    h = (unsigned short)(hb >> 16);
    float d = x - __uint_as_float(hb);
    l = (unsigned short)(__float_as_uint(d) >> 16);
}

__device__ __forceinline__ float b2f(unsigned short s) {
    return __uint_as_float((unsigned)s << 16);
}

__device__ __forceinline__ f32x4 mfma3(bf16x8 ah, bf16x8 al, bf16x8 bh,
                                       bf16x8 bl, f32x4 c) {
    c = __builtin_amdgcn_mfma_f32_16x16x32_bf16(ah, bh, c, 0, 0, 0);
    c = __builtin_amdgcn_mfma_f32_16x16x32_bf16(ah, bl, c, 0, 0, 0);
    c = __builtin_amdgcn_mfma_f32_16x16x32_bf16(al, bh, c, 0, 0, 0);
    return c;
}

// split a float4 into hi/lo planes, write packed uint2 at H[off], L[off]
__device__ __forceinline__ void stage_split4(float4 av, unsigned short* H,
                                             unsigned short* L, int off) {
    unsigned short h0, h1, h2, h3, l0, l1, l2, l3;
    split2(av.x, h0, l0); split2(av.y, h1, l1);
    split2(av.z, h2, l2); split2(av.w, h3, l3);
    uint2 ph, pl;
    ph.x = (unsigned)h0 | ((unsigned)h1 << 16);
    ph.y = (unsigned)h2 | ((unsigned)h3 << 16);
    pl.x = (unsigned)l0 | ((unsigned)l1 << 16);
    pl.y = (unsigned)l2 | ((unsigned)l3 << 16);
    *(uint2*)&H[off] = ph;
    *(uint2*)&L[off] = pl;
}

// ---------------------------------------------------------------------------
// X (or attn2) -> split planes (one-time)
// ---------------------------------------------------------------------------
__global__ void xsplit(const float* __restrict__ X,
                       unsigned short* __restrict__ Xh,
                       unsigned short* __restrict__ Xl) {
    int idx = blockIdx.x * 256 + threadIdx.x;
    float4 v = *(const float4*)(X + (size_t)idx * 4);
    stage_split4(v, Xh, Xl, idx * 4);
}

// ---------------------------------------------------------------------------
// zinit: z0 = a2^T / denom -> normal-layout planes ZN[m][k] only.
// ---------------------------------------------------------------------------
__global__ void zinit_n(const float* __restrict__ a2,
                        const float* __restrict__ scal,
                        unsigned short* __restrict__ Zh,
                        unsigned short* __restrict__ Zl) {
    int idx = blockIdx.x * 256 + threadIdx.x;
    float denom = scal[0] * scal[1] + 1e-8f;
    int bh = idx >> 16, r = (idx >> 8) & 255, c = idx & 255;
    float v = a2[idx] / denom;
    unsigned short h, l;
    split2(v, h, l);
    size_t o = ((size_t)bh << 16) + ((size_t)c << 8) + r;
    Zh[o] = h;
    Zl[o] = l;
}

// ---------------------------------------------------------------------------
// All-plane pinv GEMM stage: C = alpha*(A@B) + beta*A_elem.
// A = normal planes AN[m][k]; B = transposed planes BT[n][k].
// Outputs: optional normal planes CN, optional transposed planes CT.
// 256x256 per z, 64x64 tile, grid (4,4,32), 256 threads.
// ---------------------------------------------------------------------------
template <int EPI, bool ASCAL, bool WN, bool WTT>
__global__ __launch_bounds__(256) void mfma_gemm_p(
    const unsigned short* __restrict__ ANh, const unsigned short* __restrict__ ANl,
    const unsigned short* __restrict__ BTh, const unsigned short* __restrict__ BTl,
    unsigned short* __restrict__ CNh, unsigned short* __restrict__ CNl,
    unsigned short* __restrict__ CTh, unsigned short* __restrict__ CTl,
    float alpha, float beta, const float* __restrict__ scal) {
    __shared__ unsigned short Ah[64 * 40], Al[64 * 40];
    __shared__ unsigned short Bh[64 * 40], Bl[64 * 40];
    const int t = threadIdx.x;
    const int wave = t >> 6, lane = t & 63, lm = lane & 15, lq = lane >> 4;
    const int z = blockIdx.z;
    const int m0 = blockIdx.y * 64, n0 = blockIdx.x * 64;
    const size_t zo = (size_t)z * 65536;

    f32x4 acc[4];
#pragma unroll
    for (int j = 0; j < 4; ++j) acc[j] = (f32x4){0.f, 0.f, 0.f, 0.f};

    const int row = t >> 2, ko = (t & 3) * 8;
    for (int kt = 0; kt < 256; kt += 32) {
        *(uint4*)&Ah[row * 40 + ko] =
            *(const uint4*)(ANh + zo + (size_t)(m0 + row) * 256 + kt + ko);
        *(uint4*)&Al[row * 40 + ko] =
            *(const uint4*)(ANl + zo + (size_t)(m0 + row) * 256 + kt + ko);
        *(uint4*)&Bh[row * 40 + ko] =
            *(const uint4*)(BTh + zo + (size_t)(n0 + row) * 256 + kt + ko);
        *(uint4*)&Bl[row * 40 + ko] =
            *(const uint4*)(BTl + zo + (size_t)(n0 + row) * 256 + kt + ko);
        __syncthreads();
        bf16x8 ah = *(const bf16x8*)&Ah[(wave * 16 + lm) * 40 + lq * 8];
        bf16x8 al = *(const bf16x8*)&Al[(wave * 16 + lm) * 40 + lq * 8];
#pragma unroll
        for (int j = 0; j < 4; ++j) {
            bf16x8 bh = *(const bf16x8*)&Bh[(j * 16 + lm) * 40 + lq * 8];
            bf16x8 bl = *(const bf16x8*)&Bl[(j * 16 + lm) * 40 + lq * 8];
            acc[j] = mfma3(ah, al, bh, bl, acc[j]);
        }
        __syncthreads();
    }

    float a = alpha;
    if (ASCAL) a = 1.0f / (scal[0] * scal[1] + 1e-8f);
    const int r0 = m0 + wave * 16 + lq * 4;
#pragma unroll
    for (int j = 0; j < 4; ++j) {
        int c = n0 + j * 16 + lm;
        float vals[4];
#pragma unroll
        for (int e = 0; e < 4; ++e) {
            vals[e] = a * acc[j][e];
            if (EPI == 1) {
                size_t ao = zo + (size_t)(r0 + e) * 256 + c;
                vals[e] += beta * (b2f(ANh[ao]) + b2f(ANl[ao]));
            }
        }
        unsigned short hh[4], ll[4];
#pragma unroll
        for (int e = 0; e < 4; ++e) split2(vals[e], hh[e], ll[e]);
        if (WN) {
#pragma unroll
            for (int e = 0; e < 4; ++e) {
                size_t o = zo + (size_t)(r0 + e) * 256 + c;
                CNh[o] = hh[e];
                CNl[o] = ll[e];
            }
        }
        if (WTT) {
            uint2 ph, pl;
            ph.x = (unsigned)hh[0] | ((unsigned)hh[1] << 16);
            ph.y = (unsigned)hh[2] | ((unsigned)hh[3] << 16);
            pl.x = (unsigned)ll[0] | ((unsigned)ll[1] << 16);
            pl.y = (unsigned)ll[2] | ((unsigned)ll[3] << 16);
            *(uint2*)&CTh[zo + (size_t)c * 256 + r0] = ph;
            *(uint2*)&CTl[zo + (size_t)c * 256 + r0] = pl;
        }
    }
}

// fp32 64x64 micro-kernel (used by attn2 gemm and t2 stage)
__device__ __forceinline__ void mt16(const float* As, const float* Bs,
                                     int ty4, int tx4, float (&acc)[4][4]) {
#pragma unroll
    for (int kk = 0; kk < 16; ++kk) {
        float4 a4 = *(const float4*)(As + kk * 68 + ty4);
        float4 b4 = *(const float4*)(Bs + kk * 68 + tx4);
        float aa[4] = {a4.x, a4.y, a4.z, a4.w};
        float bb[4] = {b4.x, b4.y, b4.z, b4.w};
#pragma unroll
        for (int u = 0; u < 4; ++u)
#pragma unroll
            for (int w = 0; w < 4; ++w)
                acc[u][w] += aa[u] * bb[w];
    }
}

// ---------------------------------------------------------------------------
// t2 = z6 @ (t1/rs3): A from ZN planes (h+l recombine), fp32 micro-kernel.
// grid (1, 4, 32). Emits t2 fp32 + t2^T planes (stride 16384/z).
// ---------------------------------------------------------------------------
__global__ __launch_bounds__(256) void t2_gemm(
    const unsigned short* __restrict__ ANh, const unsigned short* __restrict__ ANl,
    const float* __restrict__ t1, const float* __restrict__ rs3,
    float* __restrict__ t2, unsigned short* __restrict__ t2Th,
    unsigned short* __restrict__ t2Tl) {
    __shared__ float As[16 * 68];
    __shared__ float Bs[16 * 68];
    const int t  = threadIdx.x;
    const int z  = blockIdx.z;
    const int m0 = blockIdx.y * 64;
    const size_t zo = (size_t)z * 65536;
    const float* Bb = t1 + (size_t)z * 16384;
    float* Cb = t2 + (size_t)z * 16384;
    const int tx4 = (t & 15) * 4;
    const int ty4 = (t >> 4) * 4;
    const int ar  = t >> 2, ak = (t & 3) * 4;
    const int bkr = t >> 4, bc4 = (t & 15) * 4;
    float acc[4][4] = {};
    for (int kt = 0; kt < 256; kt += 16) {
        uint2 h2 = *(const uint2*)(ANh + zo + (size_t)(m0 + ar) * 256 + kt + ak);
        uint2 l2 = *(const uint2*)(ANl + zo + (size_t)(m0 + ar) * 256 + kt + ak);
        const unsigned short* hp = (const unsigned short*)&h2;
        const unsigned short* lp = (const unsigned short*)&l2;
        float4 av = make_float4(b2f(hp[0]) + b2f(lp[0]), b2f(hp[1]) + b2f(lp[1]),
                                b2f(hp[2]) + b2f(lp[2]), b2f(hp[3]) + b2f(lp[3]));
        float4 bv = *(const float4*)(Bb + (size_t)(kt + bkr) * 64 + bc4);
        float rr = 1.0f / rs3[z * 256 + kt + bkr];
        bv.x *= rr; bv.y *= rr; bv.z *= rr; bv.w *= rr;
        As[(ak + 0) * 68 + ar] = av.x;
        As[(ak + 1) * 68 + ar] = av.y;
        As[(ak + 2) * 68 + ar] = av.z;
        As[(ak + 3) * 68 + ar] = av.w;
        *(float4*)(Bs + bkr * 68 + bc4) = bv;
        __syncthreads();
        mt16(As, Bs, ty4, tx4, acc);
        __syncthreads();
    }
#pragma unroll
    for (int u = 0; u < 4; ++u) {
        int rowc = m0 + ty4 + u;
        *(float4*)(Cb + (size_t)rowc * 64 + tx4) =
            make_float4(acc[u][0], acc[u][1], acc[u][2], acc[u][3]);
    }
#pragma unroll
    for (int w = 0; w < 4; ++w) {
        unsigned short hh[4], ll[4];
#pragma unroll
        for (int u = 0; u < 4; ++u) split2(acc[u][w], hh[u], ll[u]);
        uint2 ph, pl;
        ph.x = (unsigned)hh[0] | ((unsigned)hh[1] << 16);
        ph.y = (unsigned)hh[2] | ((unsigned)hh[3] << 16);
        pl.x = (unsigned)ll[0] | ((unsigned)ll[1] << 16);
        pl.y = (unsigned)ll[2] | ((unsigned)ll[3] << 16);
        size_t off = (size_t)z * 16384 + (size_t)(tx4 + w) * 256 + m0 + ty4;
        *(uint2*)&t2Th[off] = ph;
        *(uint2*)&t2Tl[off] = pl;
    }
}

// ---------------------------------------------------------------------------
// qkv MFMA GEMM: X planes [16384,512] @ w_qkv planes; emits q/k planes
// ([bh][n][d], q scaled 0.125) and vT planes [bh][dh][4096]. grid (12,128).
// ---------------------------------------------------------------------------
__global__ __launch_bounds__(256) void mfma_qkv(
    const unsigned short* __restrict__ Xh_, const unsigned short* __restrict__ Xl_,
    const unsigned short* __restrict__ WTh, const unsigned short* __restrict__ WTl,
    unsigned short* __restrict__ qh, unsigned short* __restrict__ ql,
    unsigned short* __restrict__ kh, unsigned short* __restrict__ kl,
    unsigned short* __restrict__ vTh, unsigned short* __restrict__ vTl) {
    __shared__ unsigned short Ah[128 * 40], Al[128 * 40];
    __shared__ unsigned short Bh[128 * 40], Bl[128 * 40];
    const int t = threadIdx.x;
    const int wave = t >> 6, lane = t & 63, lm = lane & 15, lq = lane >> 4;
    // XCD-aware bijective swizzle: nwg=1536, 1536/8=192 per XCD
    int orig = blockIdx.y * 12 + blockIdx.x;
    int wg = (orig & 7) * 192 + (orig >> 3);
    const int m0 = (wg / 12) * 128, n0 = (wg % 12) * 128;
    const int mb = (wave >> 1) * 64, nb = (wave & 1) * 64;
    f32x4 acc[4][4];
#pragma unroll
    for (int i = 0; i < 4; ++i)
#pragma unroll
        for (int j = 0; j < 4; ++j) acc[i][j] = (f32x4){0.f, 0.f, 0.f, 0.f};

    for (int kt = 0; kt < 512; kt += 32) {
#pragma unroll
        for (int r = 0; r < 2; ++r) {
            int id = t + r * 256, row = id >> 2, ko = (id & 3) * 8;
            *(uint4*)&Ah[row * 40 + ko] =
                *(const uint4*)(Xh_ + (size_t)(m0 + row) * 512 + kt + ko);
            *(uint4*)&Al[row * 40 + ko] =
                *(const uint4*)(Xl_ + (size_t)(m0 + row) * 512 + kt + ko);
        }
#pragma unroll
        for (int r = 0; r < 2; ++r) {
            int id = t + r * 256, row = id >> 2, ko = (id & 3) * 8;
            *(uint4*)&Bh[row * 40 + ko] =
                *(const uint4*)(WTh + (size_t)(n0 + row) * 512 + kt + ko);
            *(uint4*)&Bl[row * 40 + ko] =
                *(const uint4*)(WTl + (size_t)(n0 + row) * 512 + kt + ko);
        }
        __syncthreads();
        bf16x8 ah[4], al[4], bh[4], bl[4];
#pragma unroll
        for (int i = 0; i < 4; ++i) {
            ah[i] = *(const bf16x8*)&Ah[(mb + i * 16 + lm) * 40 + lq * 8];
            al[i] = *(const bf16x8*)&Al[(mb + i * 16 + lm) * 40 + lq * 8];
        }
#pragma unroll
        for (int j = 0; j < 4; ++j) {
            bh[j] = *(const bf16x8*)&Bh[(nb + j * 16 + lm) * 40 + lq * 8];
            bl[j] = *(const bf16x8*)&Bl[(nb + j * 16 + lm) * 40 + lq * 8];
        }
#pragma unroll
        for (int i = 0; i < 4; ++i)
#pragma unroll
            for (int j = 0; j < 4; ++j)
                acc[i][j] = mfma3(ah[i], al[i], bh[j], bl[j], acc[i][j]);
        __syncthreads();
    }
#pragma unroll
    for (int i = 0; i < 4; ++i)
#pragma unroll
        for (int j = 0; j < 4; ++j) {
            int r0 = m0 + mb + i * 16 + lq * 4;
            int c  = n0 + nb + j * 16 + lm;
            int which = c >> 9, h = (c >> 6) & 7, d = c & 63;
            int b = r0 >> 12, nbase = r0 & 4095;
            if (which == 2) {
                unsigned short hh[4], ll[4];
#pragma unroll
                for (int e = 0; e < 4; ++e) split2(acc[i][j][e], hh[e], ll[e]);
                uint2 ph, pl;
                ph.x = (unsigned)hh[0] | ((unsigned)hh[1] << 16);
                ph.y = (unsigned)hh[2] | ((unsigned)hh[3] << 16);
                pl.x = (unsigned)ll[0] | ((unsigned)ll[1] << 16);
                pl.y = (unsigned)ll[2] | ((unsigned)ll[3] << 16);
                size_t off = ((size_t)(b * 8 + h) * 64 + d) * 4096 + nbase;
                *(uint2*)&vTh[off] = ph;
                *(uint2*)&vTl[off] = pl;
            } else {
                unsigned short* Ph = which ? kh : qh;
                unsigned short* Pl = which ? kl : ql;
                float sc = which ? 1.0f : 0.125f;
#pragma unroll
                for (int e = 0; e < 4; ++e) {
                    unsigned short hh, ll;
                    split2(acc[i][j][e] * sc, hh, ll);
                    size_t off = (size_t)(b * 8 + h) * 262144 +
                                 (size_t)(nbase + e) * 64 + d;
                    Ph[off] = hh;
                    Pl[off] = ll;
                }
            }
        }
}

// ---------------------------------------------------------------------------
// final MFMA GEMM: out[16384,512] = OH planes (gathered) @ w_out planes.
// grid (4,128).
// ---------------------------------------------------------------------------
__global__ __launch_bounds__(256) void mfma_final(
    const unsigned short* __restrict__ OHh, const unsigned short* __restrict__ OHl,
    const unsigned short* __restrict__ WTh, const unsigned short* __restrict__ WTl,
    float* __restrict__ out) {
    __shared__ unsigned short Ah[128 * 40], Al[128 * 40];
    __shared__ unsigned short Bh[128 * 40], Bl[128 * 40];
    const int t = threadIdx.x;
    const int wave = t >> 6, lane = t & 63, lm = lane & 15, lq = lane >> 4;
    // XCD-aware bijective swizzle: nwg=512, 512/8=64 per XCD
    int orig = blockIdx.y * 4 + blockIdx.x;
    int wg = (orig & 7) * 64 + (orig >> 3);
    const int m0 = (wg >> 2) * 128, n0 = (wg & 3) * 128;
    const int mb = (wave >> 1) * 64, nb = (wave & 1) * 64;
    f32x4 acc[4][4];
#pragma unroll
    for (int i = 0; i < 4; ++i)
#pragma unroll
        for (int j = 0; j < 4; ++j) acc[i][j] = (f32x4){0.f, 0.f, 0.f, 0.f};

    for (int kt = 0; kt < 512; kt += 32) {
#pragma unroll
        for (int r = 0; r < 2; ++r) {
            int id = t + r * 256, row = id >> 2, ko = (id & 3) * 8;
            int gr = m0 + row, b = gr >> 12, n = gr & 4095;
            int kk = kt + ko;
            size_t off = (size_t)(b * 8 + (kk >> 6)) * 262144 +
                         (size_t)n * 64 + (kk & 63);
            *(uint4*)&Ah[row * 40 + ko] = *(const uint4*)(OHh + off);
            *(uint4*)&Al[row * 40 + ko] = *(const uint4*)(OHl + off);
        }
#pragma unroll
        for (int r = 0; r < 2; ++r) {
            int id = t + r * 256, row = id >> 2, ko = (id & 3) * 8;
            *(uint4*)&Bh[row * 40 + ko] =
                *(const uint4*)(WTh + (size_t)(n0 + row) * 512 + kt + ko);
            *(uint4*)&Bl[row * 40 + ko] =
                *(const uint4*)(WTl + (size_t)(n0 + row) * 512 + kt + ko);
        }
        __syncthreads();
        bf16x8 ah[4], al[4], bh[4], bl[4];
#pragma unroll
        for (int i = 0; i < 4; ++i) {
            ah[i] = *(const bf16x8*)&Ah[(mb + i * 16 + lm) * 40 + lq * 8];
            al[i] = *(const bf16x8*)&Al[(mb + i * 16 + lm) * 40 + lq * 8];
        }
#pragma unroll
        for (int j = 0; j < 4; ++j) {
            bh[j] = *(const bf16x8*)&Bh[(nb + j * 16 + lm) * 40 + lq * 8];
            bl[j] = *(const bf16x8*)&Bl[(nb + j * 16 + lm) * 40 + lq * 8];
        }
#pragma unroll
        for (int i = 0; i < 4; ++i)
#pragma unroll
            for (int j = 0; j < 4; ++j)
                acc[i][j] = mfma3(ah[i], al[i], bh[j], bl[j], acc[i][j]);
        __syncthreads();
    }
#pragma unroll
    for (int i = 0; i < 4; ++i)
#pragma unroll
        for (int j = 0; j < 4; ++j) {
            int r0 = m0 + mb + i * 16 + lq * 4;
            int c  = n0 + nb + j * 16 + lm;
#pragma unroll
            for (int e = 0; e < 4; ++e)
                out[(size_t)(r0 + e) * 512 + c] = acc[i][j][e];
        }
}

// ---------------------------------------------------------------------------
// F3 MFMA: t1 += exp(qland@k^T)@v, rs3 += rowsums. grid (8, 4, 32).
// ---------------------------------------------------------------------------
__global__ __launch_bounds__(256) void attn3v_mfma(
    const unsigned short* __restrict__ qlh, const unsigned short* __restrict__ qll,
    const unsigned short* __restrict__ kh_, const unsigned short* __restrict__ kl_,
    const unsigned short* __restrict__ vTh, const unsigned short* __restrict__ vTl,
    float* __restrict__ t1, float* __restrict__ rs3) {
    __shared__ unsigned short Qh[4608], Ql[4608];
    __shared__ unsigned short Kh[4608], Kl[4608];
    __shared__ unsigned short Eh[4608], El[4608];
    const int t = threadIdx.x;
    const int wave = t >> 6, lane = t & 63, lm = lane & 15, lq = lane >> 4;
    const int bz = blockIdx.z, m0 = blockIdx.y * 64, c0 = blockIdx.x * 8;
    const unsigned short* qhb = qlh + (size_t)bz * 16384;
    const unsigned short* qlb = qll + (size_t)bz * 16384;
    const unsigned short* khb = kh_ + (size_t)bz * 262144;
    const unsigned short* klb = kl_ + (size_t)bz * 262144;
    const unsigned short* vhb = vTh + (size_t)bz * 262144;
    const unsigned short* vlb = vTl + (size_t)bz * 262144;
#pragma unroll
    for (int r = 0; r < 2; ++r) {
        int id = t + r * 256, row = id >> 3, ko = (id & 7) * 8;
        *(uint4*)&Qh[row * 72 + ko] =
            *(const uint4*)(qhb + (size_t)(m0 + row) * 64 + ko);
        *(uint4*)&Ql[row * 72 + ko] =
            *(const uint4*)(qlb + (size_t)(m0 + row) * 64 + ko);
    }
    f32x4 acc[4];
#pragma unroll
    for (int j = 0; j < 4; ++j) acc[j] = (f32x4){0.f, 0.f, 0.f, 0.f};
    float rsum[4] = {0.f, 0.f, 0.f, 0.f};
    __syncthreads();

    for (int c = c0; c < c0 + 8; ++c) {
        const int tok0 = c * 64;
#pragma unroll
        for (int r = 0; r < 2; ++r) {
            int id = t + r * 256, row = id >> 3, ko = (id & 7) * 8;
            *(uint4*)&Kh[row * 72 + ko] =
                *(const uint4*)(khb + (size_t)(tok0 + row) * 64 + ko);
            *(uint4*)&Kl[row * 72 + ko] =
                *(const uint4*)(klb + (size_t)(tok0 + row) * 64 + ko);
        }
        __syncthreads();
        bf16x8 a0  = *(const bf16x8*)&Qh[(wave * 16 + lm) * 72 + lq * 8];
        bf16x8 a0l = *(const bf16x8*)&Ql[(wave * 16 + lm) * 72 + lq * 8];
        bf16x8 a1  = *(const bf16x8*)&Qh[(wave * 16 + lm) * 72 + 32 + lq * 8];
        bf16x8 a1l = *(const bf16x8*)&Ql[(wave * 16 + lm) * 72 + 32 + lq * 8];
        f32x4 s[4];
#pragma unroll
        for (int j = 0; j < 4; ++j) s[j] = (f32x4){0.f, 0.f, 0.f, 0.f};
#pragma unroll
        for (int j = 0; j < 4; ++j) {
            bf16x8 b0  = *(const bf16x8*)&Kh[(j * 16 + lm) * 72 + lq * 8];
            bf16x8 b0l = *(const bf16x8*)&Kl[(j * 16 + lm) * 72 + lq * 8];
            bf16x8 b1  = *(const bf16x8*)&Kh[(j * 16 + lm) * 72 + 32 + lq * 8];
            bf16x8 b1l = *(const bf16x8*)&Kl[(j * 16 + lm) * 72 + 32 + lq * 8];
            s[j] = mfma3(a0, a0l, b0, b0l, s[j]);
            s[j] = mfma3(a1, a1l, b1, b1l, s[j]);
        }
        __syncthreads();
#pragma unroll
        for (int j = 0; j < 4; ++j)
#pragma unroll
            for (int e = 0; e < 4; ++e) {
                float ev = __expf(s[j][e]);
                rsum[e] += ev;
                unsigned short h, l;
                split2(ev, h, l);
                int off = (wave * 16 + lq * 4 + e) * 72 + j * 16 + lm;
                Eh[off] = h;
                El[off] = l;
            }
#pragma unroll
        for (int r = 0; r < 2; ++r) {
            int id = t + r * 256, dh = id >> 3, t8 = (id & 7) * 8;
            *(uint4*)&Kh[dh * 72 + t8] =
                *(const uint4*)(vhb + (size_t)dh * 4096 + tok0 + t8);
            *(uint4*)&Kl[dh * 72 + t8] =
                *(const uint4*)(vlb + (size_t)dh * 4096 + tok0 + t8);
        }
        __syncthreads();
        bf16x8 e0  = *(const bf16x8*)&Eh[(wave * 16 + lm) * 72 + lq * 8];
        bf16x8 e0l = *(const bf16x8*)&El[(wave * 16 + lm) * 72 + lq * 8];
        bf16x8 e1  = *(const bf16x8*)&Eh[(wave * 16 + lm) * 72 + 32 + lq * 8];
        bf16x8 e1l = *(const bf16x8*)&El[(wave * 16 + lm) * 72 + 32 + lq * 8];
#pragma unroll
        for (int j = 0; j < 4; ++j) {
            bf16x8 v0  = *(const bf16x8*)&Kh[(j * 16 + lm) * 72 + lq * 8];
            bf16x8 v0l = *(const bf16x8*)&Kl[(j * 16 + lm) * 72 + lq * 8];
            bf16x8 v1  = *(const bf16x8*)&Kh[(j * 16 + lm) * 72 + 32 + lq * 8];
            bf16x8 v1l = *(const bf16x8*)&Kl[(j * 16 + lm) * 72 + 32 + lq * 8];
            acc[j] = mfma3(e0, e0l, v0, v0l, acc[j]);
            acc[j] = mfma3(e1, e1l, v1, v1l, acc[j]);
        }
        __syncthreads();
    }
    float* t1b = t1 + (size_t)bz * 16384;
#pragma unroll
    for (int j = 0; j < 4; ++j)
#pragma unroll
        for (int e = 0; e < 4; ++e)
            atomicAdd(t1b + (size_t)(m0 + wave * 16 + lq * 4 + e) * 64 +
                          j * 16 + lm,
                      acc[j][e]);
#pragma unroll
    for (int e = 0; e < 4; ++e) {
        float vs = rsum[e];
        for (int mm = 1; mm < 16; mm <<= 1) vs += __shfl_xor(vs, mm);
        if (lm == 0)
            atomicAdd(rs3 + bz * 256 + m0 + wave * 16 + lq * 4 + e, vs);
    }
}

// ---------------------------------------------------------------------------
// F1 MFMA: oh = softmax(q@kland^T) @ t2 (normalized). t2 planes stride 16384.
// grid (64, 32).
// ---------------------------------------------------------------------------
__global__ __launch_bounds__(256) void attn1t2_mfma(
    const unsigned short* __restrict__ qh_, const unsigned short* __restrict__ ql_,
    const unsigned short* __restrict__ klh, const unsigned short* __restrict__ kll,
    const unsigned short* __restrict__ t2Th,
    const unsigned short* __restrict__ t2Tl, float* __restrict__ oh) {
    __shared__ unsigned short Qh[4608], Ql[4608];
    __shared__ unsigned short Kh[4608], Kl[4608];
    __shared__ unsigned short Eh[4608], El[4608];
    const int t = threadIdx.x;
    const int wave = t >> 6, lane = t & 63, lm = lane & 15, lq = lane >> 4;
    const int bz = blockIdx.y, m0 = blockIdx.x * 64;
    const unsigned short* qhb = qh_ + (size_t)bz * 262144;
    const unsigned short* qlb = ql_ + (size_t)bz * 262144;
    const unsigned short* khb = klh + (size_t)bz * 16384;
    const unsigned short* klb = kll + (size_t)bz * 16384;
    const unsigned short* t2h = t2Th + (size_t)bz * 16384;
    const unsigned short* t2l = t2Tl + (size_t)bz * 16384;
#pragma unroll
    for (int r = 0; r < 2; ++r) {
        int id = t + r * 256, row = id >> 3, ko = (id & 7) * 8;
        *(uint4*)&Qh[row * 72 + ko] =
            *(const uint4*)(qhb + (size_t)(m0 + row) * 64 + ko);
        *(uint4*)&Ql[row * 72 + ko] =
            *(const uint4*)(qlb + (size_t)(m0 + row) * 64 + ko);
    }
    f32x4 acc[4];
#pragma unroll
    for (int j = 0; j < 4; ++j) acc[j] = (f32x4){0.f, 0.f, 0.f, 0.f};
    float rsum[4] = {0.f, 0.f, 0.f, 0.f};
    __syncthreads();

    for (int lc = 0; lc < 4; ++lc) {
        const int l0 = lc * 64;
#pragma unroll
        for (int r = 0; r < 2; ++r) {
            int id = t + r * 256, row = id >> 3, ko = (id & 7) * 8;
            *(uint4*)&Kh[row * 72 + ko] =
                *(const uint4*)(khb + (size_t)(l0 + row) * 64 + ko);
            *(uint4*)&Kl[row * 72 + ko] =
                *(const uint4*)(klb + (size_t)(l0 + row) * 64 + ko);
        }
        __syncthreads();
        bf16x8 a0  = *(const bf16x8*)&Qh[(wave * 16 + lm) * 72 + lq * 8];
        bf16x8 a0l = *(const bf16x8*)&Ql[(wave * 16 + lm) * 72 + lq * 8];
        bf16x8 a1  = *(const bf16x8*)&Qh[(wave * 16 + lm) * 72 + 32 + lq * 8];
        bf16x8 a1l = *(const bf16x8*)&Ql[(wave * 16 + lm) * 72 + 32 + lq * 8];
        f32x4 s[4];
#pragma unroll
        for (int j = 0; j < 4; ++j) s[j] = (f32x4){0.f, 0.f, 0.f, 0.f};
#pragma unroll
        for (int j = 0; j < 4; ++j) {
            bf16x8 b0  = *(const bf16x8*)&Kh[(j * 16 + lm) * 72 + lq * 8];
            bf16x8 b0l = *(const bf16x8*)&Kl[(j * 16 + lm) * 72 + lq * 8];
            bf16x8 b1  = *(const bf16x8*)&Kh[(j * 16 + lm) * 72 + 32 + lq * 8];
            bf16x8 b1l = *(const bf16x8*)&Kl[(j * 16 + lm) * 72 + 32 + lq * 8];
            s[j] = mfma3(a0, a0l, b0, b0l, s[j]);
            s[j] = mfma3(a1, a1l, b1, b1l, s[j]);
        }
        __syncthreads();
#pragma unroll
        for (int j = 0; j < 4; ++j)
#pragma unroll
            for (int e = 0; e < 4; ++e) {
                float ev = __expf(s[j][e]);
                rsum[e] += ev;
                unsigned short h, l;
                split2(ev, h, l);
                int off = (wave * 16 + lq * 4 + e) * 72 + j * 16 + lm;
                Eh[off] = h;
                El[off] = l;
            }
#pragma unroll
        for (int r = 0; r < 2; ++r) {
            int id = t + r * 256, dh = id >> 3, t8 = (id & 7) * 8;
            *(uint4*)&Kh[dh * 72 + t8] =
                *(const uint4*)(t2h + (size_t)dh * 256 + l0 + t8);
            *(uint4*)&Kl[dh * 72 + t8] =
                *(const uint4*)(t2l + (size_t)dh * 256 + l0 + t8);
        }
        __syncthreads();
        bf16x8 e0  = *(const bf16x8*)&Eh[(wave * 16 + lm) * 72 + lq * 8];
        bf16x8 e0l = *(const bf16x8*)&El[(wave * 16 + lm) * 72 + lq * 8];
        bf16x8 e1  = *(const bf16x8*)&Eh[(wave * 16 + lm) * 72 + 32 + lq * 8];
        bf16x8 e1l = *(const bf16x8*)&El[(wave * 16 + lm) * 72 + 32 + lq * 8];
#pragma unroll
        for (int j = 0; j < 4; ++j) {
            bf16x8 v0  = *(const bf16x8*)&Kh[(j * 16 + lm) * 72 + lq * 8];
            bf16x8 v0l = *(const bf16x8*)&Kl[(j * 16 + lm) * 72 + lq * 8];
            bf16x8 v1  = *(const bf16x8*)&Kh[(j * 16 + lm) * 72 + 32 + lq * 8];
            bf16x8 v1l = *(const bf16x8*)&Kl[(j * 16 + lm) * 72 + 32 + lq * 8];
            acc[j] = mfma3(e0, e0l, v0, v0l, acc[j]);
            acc[j] = mfma3(e1, e1l, v1, v1l, acc[j]);
        }
        __syncthreads();
    }
    float rinv[4];
#pragma unroll
    for (int e = 0; e < 4; ++e) {
        float vs = rsum[e];
        for (int mm = 1; mm < 16; mm <<= 1) vs += __shfl_xor(vs, mm);
        rinv[e] = 1.0f / vs;
    }
    float* ohb = oh + (size_t)bz * 262144;
#pragma unroll
    for (int j = 0; j < 4; ++j)
#pragma unroll
        for (int e = 0; e < 4; ++e)
            ohb[(size_t)(m0 + wave * 16 + lq * 4 + e) * 64 + j * 16 + lm] =
                acc[j][e] * rinv[e];
}

// ---------------------------------------------------------------------------
// weight transpose+split: W[512][N] -> planes T[N][512]
// ---------------------------------------------------------------------------
__global__ void wtrans(const float* __restrict__ W, int N,
                       unsigned short* __restrict__ Th,
                       unsigned short* __restrict__ Tl) {
    int idx = blockIdx.x * 256 + threadIdx.x;
    int n = idx >> 9, kk = idx & 511;
    float x = W[(size_t)kk * N + n];
    unsigned short h, l;
    split2(x, h, l);
    Th[idx] = h;
    Tl[idx] = l;
}

// ---------------------------------------------------------------------------
// fp32 gemm for attn2 (TRANSB)
// ---------------------------------------------------------------------------
__global__ __launch_bounds__(256) void gemm_a2(
    const float* __restrict__ A, const float* __restrict__ B,
    float* __restrict__ C) {
    __shared__ float As[16 * 68];
    __shared__ float Bs[16 * 68];
    const int t  = threadIdx.x;
    const int z  = blockIdx.z;
    const int m0 = blockIdx.y * 64;
    const int n0 = blockIdx.x * 64;
    const float* Ab = A + (size_t)z * 16384;
    const float* Bb = B + (size_t)z * 16384;
    float*       Cb = C + (size_t)z * 65536;
    const int tx4 = (t & 15) * 4;
    const int ty4 = (t >> 4) * 4;
    const int ar  = t >> 2, ak = (t & 3) * 4;
    float acc[4][4] = {};
    for (int kt = 0; kt < 64; kt += 16) {
        float4 av = *(const float4*)(Ab + (size_t)(m0 + ar) * 64 + kt + ak);
        float4 bv = *(const float4*)(Bb + (size_t)(n0 + ar) * 64 + kt + ak);
        As[(ak + 0) * 68 + ar] = av.x;
        As[(ak + 1) * 68 + ar] = av.y;
        As[(ak + 2) * 68 + ar] = av.z;
        As[(ak + 3) * 68 + ar] = av.w;
        Bs[(ak + 0) * 68 + ar] = bv.x;
        Bs[(ak + 1) * 68 + ar] = bv.y;
        Bs[(ak + 2) * 68 + ar] = bv.z;
        Bs[(ak + 3) * 68 + ar] = bv.w;
        __syncthreads();
        mt16(As, Bs, ty4, tx4, acc);
        __syncthreads();
    }
#pragma unroll
    for (int u = 0; u < 4; ++u) {
        int row = m0 + ty4 + u;
        *(float4*)(Cb + (size_t)row * 256 + n0 + tx4) =
            make_float4(acc[u][0], acc[u][1], acc[u][2], acc[u][3]);
    }
}

// ---------------------------------------------------------------------------
// small kernels
// ---------------------------------------------------------------------------
__global__ void zero_f(float* __restrict__ p, int n) {
    int i = blockIdx.x * 256 + threadIdx.x;
    if (i < n) p[i] = 0.f;
}

// landmark mean from split planes; emits fp32 + split planes
__global__ void landmark_mean_p(const unsigned short* __restrict__ sh,
                                const unsigned short* __restrict__ sl,
                                float* __restrict__ dst,
                                unsigned short* __restrict__ dh,
                                unsigned short* __restrict__ dl) {
    int o = blockIdx.x * 256 + threadIdx.x;
    int d = o & 63, m = (o >> 6) & 255, bh = o >> 14;
    size_t base = (size_t)bh * 262144 + (size_t)m * 1024 + d;
    float acc = 0.f;
#pragma unroll
    for (int j = 0; j < 16; ++j)
        acc += b2f(sh[base + j * 64]) + b2f(sl[base + j * 64]);
    float v = acc * (1.0f / 16.0f);
    dst[o] = v;
    unsigned short h, l;
    split2(v, h, l);
    dh[o] = h;
    dl[o] = l;
}

__global__ void softmax_rows(float* __restrict__ a) {
    __shared__ float red[256];
    int row = blockIdx.x, t = threadIdx.x;
    float v = a[(size_t)row * 256 + t];
    red[t] = v;
    __syncthreads();
    for (int s = 128; s > 0; s >>= 1) {
        if (t < s) red[t] = fmaxf(red[t], red[t + s]);
        __syncthreads();
    }
    float mx = red[0];
    __syncthreads();
    float e = __expf(v - mx);
    red[t] = e;
    __syncthreads();
    for (int s = 128; s > 0; s >>= 1) {
        if (t < s) red[t] += red[t + s];
        __syncthreads();
    }
    a[(size_t)row * 256 + t] = e / red[0];
}

__global__ __launch_bounds__(256) void scalar_prep(const float* __restrict__ a,
                                                   float* __restrict__ scal) {
    __shared__ float red[256];
    int bh = blockIdx.x, t = threadIdx.x;
    const float* ab = a + (size_t)bh * 65536;
    float cs = 0.f;
    for (int i = 0; i < 256; ++i) cs += ab[i * 256 + t];
    red[t] = cs;
    __syncthreads();
    for (int s = 128; s > 0; s >>= 1) {
        if (t < s) red[t] = fmaxf(red[t], red[t + s]);
        __syncthreads();
    }
    float mcol = red[0];
    __syncthreads();
    float rs = 0.f;
    for (int j = 0; j < 256; ++j) rs += ab[t * 256 + j];
    red[t] = rs;
    __syncthreads();
    for (int s = 128; s > 0; s >>= 1) {
        if (t < s) red[t] = fmaxf(red[t], red[t + s]);
        __syncthreads();
    }
    if (t == 0) {
        atomicMax((unsigned int*)&scal[0], __float_as_uint(mcol));
        atomicMax((unsigned int*)&scal[1], __float_as_uint(red[0]));
    }
}

// ---------------------------------------------------------------------------
// LDS-tiled depthwise conv reading vT planes; emits OH planes (oh + conv).
// grid (32 tiles, 32 bh).
// ---------------------------------------------------------------------------
__global__ __launch_bounds__(256) void conv_tiled(
    const float* __restrict__ ohin, const unsigned short* __restrict__ vTh,
    const unsigned short* __restrict__ vTl, const float* __restrict__ wres,
    unsigned short* __restrict__ OHh, unsigned short* __restrict__ OHl) {
    __shared__ float Vs[160 * 65];
    __shared__ float Ws[33];
    const int t = threadIdx.x;
    const int bh = blockIdx.y;
    const int n0 = blockIdx.x * 128;
    const int h = bh & 7;
    if (t < 33) Ws[t] = wres[h * 33 + t];
    const unsigned short* vhb = vTh + (size_t)bh * 262144;
    const unsigned short* vlb = vTl + (size_t)bh * 262144;
#pragma unroll
    for (int r = 0; r < 5; ++r) {
        int id = t + r * 256;               // 0..1279: 64 dh x 20 chunks of 8
        int d = id / 20, ch = id - d * 20;
        int n = n0 - 16 + ch * 8;
        uint4 h4 = make_uint4(0u, 0u, 0u, 0u);
        uint4 l4 = make_uint4(0u, 0u, 0u, 0u);
        if ((unsigned)n < 4096u) {
            h4 = *(const uint4*)(vhb + (size_t)d * 4096 + n);
            l4 = *(const uint4*)(vlb + (size_t)d * 4096 + n);
        }
        const unsigned short* hp = (const unsigned short*)&h4;
        const unsigned short* lp = (const unsigned short*)&l4;
        int row0 = ch * 8;
#pragma unroll
        for (int i = 0; i < 8; ++i)
            Vs[(row0 + i) * 65 + d] = b2f(hp[i]) + b2f(lp[i]);
    }
    __syncthreads();
    const int d = t & 63;
    const int g0 = (t >> 6) * 32;
    const float* ohb = ohin + (size_t)bh * 262144 + (size_t)n0 * 64;
    unsigned short* Hh = OHh + (size_t)bh * 262144 + (size_t)n0 * 64;
    unsigned short* Hl = OHl + (size_t)bh * 262144 + (size_t)n0 * 64;
    float w[33];
#pragma unroll
    for (int j = 0; j < 33; ++j) w[j] = Vs[(g0 + j) * 65 + d];
#pragma unroll
    for (int i = 0; i < 32; ++i) {
        float acc = ohb[(size_t)(g0 + i) * 64 + d];
#pragma unroll
        for (int tt = 0; tt < 33; ++tt) acc += w[tt] * Ws[tt];
        unsigned short hh, ll;
        split2(acc, hh, ll);
        Hh[(size_t)(g0 + i) * 64 + d] = hh;
        Hl[(size_t)(g0 + i) * 64 + d] = ll;
        if (i < 31) {
#pragma unroll
            for (int j = 0; j < 32; ++j) w[j] = w[j + 1];
            w[32] = Vs[(g0 + i + 33) * 65 + d];
        }
    }
}

// ---------------------------------------------------------------------------
extern "C" void kernel_launch(void* const* d_in, const int* in_sizes, int n_in,
                              void* d_out, int out_size, void* d_ws, size_t ws_size,
                              hipStream_t stream) {
    const float* x     = (const float*)d_in[0];
    const float* w_qkv = (const float*)d_in[1];
    const float* w_out = (const float*)d_in[2];
    const float* w_res = (const float*)d_in[3];
    float* out = (float*)d_out;
    float* ws  = (float*)d_ws;

    // planes (ushort units)
    unsigned short* Xh  = (unsigned short*)(ws + O_XP);
    unsigned short* Xl  = Xh + 8388608;
    unsigned short* qh  = (unsigned short*)(ws + O_QP);
    unsigned short* ql  = qh + 8388608;
    unsigned short* kh  = (unsigned short*)(ws + O_KP);
    unsigned short* kl  = kh + 8388608;
    unsigned short* vTh = (unsigned short*)(ws + O_VT);
    unsigned short* vTl = vTh + 8388608;
    unsigned short* qlh = (unsigned short*)(ws + O_QLP);
    unsigned short* qll = qlh + 524288;
    unsigned short* klh = (unsigned short*)(ws + O_KLP);
    unsigned short* kll = klh + 524288;

    float* qland = ws + O_QL;
    float* kland = ws + O_KL;
    float* attn2 = ws + O_A2;
    float* t1    = ws + O_T1;
    float* rs3   = ws + O_RS3;
    float* scal  = ws + O_SCAL;
    float* t2    = ws + O_T2;

    // pinv plane pool A: k-plane region (dead after attn3v), 8 planes
    unsigned short* PBu  = (unsigned short*)(ws + O_KP);
    unsigned short* A2Ph = PBu + 0;
    unsigned short* A2Pl = PBu + 2097152;
    unsigned short* XZNh = PBu + 4194304;
    unsigned short* XZNl = PBu + 6291456;
    unsigned short* XZTh = PBu + 8388608;
    unsigned short* XZTl = PBu + 10485760;
    unsigned short* Y1Th = PBu + 12582912;
    unsigned short* Y1Tl = PBu + 14680064;
    // pinv plane pool B: X-plane region (dead after qkv), 8 planes
    unsigned short* XRu  = (unsigned short*)(ws + O_XP);
    unsigned short* ZNah = XRu + 0;
    unsigned short* ZNal = XRu + 2097152;
    unsigned short* ZNbh = XRu + 4194304;
    unsigned short* ZNbl = XRu + 6291456;
    unsigned short* ZTh_ = XRu + 8388608;
    unsigned short* ZTl_ = XRu + 10485760;
    unsigned short* Y2Th = XRu + 12582912;
    unsigned short* Y2Tl = XRu + 14680064;
    // post-pinv aliases
    unsigned short* t2Th = PBu;                 // A2P dead after last xz
    unsigned short* t2Tl = PBu + 524288;
    float* ohf = ws + O_XP;                     // pool B dead after t2
    unsigned short* OHh = PBu;                  // t2T consumed by attn1t2
    unsigned short* OHl = PBu + 8388608;

    unsigned short* WQTh = (unsigned short*)(ws + O_WQT);
    unsigned short* WQTl = WQTh + 786432;
    unsigned short* WOTh = (unsigned short*)(ws + O_WOT);
    unsigned short* WOTl = WOTh + 262144;

    zero_f<<<2081, 256, 0, stream>>>(t1, 532496);   // t1+rs3+scal
    wtrans<<<3072, 256, 0, stream>>>(w_qkv, 1536, WQTh, WQTl);
    wtrans<<<1024, 256, 0, stream>>>(w_out, 512, WOTh, WOTl);
    xsplit<<<8192, 256, 0, stream>>>(x, Xh, Xl);

    mfma_qkv<<<dim3(12, 128), 256, 0, stream>>>(Xh, Xl, WQTh, WQTl,
                                                qh, ql, kh, kl, vTh, vTl);

    landmark_mean_p<<<2048, 256, 0, stream>>>(qh, ql, qland, qlh, qll);
    landmark_mean_p<<<2048, 256, 0, stream>>>(kh, kl, kland, klh, kll);

    gemm_a2<<<dim3(4, 4, 32), 256, 0, stream>>>(qland, kland, attn2);
    softmax_rows<<<8192, 256, 0, stream>>>(attn2);
    scalar_prep<<<32, 256, 0, stream>>>(attn2, scal);

    // F3 before pinv (k and vT planes consumed here; k planes die here)
    attn3v_mfma<<<dim3(8, 4, 32), 256, 0, stream>>>(qlh, qll, kh, kl,
                                                    vTh, vTl, t1, rs3);

    // pinv: pre-split attn2 planes; z0 normal planes; 6x4 all-plane stages.
    xsplit<<<2048, 256, 0, stream>>>(attn2, A2Ph, A2Pl);
    zinit_n<<<8192, 256, 0, stream>>>(attn2, scal, ZNah, ZNal);

    unsigned short* ZNh[2] = {ZNah, ZNbh};
    unsigned short* ZNl[2] = {ZNal, ZNbl};
    int cur = 0;
    const dim3 pg(4, 4, 32);
    for (int it = 0; it < 6; ++it) {
        if (it == 0) {
            // xz = (1/denom) * (a2 @ a2^T): B planes = a2 normal planes
            mfma_gemm_p<0, true, true, true><<<pg, 256, 0, stream>>>(
                A2Ph, A2Pl, A2Ph, A2Pl, XZNh, XZNl, XZTh, XZTl,
                0.f, 0.f, scal);
        } else {
            mfma_gemm_p<0, false, true, true><<<pg, 256, 0, stream>>>(
                A2Ph, A2Pl, ZTh_, ZTl_, XZNh, XZNl, XZTh, XZTl,
                1.f, 0.f, nullptr);
        }
        // Y1 = -xz@xz + 7*xz
        mfma_gemm_p<1, false, false, true><<<pg, 256, 0, stream>>>(
            XZNh, XZNl, XZTh, XZTl, nullptr, nullptr, Y1Th, Y1Tl,
            -1.f, 7.f, nullptr);
        // Y2 = -xz@Y1 + 15*xz
        mfma_gemm_p<1, false, false, true><<<pg, 256, 0, stream>>>(
            XZNh, XZNl, Y1Th, Y1Tl, nullptr, nullptr, Y2Th, Y2Tl,
            -1.f, 15.f, nullptr);
        // z' = -0.25*z@Y2 + 3.25*z
        mfma_gemm_p<1, false, true, true><<<pg, 256, 0, stream>>>(
            ZNh[cur], ZNl[cur], Y2Th, Y2Tl, ZNh[1 - cur], ZNl[1 - cur],
            ZTh_, ZTl_, -0.25f, 3.25f, nullptr);
        cur = 1 - cur;
    }
    // zfin = ZN[cur] (cur back to 0 after 6 iters)

    // t2 = zfin @ (t1 / rs3); emits t2^T planes (stride 16384/z)
    t2_gemm<<<dim3(1, 4, 32), 256, 0, stream>>>(ZNh[cur], ZNl[cur], t1, rs3,
                                                t2, t2Th, t2Tl);

    // F1: oh = softmax(q@kland^T)@t2 -> ohf (pool-B region, now dead)
    attn1t2_mfma<<<dim3(64, 32), 256, 0, stream>>>(qh, ql, klh, kll,
                                                   t2Th, t2Tl, ohf);

    // OH planes = oh + depthwise conv(v), from vT planes
    conv_tiled<<<dim3(32, 32), 256, 0, stream>>>(ohf, vTh, vTl, w_res,
                                                 OHh, OHl);

    mfma_final<<<dim3(4, 128), 256, 0, stream>>>(OHh, OHl, WOTh, WOTl, out);

    (void)in_sizes; (void)n_in; (void)out_size; (void)ws_size;
}

// Round 5
// 834.688 us; speedup vs baseline: 1.4972x; 1.0079x over previous
//
#include <hip/hip_runtime.h>

// ---------------------------------------------------------------------------
// Nystrom attention: split-bf16 (hi/lo, 3xMFMA) everywhere.
// R10: fusion package. softmax emits a2 normal+transposed planes + colsum
// atomics (kills zinit + a2split + scalar_prep second pass); iter-1 stage-4
// reads a2^T planes with runtime 1/denom (SC=2); conv fused into attn1t2
// (ohf fp32 round-trip gone); wtrans and landmark_mean merged; attn3v moved
// before softmax. 40 -> 33 dispatches.
// B=4, N=4096, DIM=512, H=8, DH=64, M=256, l=16, 6 pinv iters, conv K=33.
// ---------------------------------------------------------------------------

typedef __attribute__((ext_vector_type(8))) short bf16x8;
typedef __attribute__((ext_vector_type(4))) float f32x4;

// workspace layout (float units)
constexpr size_t O_XP  = 0;          // Xh/Xl planes; later pool B (ZN/ZT/Y2T, A2T)
constexpr size_t O_QP  = 8388608;    // q planes (hi/lo)
constexpr size_t O_KP  = 16777216;   // k planes; later pool A (A2P/XZN/XZT/Y1T); later OH planes
constexpr size_t O_VT  = 25165824;   // vT planes
constexpr size_t O_QL  = 33554432;   // qland fp32; later t2T planes
constexpr size_t O_KL  = 34078720;   // kland fp32
constexpr size_t O_QLP = 34603008;   // qland planes
constexpr size_t O_KLP = 35127296;   // kland planes
constexpr size_t O_A2  = 35651584;   // attn2 fp32 (pre-softmax scores)
constexpr size_t O_T1  = 37748736;
constexpr size_t O_RS3 = 38273024;
constexpr size_t O_SCAL= 38281216;
constexpr size_t O_CS  = 38281232;   // colsum [32][256]
constexpr size_t O_WQT = 38805520;
constexpr size_t O_WOT = 39591952;
constexpr size_t O_END = 39854096;   // ~159.4 MB

// ---------------------------------------------------------------------------
__device__ __forceinline__ void split2(float x, unsigned short& h,
                                       unsigned short& l) {
    unsigned u  = __float_as_uint(x);
    unsigned hb = (u + 0x7FFFu + ((u >> 16) & 1u)) & 0xFFFF0000u;  // RNE hi
    h = (unsigned short)(hb >> 16);
    float d = x - __uint_as_float(hb);
    l = (unsigned short)(__float_as_uint(d) >> 16);
}

__device__ __forceinline__ float b2f(unsigned short s) {
    return __uint_as_float((unsigned)s << 16);
}

__device__ __forceinline__ f32x4 mfma3(bf16x8 ah, bf16x8 al, bf16x8 bh,
                                       bf16x8 bl, f32x4 c) {
    c = __builtin_amdgcn_mfma_f32_16x16x32_bf16(ah, bh, c, 0, 0, 0);
    c = __builtin_amdgcn_mfma_f32_16x16x32_bf16(ah, bl, c, 0, 0, 0);
    c = __builtin_amdgcn_mfma_f32_16x16x32_bf16(al, bh, c, 0, 0, 0);
    return c;
}

// split a float4 into hi/lo planes, write packed uint2 at H[off], L[off]
__device__ __forceinline__ void stage_split4(float4 av, unsigned short* H,
                                             unsigned short* L, int off) {
    unsigned short h0, h1, h2, h3, l0, l1, l2, l3;
    split2(av.x, h0, l0); split2(av.y, h1, l1);
    split2(av.z, h2, l2); split2(av.w, h3, l3);
    uint2 ph, pl;
    ph.x = (unsigned)h0 | ((unsigned)h1 << 16);
    ph.y = (unsigned)h2 | ((unsigned)h3 << 16);
    pl.x = (unsigned)l0 | ((unsigned)l1 << 16);
    pl.y = (unsigned)l2 | ((unsigned)l3 << 16);
    *(uint2*)&H[off] = ph;
    *(uint2*)&L[off] = pl;
}

// ---------------------------------------------------------------------------
// X -> split planes (one-time)
// ---------------------------------------------------------------------------
__global__ void xsplit(const float* __restrict__ X,
                       unsigned short* __restrict__ Xh,
                       unsigned short* __restrict__ Xl) {
    int idx = blockIdx.x * 256 + threadIdx.x;
    float4 v = *(const float4*)(X + (size_t)idx * 4);
    stage_split4(v, Xh, Xl, idx * 4);
}

// ---------------------------------------------------------------------------
// both weight transposes in one dispatch. grid 4096.
// ---------------------------------------------------------------------------
__global__ void wtrans2(const float* __restrict__ Wq,
                        const float* __restrict__ Wo,
                        unsigned short* __restrict__ QTh,
                        unsigned short* __restrict__ QTl,
                        unsigned short* __restrict__ OTh,
                        unsigned short* __restrict__ OTl) {
    int idx = blockIdx.x * 256 + threadIdx.x;
    unsigned short h, l;
    if (idx < 786432) {
        int n = idx >> 9, kk = idx & 511;
        split2(Wq[(size_t)kk * 1536 + n], h, l);
        QTh[idx] = h;
        QTl[idx] = l;
    } else {
        int j = idx - 786432;
        int n = j >> 9, kk = j & 511;
        split2(Wo[(size_t)kk * 512 + n], h, l);
        OTh[j] = h;
        OTl[j] = l;
    }
}

// ---------------------------------------------------------------------------
// All-plane pinv GEMM stage: C = alpha*(A@B) + beta*A_elem.
// SC=0: as-is. SC=1: alpha := 1/denom (EPI=0). SC=2: whole result *= 1/denom.
// A = normal planes AN[m][k]; B = transposed planes BT[n][k].
// grid (4,4,32), 64x64 tile, 256 threads.
// ---------------------------------------------------------------------------
template <int EPI, int SC, bool WN, bool WTT>
__global__ __launch_bounds__(256) void mfma_gemm_p(
    const unsigned short* __restrict__ ANh, const unsigned short* __restrict__ ANl,
    const unsigned short* __restrict__ BTh, const unsigned short* __restrict__ BTl,
    unsigned short* __restrict__ CNh, unsigned short* __restrict__ CNl,
    unsigned short* __restrict__ CTh, unsigned short* __restrict__ CTl,
    float alpha, float beta, const float* __restrict__ scal) {
    __shared__ unsigned short Ah[64 * 40], Al[64 * 40];
    __shared__ unsigned short Bh[64 * 40], Bl[64 * 40];
    const int t = threadIdx.x;
    const int wave = t >> 6, lane = t & 63, lm = lane & 15, lq = lane >> 4;
    const int z = blockIdx.z;
    const int m0 = blockIdx.y * 64, n0 = blockIdx.x * 64;
    const size_t zo = (size_t)z * 65536;

    f32x4 acc[4];
#pragma unroll
    for (int j = 0; j < 4; ++j) acc[j] = (f32x4){0.f, 0.f, 0.f, 0.f};

    const int row = t >> 2, ko = (t & 3) * 8;
    for (int kt = 0; kt < 256; kt += 32) {
        *(uint4*)&Ah[row * 40 + ko] =
            *(const uint4*)(ANh + zo + (size_t)(m0 + row) * 256 + kt + ko);
        *(uint4*)&Al[row * 40 + ko] =
            *(const uint4*)(ANl + zo + (size_t)(m0 + row) * 256 + kt + ko);
        *(uint4*)&Bh[row * 40 + ko] =
            *(const uint4*)(BTh + zo + (size_t)(n0 + row) * 256 + kt + ko);
        *(uint4*)&Bl[row * 40 + ko] =
            *(const uint4*)(BTl + zo + (size_t)(n0 + row) * 256 + kt + ko);
        __syncthreads();
        bf16x8 ah = *(const bf16x8*)&Ah[(wave * 16 + lm) * 40 + lq * 8];
        bf16x8 al = *(const bf16x8*)&Al[(wave * 16 + lm) * 40 + lq * 8];
#pragma unroll
        for (int j = 0; j < 4; ++j) {
            bf16x8 bh = *(const bf16x8*)&Bh[(j * 16 + lm) * 40 + lq * 8];
            bf16x8 bl = *(const bf16x8*)&Bl[(j * 16 + lm) * 40 + lq * 8];
            acc[j] = mfma3(ah, al, bh, bl, acc[j]);
        }
        __syncthreads();
    }

    const float scv = (SC != 0) ? 1.0f / (scal[0] + 1e-8f) : 1.0f;
    const float a = (SC == 1) ? scv : alpha;
    const int r0 = m0 + wave * 16 + lq * 4;
#pragma unroll
    for (int j = 0; j < 4; ++j) {
        int c = n0 + j * 16 + lm;
        float vals[4];
#pragma unroll
        for (int e = 0; e < 4; ++e) {
            float v = a * acc[j][e];
            if (EPI == 1) {
                size_t ao = zo + (size_t)(r0 + e) * 256 + c;
                v += beta * (b2f(ANh[ao]) + b2f(ANl[ao]));
            }
            if (SC == 2) v *= scv;
            vals[e] = v;
        }
        unsigned short hh[4], ll[4];
#pragma unroll
        for (int e = 0; e < 4; ++e) split2(vals[e], hh[e], ll[e]);
        if (WN) {
#pragma unroll
            for (int e = 0; e < 4; ++e) {
                size_t o = zo + (size_t)(r0 + e) * 256 + c;
                CNh[o] = hh[e];
                CNl[o] = ll[e];
            }
        }
        if (WTT) {
            uint2 ph, pl;
            ph.x = (unsigned)hh[0] | ((unsigned)hh[1] << 16);
            ph.y = (unsigned)hh[2] | ((unsigned)hh[3] << 16);
            pl.x = (unsigned)ll[0] | ((unsigned)ll[1] << 16);
            pl.y = (unsigned)ll[2] | ((unsigned)ll[3] << 16);
            *(uint2*)&CTh[zo + (size_t)c * 256 + r0] = ph;
            *(uint2*)&CTl[zo + (size_t)c * 256 + r0] = pl;
        }
    }
}

// fp32 64x64 micro-kernel
__device__ __forceinline__ void mt16(const float* As, const float* Bs,
                                     int ty4, int tx4, float (&acc)[4][4]) {
#pragma unroll
    for (int kk = 0; kk < 16; ++kk) {
        float4 a4 = *(const float4*)(As + kk * 68 + ty4);
        float4 b4 = *(const float4*)(Bs + kk * 68 + tx4);
        float aa[4] = {a4.x, a4.y, a4.z, a4.w};
        float bb[4] = {b4.x, b4.y, b4.z, b4.w};
#pragma unroll
        for (int u = 0; u < 4; ++u)
#pragma unroll
            for (int w = 0; w < 4; ++w)
                acc[u][w] += aa[u] * bb[w];
    }
}

// ---------------------------------------------------------------------------
// t2 = z6 @ (t1/rs3): A from ZN planes (h+l recombine). grid (1,4,32).
// Emits t2^T planes only (stride 16384/z).
// ---------------------------------------------------------------------------
__global__ __launch_bounds__(256) void t2_gemm(
    const unsigned short* __restrict__ ANh, const unsigned short* __restrict__ ANl,
    const float* __restrict__ t1, const float* __restrict__ rs3,
    unsigned short* __restrict__ t2Th, unsigned short* __restrict__ t2Tl) {
    __shared__ float As[16 * 68];
    __shared__ float Bs[16 * 68];
    const int t  = threadIdx.x;
    const int z  = blockIdx.z;
    const int m0 = blockIdx.y * 64;
    const size_t zo = (size_t)z * 65536;
    const float* Bb = t1 + (size_t)z * 16384;
    const int tx4 = (t & 15) * 4;
    const int ty4 = (t >> 4) * 4;
    const int ar  = t >> 2, ak = (t & 3) * 4;
    const int bkr = t >> 4, bc4 = (t & 15) * 4;
    float acc[4][4] = {};
    for (int kt = 0; kt < 256; kt += 16) {
        uint2 h2 = *(const uint2*)(ANh + zo + (size_t)(m0 + ar) * 256 + kt + ak);
        uint2 l2 = *(const uint2*)(ANl + zo + (size_t)(m0 + ar) * 256 + kt + ak);
        const unsigned short* hp = (const unsigned short*)&h2;
        const unsigned short* lp = (const unsigned short*)&l2;
        float4 av = make_float4(b2f(hp[0]) + b2f(lp[0]), b2f(hp[1]) + b2f(lp[1]),
                                b2f(hp[2]) + b2f(lp[2]), b2f(hp[3]) + b2f(lp[3]));
        float4 bv = *(const float4*)(Bb + (size_t)(kt + bkr) * 64 + bc4);
        float rr = 1.0f / rs3[z * 256 + kt + bkr];
        bv.x *= rr; bv.y *= rr; bv.z *= rr; bv.w *= rr;
        As[(ak + 0) * 68 + ar] = av.x;
        As[(ak + 1) * 68 + ar] = av.y;
        As[(ak + 2) * 68 + ar] = av.z;
        As[(ak + 3) * 68 + ar] = av.w;
        *(float4*)(Bs + bkr * 68 + bc4) = bv;
        __syncthreads();
        mt16(As, Bs, ty4, tx4, acc);
        __syncthreads();
    }
#pragma unroll
    for (int w = 0; w < 4; ++w) {
        unsigned short hh[4], ll[4];
#pragma unroll
        for (int u = 0; u < 4; ++u) split2(acc[u][w], hh[u], ll[u]);
        uint2 ph, pl;
        ph.x = (unsigned)hh[0] | ((unsigned)hh[1] << 16);
        ph.y = (unsigned)hh[2] | ((unsigned)hh[3] << 16);
        pl.x = (unsigned)ll[0] | ((unsigned)ll[1] << 16);
        pl.y = (unsigned)ll[2] | ((unsigned)ll[3] << 16);
        size_t off = (size_t)z * 16384 + (size_t)(tx4 + w) * 256 + m0 + ty4;
        *(uint2*)&t2Th[off] = ph;
        *(uint2*)&t2Tl[off] = pl;
    }
}

// ---------------------------------------------------------------------------
// qkv MFMA GEMM: X planes [16384,512] @ w_qkv planes; emits q/k planes
// ([bh][n][d], q scaled 0.125) and vT planes [bh][dh][4096]. grid (12,128).
// ---------------------------------------------------------------------------
__global__ __launch_bounds__(256) void mfma_qkv(
    const unsigned short* __restrict__ Xh_, const unsigned short* __restrict__ Xl_,
    const unsigned short* __restrict__ WTh, const unsigned short* __restrict__ WTl,
    unsigned short* __restrict__ qh, unsigned short* __restrict__ ql,
    unsigned short* __restrict__ kh, unsigned short* __restrict__ kl,
    unsigned short* __restrict__ vTh, unsigned short* __restrict__ vTl) {
    __shared__ unsigned short Ah[128 * 40], Al[128 * 40];
    __shared__ unsigned short Bh[128 * 40], Bl[128 * 40];
    const int t = threadIdx.x;
    const int wave = t >> 6, lane = t & 63, lm = lane & 15, lq = lane >> 4;
    // XCD-aware bijective swizzle: nwg=1536, 1536/8=192 per XCD
    int orig = blockIdx.y * 12 + blockIdx.x;
    int wg = (orig & 7) * 192 + (orig >> 3);
    const int m0 = (wg / 12) * 128, n0 = (wg % 12) * 128;
    const int mb = (wave >> 1) * 64, nb = (wave & 1) * 64;
    f32x4 acc[4][4];
#pragma unroll
    for (int i = 0; i < 4; ++i)
#pragma unroll
        for (int j = 0; j < 4; ++j) acc[i][j] = (f32x4){0.f, 0.f, 0.f, 0.f};

    for (int kt = 0; kt < 512; kt += 32) {
#pragma unroll
        for (int r = 0; r < 2; ++r) {
            int id = t + r * 256, row = id >> 2, ko = (id & 3) * 8;
            *(uint4*)&Ah[row * 40 + ko] =
                *(const uint4*)(Xh_ + (size_t)(m0 + row) * 512 + kt + ko);
            *(uint4*)&Al[row * 40 + ko] =
                *(const uint4*)(Xl_ + (size_t)(m0 + row) * 512 + kt + ko);
        }
#pragma unroll
        for (int r = 0; r < 2; ++r) {
            int id = t + r * 256, row = id >> 2, ko = (id & 3) * 8;
            *(uint4*)&Bh[row * 40 + ko] =
                *(const uint4*)(WTh + (size_t)(n0 + row) * 512 + kt + ko);
            *(uint4*)&Bl[row * 40 + ko] =
                *(const uint4*)(WTl + (size_t)(n0 + row) * 512 + kt + ko);
        }
        __syncthreads();
        bf16x8 ah[4], al[4], bh[4], bl[4];
#pragma unroll
        for (int i = 0; i < 4; ++i) {
            ah[i] = *(const bf16x8*)&Ah[(mb + i * 16 + lm) * 40 + lq * 8];
            al[i] = *(const bf16x8*)&Al[(mb + i * 16 + lm) * 40 + lq * 8];
        }
#pragma unroll
        for (int j = 0; j < 4; ++j) {
            bh[j] = *(const bf16x8*)&Bh[(nb + j * 16 + lm) * 40 + lq * 8];
            bl[j] = *(const bf16x8*)&Bl[(nb + j * 16 + lm) * 40 + lq * 8];
        }
#pragma unroll
        for (int i = 0; i < 4; ++i)
#pragma unroll
            for (int j = 0; j < 4; ++j)
                acc[i][j] = mfma3(ah[i], al[i], bh[j], bl[j], acc[i][j]);
        __syncthreads();
    }
#pragma unroll
    for (int i = 0; i < 4; ++i)
#pragma unroll
        for (int j = 0; j < 4; ++j) {
            int r0 = m0 + mb + i * 16 + lq * 4;
            int c  = n0 + nb + j * 16 + lm;
            int which = c >> 9, h = (c >> 6) & 7, d = c & 63;
            int b = r0 >> 12, nbase = r0 & 4095;
            if (which == 2) {
                unsigned short hh[4], ll[4];
#pragma unroll
                for (int e = 0; e < 4; ++e) split2(acc[i][j][e], hh[e], ll[e]);
                uint2 ph, pl;
                ph.x = (unsigned)hh[0] | ((unsigned)hh[1] << 16);
                ph.y = (unsigned)hh[2] | ((unsigned)hh[3] << 16);
                pl.x = (unsigned)ll[0] | ((unsigned)ll[1] << 16);
                pl.y = (unsigned)ll[2] | ((unsigned)ll[3] << 16);
                size_t off = ((size_t)(b * 8 + h) * 64 + d) * 4096 + nbase;
                *(uint2*)&vTh[off] = ph;
                *(uint2*)&vTl[off] = pl;
            } else {
                unsigned short* Ph = which ? kh : qh;
                unsigned short* Pl = which ? kl : ql;
                float sc = which ? 1.0f : 0.125f;
#pragma unroll
                for (int e = 0; e < 4; ++e) {
                    unsigned short hh, ll;
                    split2(acc[i][j][e] * sc, hh, ll);
                    size_t off = (size_t)(b * 8 + h) * 262144 +
                                 (size_t)(nbase + e) * 64 + d;
                    Ph[off] = hh;
                    Pl[off] = ll;
                }
            }
        }
}

// ---------------------------------------------------------------------------
// final MFMA GEMM: out[16384,512] = OH planes (gathered) @ w_out planes.
// grid (4,128).
// ---------------------------------------------------------------------------
__global__ __launch_bounds__(256) void mfma_final(
    const unsigned short* __restrict__ OHh, const unsigned short* __restrict__ OHl,
    const unsigned short* __restrict__ WTh, const unsigned short* __restrict__ WTl,
    float* __restrict__ out) {
    __shared__ unsigned short Ah[128 * 40], Al[128 * 40];
    __shared__ unsigned short Bh[128 * 40], Bl[128 * 40];
    const int t = threadIdx.x;
    const int wave = t >> 6, lane = t & 63, lm = lane & 15, lq = lane >> 4;
    // XCD-aware bijective swizzle: nwg=512, 512/8=64 per XCD
    int orig = blockIdx.y * 4 + blockIdx.x;
    int wg = (orig & 7) * 64 + (orig >> 3);
    const int m0 = (wg >> 2) * 128, n0 = (wg & 3) * 128;
    const int mb = (wave >> 1) * 64, nb = (wave & 1) * 64;
    f32x4 acc[4][4];
#pragma unroll
    for (int i = 0; i < 4; ++i)
#pragma unroll
        for (int j = 0; j < 4; ++j) acc[i][j] = (f32x4){0.f, 0.f, 0.f, 0.f};

    for (int kt = 0; kt < 512; kt += 32) {
#pragma unroll
        for (int r = 0; r < 2; ++r) {
            int id = t + r * 256, row = id >> 2, ko = (id & 3) * 8;
            int gr = m0 + row, b = gr >> 12, n = gr & 4095;
            int kk = kt + ko;
            size_t off = (size_t)(b * 8 + (kk >> 6)) * 262144 +
                         (size_t)n * 64 + (kk & 63);
            *(uint4*)&Ah[row * 40 + ko] = *(const uint4*)(OHh + off);
            *(uint4*)&Al[row * 40 + ko] = *(const uint4*)(OHl + off);
        }
#pragma unroll
        for (int r = 0; r < 2; ++r) {
            int id = t + r * 256, row = id >> 2, ko = (id & 3) * 8;
            *(uint4*)&Bh[row * 40 + ko] =
                *(const uint4*)(WTh + (size_t)(n0 + row) * 512 + kt + ko);
            *(uint4*)&Bl[row * 40 + ko] =
                *(const uint4*)(WTl + (size_t)(n0 + row) * 512 + kt + ko);
        }
        __syncthreads();
        bf16x8 ah[4], al[4], bh[4], bl[4];
#pragma unroll
        for (int i = 0; i < 4; ++i) {
            ah[i] = *(const bf16x8*)&Ah[(mb + i * 16 + lm) * 40 + lq * 8];
            al[i] = *(const bf16x8*)&Al[(mb + i * 16 + lm) * 40 + lq * 8];
        }
#pragma unroll
        for (int j = 0; j < 4; ++j) {
            bh[j] = *(const bf16x8*)&Bh[(nb + j * 16 + lm) * 40 + lq * 8];
            bl[j] = *(const bf16x8*)&Bl[(nb + j * 16 + lm) * 40 + lq * 8];
        }
#pragma unroll
        for (int i = 0; i < 4; ++i)
#pragma unroll
            for (int j = 0; j < 4; ++j)
                acc[i][j] = mfma3(ah[i], al[i], bh[j], bl[j], acc[i][j]);
        __syncthreads();
    }
#pragma unroll
    for (int i = 0; i < 4; ++i)
#pragma unroll
        for (int j = 0; j < 4; ++j) {
            int r0 = m0 + mb + i * 16 + lq * 4;
            int c  = n0 + nb + j * 16 + lm;
#pragma unroll
            for (int e = 0; e < 4; ++e)
                out[(size_t)(r0 + e) * 512 + c] = acc[i][j][e];
        }
}

// ---------------------------------------------------------------------------
// F3 MFMA: t1 += exp(qland@k^T)@v, rs3 += rowsums. grid (8, 4, 32).
// ---------------------------------------------------------------------------
__global__ __launch_bounds__(256) void attn3v_mfma(
    const unsigned short* __restrict__ qlh, const unsigned short* __restrict__ qll,
    const unsigned short* __restrict__ kh_, const unsigned short* __restrict__ kl_,
    const unsigned short* __restrict__ vTh, const unsigned short* __restrict__ vTl,
    float* __restrict__ t1, float* __restrict__ rs3) {
    __shared__ unsigned short Qh[4608], Ql[4608];
    __shared__ unsigned short Kh[4608], Kl[4608];
    __shared__ unsigned short Eh[4608], El[4608];
    const int t = threadIdx.x;
    const int wave = t >> 6, lane = t & 63, lm = lane & 15, lq = lane >> 4;
    const int bz = blockIdx.z, m0 = blockIdx.y * 64, c0 = blockIdx.x * 8;
    const unsigned short* qhb = qlh + (size_t)bz * 16384;
    const unsigned short* qlb = qll + (size_t)bz * 16384;
    const unsigned short* khb = kh_ + (size_t)bz * 262144;
    const unsigned short* klb = kl_ + (size_t)bz * 262144;
    const unsigned short* vhb = vTh + (size_t)bz * 262144;
    const unsigned short* vlb = vTl + (size_t)bz * 262144;
#pragma unroll
    for (int r = 0; r < 2; ++r) {
        int id = t + r * 256, row = id >> 3, ko = (id & 7) * 8;
        *(uint4*)&Qh[row * 72 + ko] =
            *(const uint4*)(qhb + (size_t)(m0 + row) * 64 + ko);
        *(uint4*)&Ql[row * 72 + ko] =
            *(const uint4*)(qlb + (size_t)(m0 + row) * 64 + ko);
    }
    f32x4 acc[4];
#pragma unroll
    for (int j = 0; j < 4; ++j) acc[j] = (f32x4){0.f, 0.f, 0.f, 0.f};
    float rsum[4] = {0.f, 0.f, 0.f, 0.f};
    __syncthreads();

    for (int c = c0; c < c0 + 8; ++c) {
        const int tok0 = c * 64;
#pragma unroll
        for (int r = 0; r < 2; ++r) {
            int id = t + r * 256, row = id >> 3, ko = (id & 7) * 8;
            *(uint4*)&Kh[row * 72 + ko] =
                *(const uint4*)(khb + (size_t)(tok0 + row) * 64 + ko);
            *(uint4*)&Kl[row * 72 + ko] =
                *(const uint4*)(klb + (size_t)(tok0 + row) * 64 + ko);
        }
        __syncthreads();
        bf16x8 a0  = *(const bf16x8*)&Qh[(wave * 16 + lm) * 72 + lq * 8];
        bf16x8 a0l = *(const bf16x8*)&Ql[(wave * 16 + lm) * 72 + lq * 8];
        bf16x8 a1  = *(const bf16x8*)&Qh[(wave * 16 + lm) * 72 + 32 + lq * 8];
        bf16x8 a1l = *(const bf16x8*)&Ql[(wave * 16 + lm) * 72 + 32 + lq * 8];
        f32x4 s[4];
#pragma unroll
        for (int j = 0; j < 4; ++j) s[j] = (f32x4){0.f, 0.f, 0.f, 0.f};
#pragma unroll
        for (int j = 0; j < 4; ++j) {
            bf16x8 b0  = *(const bf16x8*)&Kh[(j * 16 + lm) * 72 + lq * 8];
            bf16x8 b0l = *(const bf16x8*)&Kl[(j * 16 + lm) * 72 + lq * 8];
            bf16x8 b1  = *(const bf16x8*)&Kh[(j * 16 + lm) * 72 + 32 + lq * 8];
            bf16x8 b1l = *(const bf16x8*)&Kl[(j * 16 + lm) * 72 + 32 + lq * 8];
            s[j] = mfma3(a0, a0l, b0, b0l, s[j]);
            s[j] = mfma3(a1, a1l, b1, b1l, s[j]);
        }
        __syncthreads();
#pragma unroll
        for (int j = 0; j < 4; ++j)
#pragma unroll
            for (int e = 0; e < 4; ++e) {
                float ev = __expf(s[j][e]);
                rsum[e] += ev;
                unsigned short h, l;
                split2(ev, h, l);
                int off = (wave * 16 + lq * 4 + e) * 72 + j * 16 + lm;
                Eh[off] = h;
                El[off] = l;
            }
#pragma unroll
        for (int r = 0; r < 2; ++r) {
            int id = t + r * 256, dh = id >> 3, t8 = (id & 7) * 8;
            *(uint4*)&Kh[dh * 72 + t8] =
                *(const uint4*)(vhb + (size_t)dh * 4096 + tok0 + t8);
            *(uint4*)&Kl[dh * 72 + t8] =
                *(const uint4*)(vlb + (size_t)dh * 4096 + tok0 + t8);
        }
        __syncthreads();
        bf16x8 e0  = *(const bf16x8*)&Eh[(wave * 16 + lm) * 72 + lq * 8];
        bf16x8 e0l = *(const bf16x8*)&El[(wave * 16 + lm) * 72 + lq * 8];
        bf16x8 e1  = *(const bf16x8*)&Eh[(wave * 16 + lm) * 72 + 32 + lq * 8];
        bf16x8 e1l = *(const bf16x8*)&El[(wave * 16 + lm) * 72 + 32 + lq * 8];
#pragma unroll
        for (int j = 0; j < 4; ++j) {
            bf16x8 v0  = *(const bf16x8*)&Kh[(j * 16 + lm) * 72 + lq * 8];
            bf16x8 v0l = *(const bf16x8*)&Kl[(j * 16 + lm) * 72 + lq * 8];
            bf16x8 v1  = *(const bf16x8*)&Kh[(j * 16 + lm) * 72 + 32 + lq * 8];
            bf16x8 v1l = *(const bf16x8*)&Kl[(j * 16 + lm) * 72 + 32 + lq * 8];
            acc[j] = mfma3(e0, e0l, v0, v0l, acc[j]);
            acc[j] = mfma3(e1, e1l, v1, v1l, acc[j]);
        }
        __syncthreads();
    }
    float* t1b = t1 + (size_t)bz * 16384;
#pragma unroll
    for (int j = 0; j < 4; ++j)
#pragma unroll
        for (int e = 0; e < 4; ++e)
            atomicAdd(t1b + (size_t)(m0 + wave * 16 + lq * 4 + e) * 64 +
                          j * 16 + lm,
                      acc[j][e]);
#pragma unroll
    for (int e = 0; e < 4; ++e) {
        float vs = rsum[e];
        for (int mm = 1; mm < 16; mm <<= 1) vs += __shfl_xor(vs, mm);
        if (lm == 0)
            atomicAdd(rs3 + bz * 256 + m0 + wave * 16 + lq * 4 + e, vs);
    }
}

// ---------------------------------------------------------------------------
// F1 MFMA + fused depthwise conv: OH planes = softmax(q@kland^T)@t2 + conv(v).
// After the PV loop the Q/K LDS region is dead -> re-used as the fp32 v
// window Vs[96][65]. grid (64, 32).
// ---------------------------------------------------------------------------
__global__ __launch_bounds__(256) void attn1t2_conv(
    const unsigned short* __restrict__ qh_, const unsigned short* __restrict__ ql_,
    const unsigned short* __restrict__ klh, const unsigned short* __restrict__ kll,
    const unsigned short* __restrict__ t2Th, const unsigned short* __restrict__ t2Tl,
    const unsigned short* __restrict__ vTh, const unsigned short* __restrict__ vTl,
    const float* __restrict__ wres,
    unsigned short* __restrict__ OHh, unsigned short* __restrict__ OHl) {
    __shared__ __align__(16) unsigned short SH[27648];   // 55296 B
    unsigned short* Qh = SH;
    unsigned short* Ql = SH + 4608;
    unsigned short* Kh = SH + 9216;
    unsigned short* Kl = SH + 13824;
    unsigned short* Eh = SH + 18432;
    unsigned short* El = SH + 23040;
    __shared__ float Ws[33];
    const int t = threadIdx.x;
    const int wave = t >> 6, lane = t & 63, lm = lane & 15, lq = lane >> 4;
    const int bz = blockIdx.y, m0 = blockIdx.x * 64;
    if (t < 33) Ws[t] = wres[(bz & 7) * 33 + t];
    const unsigned short* qhb = qh_ + (size_t)bz * 262144;
    const unsigned short* qlb = ql_ + (size_t)bz * 262144;
    const unsigned short* khb = klh + (size_t)bz * 16384;
    const unsigned short* klb = kll + (size_t)bz * 16384;
    const unsigned short* t2h = t2Th + (size_t)bz * 16384;
    const unsigned short* t2l = t2Tl + (size_t)bz * 16384;
#pragma unroll
    for (int r = 0; r < 2; ++r) {
        int id = t + r * 256, row = id >> 3, ko = (id & 7) * 8;
        *(uint4*)&Qh[row * 72 + ko] =
            *(const uint4*)(qhb + (size_t)(m0 + row) * 64 + ko);
        *(uint4*)&Ql[row * 72 + ko] =
            *(const uint4*)(qlb + (size_t)(m0 + row) * 64 + ko);
    }
    f32x4 acc[4];
#pragma unroll
    for (int j = 0; j < 4; ++j) acc[j] = (f32x4){0.f, 0.f, 0.f, 0.f};
    float rsum[4] = {0.f, 0.f, 0.f, 0.f};
    __syncthreads();

    for (int lc = 0; lc < 4; ++lc) {
        const int l0 = lc * 64;
#pragma unroll
        for (int r = 0; r < 2; ++r) {
            int id = t + r * 256, row = id >> 3, ko = (id & 7) * 8;
            *(uint4*)&Kh[row * 72 + ko] =
                *(const uint4*)(khb + (size_t)(l0 + row) * 64 + ko);
            *(uint4*)&Kl[row * 72 + ko] =
                *(const uint4*)(klb + (size_t)(l0 + row) * 64 + ko);
        }
        __syncthreads();
        bf16x8 a0  = *(const bf16x8*)&Qh[(wave * 16 + lm) * 72 + lq * 8];
        bf16x8 a0l = *(const bf16x8*)&Ql[(wave * 16 + lm) * 72 + lq * 8];
        bf16x8 a1  = *(const bf16x8*)&Qh[(wave * 16 + lm) * 72 + 32 + lq * 8];
        bf16x8 a1l = *(const bf16x8*)&Ql[(wave * 16 + lm) * 72 + 32 + lq * 8];
        f32x4 s[4];
#pragma unroll
        for (int j = 0; j < 4; ++j) s[j] = (f32x4){0.f, 0.f, 0.f, 0.f};
#pragma unroll
        for (int j = 0; j < 4; ++j) {
            bf16x8 b0  = *(const bf16x8*)&Kh[(j * 16 + lm) * 72 + lq * 8];
            bf16x8 b0l = *(const bf16x8*)&Kl[(j * 16 + lm) * 72 + lq * 8];
            bf16x8 b1  = *(const bf16x8*)&Kh[(j * 16 + lm) * 72 + 32 + lq * 8];
            bf16x8 b1l = *(const bf16x8*)&Kl[(j * 16 + lm) * 72 + 32 + lq * 8];
            s[j] = mfma3(a0, a0l, b0, b0l, s[j]);
            s[j] = mfma3(a1, a1l, b1, b1l, s[j]);
        }
        __syncthreads();
#pragma unroll
        for (int j = 0; j < 4; ++j)
#pragma unroll
            for (int e = 0; e < 4; ++e) {
                float ev = __expf(s[j][e]);
                rsum[e] += ev;
                unsigned short h, l;
                split2(ev, h, l);
                int off = (wave * 16 + lq * 4 + e) * 72 + j * 16 + lm;
                Eh[off] = h;
                El[off] = l;
            }
#pragma unroll
        for (int r = 0; r < 2; ++r) {
            int id = t + r * 256, dh = id >> 3, t8 = (id & 7) * 8;
            *(uint4*)&Kh[dh * 72 + t8] =
                *(const uint4*)(t2h + (size_t)dh * 256 + l0 + t8);
            *(uint4*)&Kl[dh * 72 + t8] =
                *(const uint4*)(t2l + (size_t)dh * 256 + l0 + t8);
        }
        __syncthreads();
        bf16x8 e0  = *(const bf16x8*)&Eh[(wave * 16 + lm) * 72 + lq * 8];
        bf16x8 e0l = *(const bf16x8*)&El[(wave * 16 + lm) * 72 + lq * 8];
        bf16x8 e1  = *(const bf16x8*)&Eh[(wave * 16 + lm) * 72 + 32 + lq * 8];
        bf16x8 e1l = *(const bf16x8*)&El[(wave * 16 + lm) * 72 + 32 + lq * 8];
#pragma unroll
        for (int j = 0; j < 4; ++j) {
            bf16x8 v0  = *(const bf16x8*)&Kh[(j * 16 + lm) * 72 + lq * 8];
            bf16x8 v0l = *(const bf16x8*)&Kl[(j * 16 + lm) * 72 + lq * 8];
            bf16x8 v1  = *(const bf16x8*)&Kh[(j * 16 + lm) * 72 + 32 + lq * 8];
            bf16x8 v1l = *(const bf16x8*)&Kl[(j * 16 + lm) * 72 + 32 + lq * 8];
            acc[j] = mfma3(e0, e0l, v0, v0l, acc[j]);
            acc[j] = mfma3(e1, e1l, v1, v1l, acc[j]);
        }
        __syncthreads();
    }
    float rinv[4];
#pragma unroll
    for (int e = 0; e < 4; ++e) {
        float vs = rsum[e];
        for (int mm = 1; mm < 16; mm <<= 1) vs += __shfl_xor(vs, mm);
        rinv[e] = 1.0f / vs;
    }

    // ---- fused conv: stage v window [m0-16, m0+80) into dead Q/K LDS ----
    __syncthreads();
    float* Vs = (float*)SH;                      // 96 x 65 fp32 = 24960 B
    const unsigned short* vhb = vTh + (size_t)bz * 262144;
    const unsigned short* vlb = vTl + (size_t)bz * 262144;
#pragma unroll
    for (int r = 0; r < 3; ++r) {
        int id = t + r * 256;                    // 0..767 = 64 dh x 12 chunks
        int d = id / 12, ch = id - d * 12;
        int n = m0 - 16 + ch * 8;
        uint4 h4 = make_uint4(0u, 0u, 0u, 0u);
        uint4 l4 = make_uint4(0u, 0u, 0u, 0u);
        if ((unsigned)n < 4096u) {
            h4 = *(const uint4*)(vhb + (size_t)d * 4096 + n);
            l4 = *(const uint4*)(vlb + (size_t)d * 4096 + n);
        }
        const unsigned short* hp = (const unsigned short*)&h4;
        const unsigned short* lp = (const unsigned short*)&l4;
#pragma unroll
        for (int i = 0; i < 8; ++i)
            Vs[(ch * 8 + i) * 65 + d] = b2f(hp[i]) + b2f(lp[i]);
    }
    __syncthreads();
    unsigned short* Hh = OHh + (size_t)bz * 262144;
    unsigned short* Hl = OHl + (size_t)bz * 262144;
    const int rbase = wave * 16 + lq * 4;
#pragma unroll
    for (int j = 0; j < 4; ++j) {
        int cc = j * 16 + lm;
        float w[36];
#pragma unroll
        for (int u = 0; u < 36; ++u) w[u] = Vs[(rbase + u) * 65 + cc];
#pragma unroll
        for (int e = 0; e < 4; ++e) {
            float cv = 0.f;
#pragma unroll
            for (int tt = 0; tt < 33; ++tt) cv += w[e + tt] * Ws[tt];
            float o = acc[j][e] * rinv[e] + cv;
            unsigned short hh, ll;
            split2(o, hh, ll);
            size_t off = (size_t)(m0 + rbase + e) * 64 + cc;
            Hh[off] = hh;
            Hl[off] = ll;
        }
    }
}

// ---------------------------------------------------------------------------
// fp32 gemm for attn2 scores
// ---------------------------------------------------------------------------
__global__ __launch_bounds__(256) void gemm_a2(
    const float* __restrict__ A, const float* __restrict__ B,
    float* __restrict__ C) {
    __shared__ float As[16 * 68];
    __shared__ float Bs[16 * 68];
    const int t  = threadIdx.x;
    const int z  = blockIdx.z;
    const int m0 = blockIdx.y * 64;
    const int n0 = blockIdx.x * 64;
    const float* Ab = A + (size_t)z * 16384;
    const float* Bb = B + (size_t)z * 16384;
    float*       Cb = C + (size_t)z * 65536;
    const int tx4 = (t & 15) * 4;
    const int ty4 = (t >> 4) * 4;
    const int ar  = t >> 2, ak = (t & 3) * 4;
    float acc[4][4] = {};
    for (int kt = 0; kt < 64; kt += 16) {
        float4 av = *(const float4*)(Ab + (size_t)(m0 + ar) * 64 + kt + ak);
        float4 bv = *(const float4*)(Bb + (size_t)(n0 + ar) * 64 + kt + ak);
        As[(ak + 0) * 68 + ar] = av.x;
        As[(ak + 1) * 68 + ar] = av.y;
        As[(ak + 2) * 68 + ar] = av.z;
        As[(ak + 3) * 68 + ar] = av.w;
        Bs[(ak + 0) * 68 + ar] = bv.x;
        Bs[(ak + 1) * 68 + ar] = bv.y;
        Bs[(ak + 2) * 68 + ar] = bv.z;
        Bs[(ak + 3) * 68 + ar] = bv.w;
        __syncthreads();
        mt16(As, Bs, ty4, tx4, acc);
        __syncthreads();
    }
#pragma unroll
    for (int u = 0; u < 4; ++u) {
        int row = m0 + ty4 + u;
        *(float4*)(Cb + (size_t)row * 256 + n0 + tx4) =
            make_float4(acc[u][0], acc[u][1], acc[u][2], acc[u][3]);
    }
}

// ---------------------------------------------------------------------------
// small kernels
// ---------------------------------------------------------------------------
__global__ void zero_f(float* __restrict__ p, int n) {
    int i = blockIdx.x * 256 + threadIdx.x;
    if (i < n) p[i] = 0.f;
}

// both landmark means in one dispatch. grid 4096.
__global__ void landmark_mean2(
    const unsigned short* __restrict__ qh, const unsigned short* __restrict__ ql,
    const unsigned short* __restrict__ kh, const unsigned short* __restrict__ kl,
    float* __restrict__ qland, float* __restrict__ kland,
    unsigned short* __restrict__ qlh, unsigned short* __restrict__ qll,
    unsigned short* __restrict__ klh, unsigned short* __restrict__ kll) {
    int o = blockIdx.x * 256 + threadIdx.x;
    bool isq = o < 524288;
    int oo = isq ? o : o - 524288;
    const unsigned short* sh = isq ? qh : kh;
    const unsigned short* sl = isq ? ql : kl;
    float* dst = isq ? qland : kland;
    unsigned short* dh = isq ? qlh : klh;
    unsigned short* dl = isq ? qll : kll;
    int d = oo & 63, m = (oo >> 6) & 255, bh = oo >> 14;
    size_t base = (size_t)bh * 262144 + (size_t)m * 1024 + d;
    float acc = 0.f;
#pragma unroll
    for (int j = 0; j < 16; ++j)
        acc += b2f(sh[base + j * 64]) + b2f(sl[base + j * 64]);
    float v = acc * (1.0f / 16.0f);
    dst[oo] = v;
    unsigned short h, l;
    split2(v, h, l);
    dh[oo] = h;
    dl[oo] = l;
}

// softmax + emit a2 normal/transposed planes + colsum atomics. grid 8192.
__global__ void softmax_fused(const float* __restrict__ a,
                              unsigned short* __restrict__ A2Ph,
                              unsigned short* __restrict__ A2Pl,
                              unsigned short* __restrict__ A2Th,
                              unsigned short* __restrict__ A2Tl,
                              float* __restrict__ colsum) {
    __shared__ float red[256];
    int row = blockIdx.x, t = threadIdx.x;
    float v = a[(size_t)row * 256 + t];
    red[t] = v;
    __syncthreads();
    for (int s = 128; s > 0; s >>= 1) {
        if (t < s) red[t] = fmaxf(red[t], red[t + s]);
        __syncthreads();
    }
    float mx = red[0];
    __syncthreads();
    float e = __expf(v - mx);
    red[t] = e;
    __syncthreads();
    for (int s = 128; s > 0; s >>= 1) {
        if (t < s) red[t] += red[t + s];
        __syncthreads();
    }
    float val = e / red[0];
    int z = row >> 8, r = row & 255;
    atomicAdd(&colsum[z * 256 + t], val);
    unsigned short h, l;
    split2(val, h, l);
    size_t zo = (size_t)z * 65536;
    A2Ph[zo + (size_t)r * 256 + t] = h;
    A2Pl[zo + (size_t)r * 256 + t] = l;
    A2Th[zo + (size_t)t * 256 + r] = h;
    A2Tl[zo + (size_t)t * 256 + r] = l;
}

// global max over colsum -> scal[0]. grid 32.
__global__ void scal_max(const float* __restrict__ colsum,
                         float* __restrict__ scal) {
    __shared__ float red[256];
    int t = threadIdx.x;
    red[t] = colsum[blockIdx.x * 256 + t];
    __syncthreads();
    for (int s = 128; s > 0; s >>= 1) {
        if (t < s) red[t] = fmaxf(red[t], red[t + s]);
        __syncthreads();
    }
    if (t == 0) atomicMax((unsigned int*)&scal[0], __float_as_uint(red[0]));
}

// ---------------------------------------------------------------------------
extern "C" void kernel_launch(void* const* d_in, const int* in_sizes, int n_in,
                              void* d_out, int out_size, void* d_ws, size_t ws_size,
                              hipStream_t stream) {
    const float* x     = (const float*)d_in[0];
    const float* w_qkv = (const float*)d_in[1];
    const float* w_out = (const float*)d_in[2];
    const float* w_res = (const float*)d_in[3];
    float* out = (float*)d_out;
    float* ws  = (float*)d_ws;

    // planes (ushort units)
    unsigned short* Xh  = (unsigned short*)(ws + O_XP);
    unsigned short* Xl  = Xh + 8388608;
    unsigned short* qh  = (unsigned short*)(ws + O_QP);
    unsigned short* ql  = qh + 8388608;
    unsigned short* kh  = (unsigned short*)(ws + O_KP);
    unsigned short* kl  = kh + 8388608;
    unsigned short* vTh = (unsigned short*)(ws + O_VT);
    unsigned short* vTl = vTh + 8388608;
    unsigned short* qlh = (unsigned short*)(ws + O_QLP);
    unsigned short* qll = qlh + 524288;
    unsigned short* klh = (unsigned short*)(ws + O_KLP);
    unsigned short* kll = klh + 524288;

    float* qland = ws + O_QL;
    float* kland = ws + O_KL;
    float* attn2 = ws + O_A2;
    float* t1    = ws + O_T1;
    float* rs3   = ws + O_RS3;
    float* scal  = ws + O_SCAL;
    float* colsum= ws + O_CS;

    // pinv plane pool A: k-plane region (dead after attn3v)
    unsigned short* PBu  = (unsigned short*)(ws + O_KP);
    unsigned short* A2Ph = PBu + 0;
    unsigned short* A2Pl = PBu + 2097152;
    unsigned short* XZNh = PBu + 4194304;
    unsigned short* XZNl = PBu + 6291456;
    unsigned short* XZTh = PBu + 8388608;
    unsigned short* XZTl = PBu + 10485760;
    unsigned short* Y1Th = PBu + 12582912;
    unsigned short* Y1Tl = PBu + 14680064;
    // pinv plane pool B: X-plane region (dead after qkv)
    unsigned short* XRu  = (unsigned short*)(ws + O_XP);
    unsigned short* ZNah = XRu + 0;            // also hosts A2T (pre-iter2)
    unsigned short* ZNal = XRu + 2097152;
    unsigned short* ZNbh = XRu + 4194304;
    unsigned short* ZNbl = XRu + 6291456;
    unsigned short* ZTh_ = XRu + 8388608;
    unsigned short* ZTl_ = XRu + 10485760;
    unsigned short* Y2Th = XRu + 12582912;
    unsigned short* Y2Tl = XRu + 14680064;
    unsigned short* A2Th = ZNah;               // a2^T planes (z0 * denom)
    unsigned short* A2Tl = ZNal;
    // post-pinv aliases
    unsigned short* t2Th = (unsigned short*)(ws + O_QL);   // qland dead
    unsigned short* t2Tl = t2Th + 524288;
    unsigned short* OHh = PBu;                 // pool A dead after pinv
    unsigned short* OHl = PBu + 8388608;

    unsigned short* WQTh = (unsigned short*)(ws + O_WQT);
    unsigned short* WQTl = WQTh + 786432;
    unsigned short* WOTh = (unsigned short*)(ws + O_WOT);
    unsigned short* WOTl = WOTh + 262144;

    zero_f<<<2113, 256, 0, stream>>>(t1, 540688);   // t1+rs3+scal+colsum
    wtrans2<<<4096, 256, 0, stream>>>(w_qkv, w_out, WQTh, WQTl, WOTh, WOTl);
    xsplit<<<8192, 256, 0, stream>>>(x, Xh, Xl);

    mfma_qkv<<<dim3(12, 128), 256, 0, stream>>>(Xh, Xl, WQTh, WQTl,
                                                qh, ql, kh, kl, vTh, vTl);

    landmark_mean2<<<4096, 256, 0, stream>>>(qh, ql, kh, kl, qland, kland,
                                             qlh, qll, klh, kll);

    // F3 first: consumes k planes (pool A overwritten by softmax_fused next)
    attn3v_mfma<<<dim3(8, 4, 32), 256, 0, stream>>>(qlh, qll, kh, kl,
                                                    vTh, vTl, t1, rs3);

    gemm_a2<<<dim3(4, 4, 32), 256, 0, stream>>>(qland, kland, attn2);
    softmax_fused<<<8192, 256, 0, stream>>>(attn2, A2Ph, A2Pl, A2Th, A2Tl,
                                            colsum);
    scal_max<<<32, 256, 0, stream>>>(colsum, scal);

    // pinv: 6x4 all-plane stages (zinit folded into SC modes)
    unsigned short* ZNh[2] = {ZNah, ZNbh};
    unsigned short* ZNl[2] = {ZNal, ZNbl};
    int cur = 0;
    const dim3 pg(4, 4, 32);
    for (int it = 0; it < 6; ++it) {
        if (it == 0) {
            // xz = (1/denom) * (a2 @ a2^T)
            mfma_gemm_p<0, 1, true, true><<<pg, 256, 0, stream>>>(
                A2Ph, A2Pl, A2Ph, A2Pl, XZNh, XZNl, XZTh, XZTl,
                0.f, 0.f, scal);
        } else {
            mfma_gemm_p<0, 0, true, true><<<pg, 256, 0, stream>>>(
                A2Ph, A2Pl, ZTh_, ZTl_, XZNh, XZNl, XZTh, XZTl,
                1.f, 0.f, scal);
        }
        // Y1 = -xz@xz + 7*xz
        mfma_gemm_p<1, 0, false, true><<<pg, 256, 0, stream>>>(
            XZNh, XZNl, XZTh, XZTl, nullptr, nullptr, Y1Th, Y1Tl,
            -1.f, 7.f, scal);
        // Y2 = -xz@Y1 + 15*xz
        mfma_gemm_p<1, 0, false, true><<<pg, 256, 0, stream>>>(
            XZNh, XZNl, Y1Th, Y1Tl, nullptr, nullptr, Y2Th, Y2Tl,
            -1.f, 15.f, scal);
        // z' = -0.25*z@Y2 + 3.25*z
        if (it == 0) {
            // z = a2^T/denom: A = A2T, whole result scaled by 1/denom (SC=2)
            mfma_gemm_p<1, 2, true, true><<<pg, 256, 0, stream>>>(
                A2Th, A2Tl, Y2Th, Y2Tl, ZNbh, ZNbl, ZTh_, ZTl_,
                -0.25f, 3.25f, scal);
            cur = 1;
        } else {
            mfma_gemm_p<1, 0, true, true><<<pg, 256, 0, stream>>>(
                ZNh[cur], ZNl[cur], Y2Th, Y2Tl, ZNh[1 - cur], ZNl[1 - cur],
                ZTh_, ZTl_, -0.25f, 3.25f, scal);
            cur = 1 - cur;
        }
    }
    // zfin = ZN[0] (it1:->0, it2:->1, it3:->0, it4:->1, it5:->0)

    // t2 = zfin @ (t1 / rs3); t2^T planes into dead qland region
    t2_gemm<<<dim3(1, 4, 32), 256, 0, stream>>>(ZNh[0], ZNl[0], t1, rs3,
                                                t2Th, t2Tl);

    // F1 + conv fused -> OH planes (pool A, fully dead now)
    attn1t2_conv<<<dim3(64, 32), 256, 0, stream>>>(qh, ql, klh, kll,
                                                   t2Th, t2Tl, vTh, vTl,
                                                   w_res, OHh, OHl);

    mfma_final<<<dim3(4, 128), 256, 0, stream>>>(OHh, OHl, WOTh, WOTl, out);

    (void)in_sizes; (void)n_in; (void)out_size; (void)ws_size;
}

// Round 6
// 777.541 us; speedup vs baseline: 1.6072x; 1.0735x over previous
//
#include <hip/hip_runtime.h>

// ---------------------------------------------------------------------------
// Nystrom attention: split-bf16 (hi/lo, 3xMFMA) everywhere.
// R11: global_load_lds staging for all plane GEMMs (mfma_qkv, mfma_final,
// pinv stages). LDS tiles unpadded (stride 32 ushorts) — read pattern is
// uniformly 8 accesses/bank either way, so the pad was free to drop; the
// linear LDS dest is what global_load_lds requires. Global source stays
// per-lane (even mfma_final's gather). No VGPR round-trip, 4x fewer staging
// instructions. Everything else as R10.
// B=4, N=4096, DIM=512, H=8, DH=64, M=256, l=16, 6 pinv iters, conv K=33.
// ---------------------------------------------------------------------------

typedef __attribute__((ext_vector_type(8))) short bf16x8;
typedef __attribute__((ext_vector_type(4))) float f32x4;

// workspace layout (float units)
constexpr size_t O_XP  = 0;          // Xh/Xl planes; later pool B (ZN/ZT/Y2T, A2T)
constexpr size_t O_QP  = 8388608;    // q planes (hi/lo)
constexpr size_t O_KP  = 16777216;   // k planes; later pool A (A2P/XZN/XZT/Y1T); later OH planes
constexpr size_t O_VT  = 25165824;   // vT planes
constexpr size_t O_QL  = 33554432;   // qland fp32; later t2T planes
constexpr size_t O_KL  = 34078720;   // kland fp32
constexpr size_t O_QLP = 34603008;   // qland planes
constexpr size_t O_KLP = 35127296;   // kland planes
constexpr size_t O_A2  = 35651584;   // attn2 fp32 (pre-softmax scores)
constexpr size_t O_T1  = 37748736;
constexpr size_t O_RS3 = 38273024;
constexpr size_t O_SCAL= 38281216;
constexpr size_t O_CS  = 38281232;   // colsum [32][256]
constexpr size_t O_WQT = 38805520;
constexpr size_t O_WOT = 39591952;
constexpr size_t O_END = 39854096;   // ~159.4 MB

// ---------------------------------------------------------------------------
__device__ __forceinline__ void split2(float x, unsigned short& h,
                                       unsigned short& l) {
    unsigned u  = __float_as_uint(x);
    unsigned hb = (u + 0x7FFFu + ((u >> 16) & 1u)) & 0xFFFF0000u;  // RNE hi
    h = (unsigned short)(hb >> 16);
    float d = x - __uint_as_float(hb);
    l = (unsigned short)(__float_as_uint(d) >> 16);
}

__device__ __forceinline__ float b2f(unsigned short s) {
    return __uint_as_float((unsigned)s << 16);
}

__device__ __forceinline__ f32x4 mfma3(bf16x8 ah, bf16x8 al, bf16x8 bh,
                                       bf16x8 bl, f32x4 c) {
    c = __builtin_amdgcn_mfma_f32_16x16x32_bf16(ah, bh, c, 0, 0, 0);
    c = __builtin_amdgcn_mfma_f32_16x16x32_bf16(ah, bl, c, 0, 0, 0);
    c = __builtin_amdgcn_mfma_f32_16x16x32_bf16(al, bh, c, 0, 0, 0);
    return c;
}

// async global->LDS, 16 B per lane (gfx950). LDS dest = uniform base + lane*16.
__device__ __forceinline__ void g2l16(const unsigned short* g,
                                      unsigned short* l) {
    __builtin_amdgcn_global_load_lds(
        (const __attribute__((address_space(1))) void*)g,
        (__attribute__((address_space(3))) void*)l, 16, 0, 0);
}

// split a float4 into hi/lo planes, write packed uint2 at H[off], L[off]
__device__ __forceinline__ void stage_split4(float4 av, unsigned short* H,
                                             unsigned short* L, int off) {
    unsigned short h0, h1, h2, h3, l0, l1, l2, l3;
    split2(av.x, h0, l0); split2(av.y, h1, l1);
    split2(av.z, h2, l2); split2(av.w, h3, l3);
    uint2 ph, pl;
    ph.x = (unsigned)h0 | ((unsigned)h1 << 16);
    ph.y = (unsigned)h2 | ((unsigned)h3 << 16);
    pl.x = (unsigned)l0 | ((unsigned)l1 << 16);
    pl.y = (unsigned)l2 | ((unsigned)l3 << 16);
    *(uint2*)&H[off] = ph;
    *(uint2*)&L[off] = pl;
}

// ---------------------------------------------------------------------------
// X -> split planes (one-time)
// ---------------------------------------------------------------------------
__global__ void xsplit(const float* __restrict__ X,
                       unsigned short* __restrict__ Xh,
                       unsigned short* __restrict__ Xl) {
    int idx = blockIdx.x * 256 + threadIdx.x;
    float4 v = *(const float4*)(X + (size_t)idx * 4);
    stage_split4(v, Xh, Xl, idx * 4);
}

// ---------------------------------------------------------------------------
// both weight transposes in one dispatch. grid 4096.
// ---------------------------------------------------------------------------
__global__ void wtrans2(const float* __restrict__ Wq,
                        const float* __restrict__ Wo,
                        unsigned short* __restrict__ QTh,
                        unsigned short* __restrict__ QTl,
                        unsigned short* __restrict__ OTh,
                        unsigned short* __restrict__ OTl) {
    int idx = blockIdx.x * 256 + threadIdx.x;
    unsigned short h, l;
    if (idx < 786432) {
        int n = idx >> 9, kk = idx & 511;
        split2(Wq[(size_t)kk * 1536 + n], h, l);
        QTh[idx] = h;
        QTl[idx] = l;
    } else {
        int j = idx - 786432;
        int n = j >> 9, kk = j & 511;
        split2(Wo[(size_t)kk * 512 + n], h, l);
        OTh[j] = h;
        OTl[j] = l;
    }
}

// ---------------------------------------------------------------------------
// All-plane pinv GEMM stage: C = alpha*(A@B) + beta*A_elem.
// SC=0: as-is. SC=1: alpha := 1/denom (EPI=0). SC=2: whole result *= 1/denom.
// A = normal planes AN[m][k]; B = transposed planes BT[n][k].
// global_load_lds staging (wave w stages buffer w, 4 chunks of 1024 B).
// grid (4,4,32), 64x64 tile, 256 threads. LDS 16 KB.
// ---------------------------------------------------------------------------
template <int EPI, int SC, bool WN, bool WTT>
__global__ __launch_bounds__(256) void mfma_gemm_p(
    const unsigned short* __restrict__ ANh, const unsigned short* __restrict__ ANl,
    const unsigned short* __restrict__ BTh, const unsigned short* __restrict__ BTl,
    unsigned short* __restrict__ CNh, unsigned short* __restrict__ CNl,
    unsigned short* __restrict__ CTh, unsigned short* __restrict__ CTl,
    float alpha, float beta, const float* __restrict__ scal) {
    __shared__ __align__(16) unsigned short Ah[64 * 32], Al[64 * 32];
    __shared__ __align__(16) unsigned short Bh[64 * 32], Bl[64 * 32];
    const int t = threadIdx.x;
    const int wave = t >> 6, lane = t & 63, lm = lane & 15, lq = lane >> 4;
    const int z = blockIdx.z;
    const int m0 = blockIdx.y * 64, n0 = blockIdx.x * 64;
    const size_t zo = (size_t)z * 65536;

    // staging role: wave 0->Ah, 1->Al, 2->Bh, 3->Bl
    const unsigned short* gsrc;
    unsigned short* ldst;
    if (wave == 0)      { gsrc = ANh + zo + (size_t)m0 * 256; ldst = Ah; }
    else if (wave == 1) { gsrc = ANl + zo + (size_t)m0 * 256; ldst = Al; }
    else if (wave == 2) { gsrc = BTh + zo + (size_t)n0 * 256; ldst = Bh; }
    else                { gsrc = BTl + zo + (size_t)n0 * 256; ldst = Bl; }
    const int srow = lane >> 2, sko = (lane & 3) * 8;

    f32x4 acc[4];
#pragma unroll
    for (int j = 0; j < 4; ++j) acc[j] = (f32x4){0.f, 0.f, 0.f, 0.f};

    for (int kt = 0; kt < 256; kt += 32) {
#pragma unroll
        for (int c = 0; c < 4; ++c)
            g2l16(gsrc + (size_t)(c * 16 + srow) * 256 + kt + sko,
                  ldst + c * 512);
        __syncthreads();
        bf16x8 ah = *(const bf16x8*)&Ah[(wave * 16 + lm) * 32 + lq * 8];
        bf16x8 al = *(const bf16x8*)&Al[(wave * 16 + lm) * 32 + lq * 8];
#pragma unroll
        for (int j = 0; j < 4; ++j) {
            bf16x8 bh = *(const bf16x8*)&Bh[(j * 16 + lm) * 32 + lq * 8];
            bf16x8 bl = *(const bf16x8*)&Bl[(j * 16 + lm) * 32 + lq * 8];
            acc[j] = mfma3(ah, al, bh, bl, acc[j]);
        }
        __syncthreads();
    }

    const float scv = (SC != 0) ? 1.0f / (scal[0] + 1e-8f) : 1.0f;
    const float a = (SC == 1) ? scv : alpha;
    const int r0 = m0 + wave * 16 + lq * 4;
#pragma unroll
    for (int j = 0; j < 4; ++j) {
        int c = n0 + j * 16 + lm;
        float vals[4];
#pragma unroll
        for (int e = 0; e < 4; ++e) {
            float v = a * acc[j][e];
            if (EPI == 1) {
                size_t ao = zo + (size_t)(r0 + e) * 256 + c;
                v += beta * (b2f(ANh[ao]) + b2f(ANl[ao]));
            }
            if (SC == 2) v *= scv;
            vals[e] = v;
        }
        unsigned short hh[4], ll[4];
#pragma unroll
        for (int e = 0; e < 4; ++e) split2(vals[e], hh[e], ll[e]);
        if (WN) {
#pragma unroll
            for (int e = 0; e < 4; ++e) {
                size_t o = zo + (size_t)(r0 + e) * 256 + c;
                CNh[o] = hh[e];
                CNl[o] = ll[e];
            }
        }
        if (WTT) {
            uint2 ph, pl;
            ph.x = (unsigned)hh[0] | ((unsigned)hh[1] << 16);
            ph.y = (unsigned)hh[2] | ((unsigned)hh[3] << 16);
            pl.x = (unsigned)ll[0] | ((unsigned)ll[1] << 16);
            pl.y = (unsigned)ll[2] | ((unsigned)ll[3] << 16);
            *(uint2*)&CTh[zo + (size_t)c * 256 + r0] = ph;
            *(uint2*)&CTl[zo + (size_t)c * 256 + r0] = pl;
        }
    }
}

// fp32 64x64 micro-kernel
__device__ __forceinline__ void mt16(const float* As, const float* Bs,
                                     int ty4, int tx4, float (&acc)[4][4]) {
#pragma unroll
    for (int kk = 0; kk < 16; ++kk) {
        float4 a4 = *(const float4*)(As + kk * 68 + ty4);
        float4 b4 = *(const float4*)(Bs + kk * 68 + tx4);
        float aa[4] = {a4.x, a4.y, a4.z, a4.w};
        float bb[4] = {b4.x, b4.y, b4.z, b4.w};
#pragma unroll
        for (int u = 0; u < 4; ++u)
#pragma unroll
            for (int w = 0; w < 4; ++w)
                acc[u][w] += aa[u] * bb[w];
    }
}

// ---------------------------------------------------------------------------
// t2 = z6 @ (t1/rs3): A from ZN planes (h+l recombine). grid (1,4,32).
// Emits t2^T planes only (stride 16384/z).
// ---------------------------------------------------------------------------
__global__ __launch_bounds__(256) void t2_gemm(
    const unsigned short* __restrict__ ANh, const unsigned short* __restrict__ ANl,
    const float* __restrict__ t1, const float* __restrict__ rs3,
    unsigned short* __restrict__ t2Th, unsigned short* __restrict__ t2Tl) {
    __shared__ float As[16 * 68];
    __shared__ float Bs[16 * 68];
    const int t  = threadIdx.x;
    const int z  = blockIdx.z;
    const int m0 = blockIdx.y * 64;
    const size_t zo = (size_t)z * 65536;
    const float* Bb = t1 + (size_t)z * 16384;
    const int tx4 = (t & 15) * 4;
    const int ty4 = (t >> 4) * 4;
    const int ar  = t >> 2, ak = (t & 3) * 4;
    const int bkr = t >> 4, bc4 = (t & 15) * 4;
    float acc[4][4] = {};
    for (int kt = 0; kt < 256; kt += 16) {
        uint2 h2 = *(const uint2*)(ANh + zo + (size_t)(m0 + ar) * 256 + kt + ak);
        uint2 l2 = *(const uint2*)(ANl + zo + (size_t)(m0 + ar) * 256 + kt + ak);
        const unsigned short* hp = (const unsigned short*)&h2;
        const unsigned short* lp = (const unsigned short*)&l2;
        float4 av = make_float4(b2f(hp[0]) + b2f(lp[0]), b2f(hp[1]) + b2f(lp[1]),
                                b2f(hp[2]) + b2f(lp[2]), b2f(hp[3]) + b2f(lp[3]));
        float4 bv = *(const float4*)(Bb + (size_t)(kt + bkr) * 64 + bc4);
        float rr = 1.0f / rs3[z * 256 + kt + bkr];
        bv.x *= rr; bv.y *= rr; bv.z *= rr; bv.w *= rr;
        As[(ak + 0) * 68 + ar] = av.x;
        As[(ak + 1) * 68 + ar] = av.y;
        As[(ak + 2) * 68 + ar] = av.z;
        As[(ak + 3) * 68 + ar] = av.w;
        *(float4*)(Bs + bkr * 68 + bc4) = bv;
        __syncthreads();
        mt16(As, Bs, ty4, tx4, acc);
        __syncthreads();
    }
#pragma unroll
    for (int w = 0; w < 4; ++w) {
        unsigned short hh[4], ll[4];
#pragma unroll
        for (int u = 0; u < 4; ++u) split2(acc[u][w], hh[u], ll[u]);
        uint2 ph, pl;
        ph.x = (unsigned)hh[0] | ((unsigned)hh[1] << 16);
        ph.y = (unsigned)hh[2] | ((unsigned)hh[3] << 16);
        pl.x = (unsigned)ll[0] | ((unsigned)ll[1] << 16);
        pl.y = (unsigned)ll[2] | ((unsigned)ll[3] << 16);
        size_t off = (size_t)z * 16384 + (size_t)(tx4 + w) * 256 + m0 + ty4;
        *(uint2*)&t2Th[off] = ph;
        *(uint2*)&t2Tl[off] = pl;
    }
}

// ---------------------------------------------------------------------------
// qkv MFMA GEMM: X planes [16384,512] @ w_qkv planes; emits q/k planes
// ([bh][n][d], q scaled 0.125) and vT planes [bh][dh][4096]. grid (12,128).
// global_load_lds staging: wave w stages buffer w (8 chunks of 1024 B).
// ---------------------------------------------------------------------------
__global__ __launch_bounds__(256) void mfma_qkv(
    const unsigned short* __restrict__ Xh_, const unsigned short* __restrict__ Xl_,
    const unsigned short* __restrict__ WTh, const unsigned short* __restrict__ WTl,
    unsigned short* __restrict__ qh, unsigned short* __restrict__ ql,
    unsigned short* __restrict__ kh, unsigned short* __restrict__ kl,
    unsigned short* __restrict__ vTh, unsigned short* __restrict__ vTl) {
    __shared__ __align__(16) unsigned short Ah[128 * 32], Al[128 * 32];
    __shared__ __align__(16) unsigned short Bh[128 * 32], Bl[128 * 32];
    const int t = threadIdx.x;
    const int wave = t >> 6, lane = t & 63, lm = lane & 15, lq = lane >> 4;
    // XCD-aware bijective swizzle: nwg=1536, 1536/8=192 per XCD
    int orig = blockIdx.y * 12 + blockIdx.x;
    int wg = (orig & 7) * 192 + (orig >> 3);
    const int m0 = (wg / 12) * 128, n0 = (wg % 12) * 128;
    const int mb = (wave >> 1) * 64, nb = (wave & 1) * 64;

    // staging role
    const unsigned short* gsrc;
    unsigned short* ldst;
    if (wave == 0)      { gsrc = Xh_ + (size_t)m0 * 512; ldst = Ah; }
    else if (wave == 1) { gsrc = Xl_ + (size_t)m0 * 512; ldst = Al; }
    else if (wave == 2) { gsrc = WTh + (size_t)n0 * 512; ldst = Bh; }
    else                { gsrc = WTl + (size_t)n0 * 512; ldst = Bl; }
    const int srow = lane >> 2, sko = (lane & 3) * 8;

    f32x4 acc[4][4];
#pragma unroll
    for (int i = 0; i < 4; ++i)
#pragma unroll
        for (int j = 0; j < 4; ++j) acc[i][j] = (f32x4){0.f, 0.f, 0.f, 0.f};

    for (int kt = 0; kt < 512; kt += 32) {
#pragma unroll
        for (int c = 0; c < 8; ++c)
            g2l16(gsrc + (size_t)(c * 16 + srow) * 512 + kt + sko,
                  ldst + c * 512);
        __syncthreads();
        bf16x8 ah[4], al[4], bh[4], bl[4];
#pragma unroll
        for (int i = 0; i < 4; ++i) {
            ah[i] = *(const bf16x8*)&Ah[(mb + i * 16 + lm) * 32 + lq * 8];
            al[i] = *(const bf16x8*)&Al[(mb + i * 16 + lm) * 32 + lq * 8];
        }
#pragma unroll
        for (int j = 0; j < 4; ++j) {
            bh[j] = *(const bf16x8*)&Bh[(nb + j * 16 + lm) * 32 + lq * 8];
            bl[j] = *(const bf16x8*)&Bl[(nb + j * 16 + lm) * 32 + lq * 8];
        }
#pragma unroll
        for (int i = 0; i < 4; ++i)
#pragma unroll
            for (int j = 0; j < 4; ++j)
                acc[i][j] = mfma3(ah[i], al[i], bh[j], bl[j], acc[i][j]);
        __syncthreads();
    }
#pragma unroll
    for (int i = 0; i < 4; ++i)
#pragma unroll
        for (int j = 0; j < 4; ++j) {
            int r0 = m0 + mb + i * 16 + lq * 4;
            int c  = n0 + nb + j * 16 + lm;
            int which = c >> 9, h = (c >> 6) & 7, d = c & 63;
            int b = r0 >> 12, nbase = r0 & 4095;
            if (which == 2) {
                unsigned short hh[4], ll[4];
#pragma unroll
                for (int e = 0; e < 4; ++e) split2(acc[i][j][e], hh[e], ll[e]);
                uint2 ph, pl;
                ph.x = (unsigned)hh[0] | ((unsigned)hh[1] << 16);
                ph.y = (unsigned)hh[2] | ((unsigned)hh[3] << 16);
                pl.x = (unsigned)ll[0] | ((unsigned)ll[1] << 16);
                pl.y = (unsigned)ll[2] | ((unsigned)ll[3] << 16);
                size_t off = ((size_t)(b * 8 + h) * 64 + d) * 4096 + nbase;
                *(uint2*)&vTh[off] = ph;
                *(uint2*)&vTl[off] = pl;
            } else {
                unsigned short* Ph = which ? kh : qh;
                unsigned short* Pl = which ? kl : ql;
                float sc = which ? 1.0f : 0.125f;
#pragma unroll
                for (int e = 0; e < 4; ++e) {
                    unsigned short hh, ll;
                    split2(acc[i][j][e] * sc, hh, ll);
                    size_t off = (size_t)(b * 8 + h) * 262144 +
                                 (size_t)(nbase + e) * 64 + d;
                    Ph[off] = hh;
                    Pl[off] = ll;
                }
            }
        }
}

// ---------------------------------------------------------------------------
// final MFMA GEMM: out[16384,512] = OH planes (gathered) @ w_out planes.
// grid (4,128). global_load_lds staging incl. per-lane gather for A.
// ---------------------------------------------------------------------------
__global__ __launch_bounds__(256) void mfma_final(
    const unsigned short* __restrict__ OHh, const unsigned short* __restrict__ OHl,
    const unsigned short* __restrict__ WTh, const unsigned short* __restrict__ WTl,
    float* __restrict__ out) {
    __shared__ __align__(16) unsigned short Ah[128 * 32], Al[128 * 32];
    __shared__ __align__(16) unsigned short Bh[128 * 32], Bl[128 * 32];
    const int t = threadIdx.x;
    const int wave = t >> 6, lane = t & 63, lm = lane & 15, lq = lane >> 4;
    // XCD-aware bijective swizzle: nwg=512, 512/8=64 per XCD
    int orig = blockIdx.y * 4 + blockIdx.x;
    int wg = (orig & 7) * 64 + (orig >> 3);
    const int m0 = (wg >> 2) * 128, n0 = (wg & 3) * 128;
    const int mb = (wave >> 1) * 64, nb = (wave & 1) * 64;

    const bool isA = wave < 2;
    const unsigned short* gA = (wave == 0) ? OHh : OHl;
    const unsigned short* gB = (wave == 2) ? WTh : WTl;
    unsigned short* ldst = (wave == 0) ? Ah : (wave == 1) ? Al
                         : (wave == 2) ? Bh : Bl;
    const int srow = lane >> 2, sko = (lane & 3) * 8;
    // A-gather constants per chunk
    int gb[8], gn[8];
#pragma unroll
    for (int c = 0; c < 8; ++c) {
        int gr = m0 + c * 16 + srow;
        gb[c] = gr >> 12;
        gn[c] = gr & 4095;
    }

    f32x4 acc[4][4];
#pragma unroll
    for (int i = 0; i < 4; ++i)
#pragma unroll
        for (int j = 0; j < 4; ++j) acc[i][j] = (f32x4){0.f, 0.f, 0.f, 0.f};

    for (int kt = 0; kt < 512; kt += 32) {
        if (isA) {
            int kk = kt + sko;
            size_t koff = (size_t)(kk >> 6) * 262144 + (kk & 63);
#pragma unroll
            for (int c = 0; c < 8; ++c)
                g2l16(gA + (size_t)gb[c] * 2097152 + koff +
                          (size_t)gn[c] * 64,
                      ldst + c * 512);
        } else {
#pragma unroll
            for (int c = 0; c < 8; ++c)
                g2l16(gB + (size_t)(n0 + c * 16 + srow) * 512 + kt + sko,
                      ldst + c * 512);
        }
        __syncthreads();
        bf16x8 ah[4], al[4], bh[4], bl[4];
#pragma unroll
        for (int i = 0; i < 4; ++i) {
            ah[i] = *(const bf16x8*)&Ah[(mb + i * 16 + lm) * 32 + lq * 8];
            al[i] = *(const bf16x8*)&Al[(mb + i * 16 + lm) * 32 + lq * 8];
        }
#pragma unroll
        for (int j = 0; j < 4; ++j) {
            bh[j] = *(const bf16x8*)&Bh[(nb + j * 16 + lm) * 32 + lq * 8];
            bl[j] = *(const bf16x8*)&Bl[(nb + j * 16 + lm) * 32 + lq * 8];
        }
#pragma unroll
        for (int i = 0; i < 4; ++i)
#pragma unroll
            for (int j = 0; j < 4; ++j)
                acc[i][j] = mfma3(ah[i], al[i], bh[j], bl[j], acc[i][j]);
        __syncthreads();
    }
#pragma unroll
    for (int i = 0; i < 4; ++i)
#pragma unroll
        for (int j = 0; j < 4; ++j) {
            int r0 = m0 + mb + i * 16 + lq * 4;
            int c  = n0 + nb + j * 16 + lm;
#pragma unroll
            for (int e = 0; e < 4; ++e)
                out[(size_t)(r0 + e) * 512 + c] = acc[i][j][e];
        }
}

// ---------------------------------------------------------------------------
// F3 MFMA: t1 += exp(qland@k^T)@v, rs3 += rowsums. grid (8, 4, 32).
// ---------------------------------------------------------------------------
__global__ __launch_bounds__(256) void attn3v_mfma(
    const unsigned short* __restrict__ qlh, const unsigned short* __restrict__ qll,
    const unsigned short* __restrict__ kh_, const unsigned short* __restrict__ kl_,
    const unsigned short* __restrict__ vTh, const unsigned short* __restrict__ vTl,
    float* __restrict__ t1, float* __restrict__ rs3) {
    __shared__ unsigned short Qh[4608], Ql[4608];
    __shared__ unsigned short Kh[4608], Kl[4608];
    __shared__ unsigned short Eh[4608], El[4608];
    const int t = threadIdx.x;
    const int wave = t >> 6, lane = t & 63, lm = lane & 15, lq = lane >> 4;
    const int bz = blockIdx.z, m0 = blockIdx.y * 64, c0 = blockIdx.x * 8;
    const unsigned short* qhb = qlh + (size_t)bz * 16384;
    const unsigned short* qlb = qll + (size_t)bz * 16384;
    const unsigned short* khb = kh_ + (size_t)bz * 262144;
    const unsigned short* klb = kl_ + (size_t)bz * 262144;
    const unsigned short* vhb = vTh + (size_t)bz * 262144;
    const unsigned short* vlb = vTl + (size_t)bz * 262144;
#pragma unroll
    for (int r = 0; r < 2; ++r) {
        int id = t + r * 256, row = id >> 3, ko = (id & 7) * 8;
        *(uint4*)&Qh[row * 72 + ko] =
            *(const uint4*)(qhb + (size_t)(m0 + row) * 64 + ko);
        *(uint4*)&Ql[row * 72 + ko] =
            *(const uint4*)(qlb + (size_t)(m0 + row) * 64 + ko);
    }
    f32x4 acc[4];
#pragma unroll
    for (int j = 0; j < 4; ++j) acc[j] = (f32x4){0.f, 0.f, 0.f, 0.f};
    float rsum[4] = {0.f, 0.f, 0.f, 0.f};
    __syncthreads();

    for (int c = c0; c < c0 + 8; ++c) {
        const int tok0 = c * 64;
#pragma unroll
        for (int r = 0; r < 2; ++r) {
            int id = t + r * 256, row = id >> 3, ko = (id & 7) * 8;
            *(uint4*)&Kh[row * 72 + ko] =
                *(const uint4*)(khb + (size_t)(tok0 + row) * 64 + ko);
            *(uint4*)&Kl[row * 72 + ko] =
                *(const uint4*)(klb + (size_t)(tok0 + row) * 64 + ko);
        }
        __syncthreads();
        bf16x8 a0  = *(const bf16x8*)&Qh[(wave * 16 + lm) * 72 + lq * 8];
        bf16x8 a0l = *(const bf16x8*)&Ql[(wave * 16 + lm) * 72 + lq * 8];
        bf16x8 a1  = *(const bf16x8*)&Qh[(wave * 16 + lm) * 72 + 32 + lq * 8];
        bf16x8 a1l = *(const bf16x8*)&Ql[(wave * 16 + lm) * 72 + 32 + lq * 8];
        f32x4 s[4];
#pragma unroll
        for (int j = 0; j < 4; ++j) s[j] = (f32x4){0.f, 0.f, 0.f, 0.f};
#pragma unroll
        for (int j = 0; j < 4; ++j) {
            bf16x8 b0  = *(const bf16x8*)&Kh[(j * 16 + lm) * 72 + lq * 8];
            bf16x8 b0l = *(const bf16x8*)&Kl[(j * 16 + lm) * 72 + lq * 8];
            bf16x8 b1  = *(const bf16x8*)&Kh[(j * 16 + lm) * 72 + 32 + lq * 8];
            bf16x8 b1l = *(const bf16x8*)&Kl[(j * 16 + lm) * 72 + 32 + lq * 8];
            s[j] = mfma3(a0, a0l, b0, b0l, s[j]);
            s[j] = mfma3(a1, a1l, b1, b1l, s[j]);
        }
        __syncthreads();
#pragma unroll
        for (int j = 0; j < 4; ++j)
#pragma unroll
            for (int e = 0; e < 4; ++e) {
                float ev = __expf(s[j][e]);
                rsum[e] += ev;
                unsigned short h, l;
                split2(ev, h, l);
                int off = (wave * 16 + lq * 4 + e) * 72 + j * 16 + lm;
                Eh[off] = h;
                El[off] = l;
            }
#pragma unroll
        for (int r = 0; r < 2; ++r) {
            int id = t + r * 256, dh = id >> 3, t8 = (id & 7) * 8;
            *(uint4*)&Kh[dh * 72 + t8] =
                *(const uint4*)(vhb + (size_t)dh * 4096 + tok0 + t8);
            *(uint4*)&Kl[dh * 72 + t8] =
                *(const uint4*)(vlb + (size_t)dh * 4096 + tok0 + t8);
        }
        __syncthreads();
        bf16x8 e0  = *(const bf16x8*)&Eh[(wave * 16 + lm) * 72 + lq * 8];
        bf16x8 e0l = *(const bf16x8*)&El[(wave * 16 + lm) * 72 + lq * 8];
        bf16x8 e1  = *(const bf16x8*)&Eh[(wave * 16 + lm) * 72 + 32 + lq * 8];
        bf16x8 e1l = *(const bf16x8*)&El[(wave * 16 + lm) * 72 + 32 + lq * 8];
#pragma unroll
        for (int j = 0; j < 4; ++j) {
            bf16x8 v0  = *(const bf16x8*)&Kh[(j * 16 + lm) * 72 + lq * 8];
            bf16x8 v0l = *(const bf16x8*)&Kl[(j * 16 + lm) * 72 + lq * 8];
            bf16x8 v1  = *(const bf16x8*)&Kh[(j * 16 + lm) * 72 + 32 + lq * 8];
            bf16x8 v1l = *(const bf16x8*)&Kl[(j * 16 + lm) * 72 + 32 + lq * 8];
            acc[j] = mfma3(e0, e0l, v0, v0l, acc[j]);
            acc[j] = mfma3(e1, e1l, v1, v1l, acc[j]);
        }
        __syncthreads();
    }
    float* t1b = t1 + (size_t)bz * 16384;
#pragma unroll
    for (int j = 0; j < 4; ++j)
#pragma unroll
        for (int e = 0; e < 4; ++e)
            atomicAdd(t1b + (size_t)(m0 + wave * 16 + lq * 4 + e) * 64 +
                          j * 16 + lm,
                      acc[j][e]);
#pragma unroll
    for (int e = 0; e < 4; ++e) {
        float vs = rsum[e];
        for (int mm = 1; mm < 16; mm <<= 1) vs += __shfl_xor(vs, mm);
        if (lm == 0)
            atomicAdd(rs3 + bz * 256 + m0 + wave * 16 + lq * 4 + e, vs);
    }
}

// ---------------------------------------------------------------------------
// F1 MFMA + fused depthwise conv: OH planes = softmax(q@kland^T)@t2 + conv(v).
// After the PV loop the Q/K LDS region is dead -> re-used as the fp32 v
// window Vs[96][65]. grid (64, 32).
// ---------------------------------------------------------------------------
__global__ __launch_bounds__(256) void attn1t2_conv(
    const unsigned short* __restrict__ qh_, const unsigned short* __restrict__ ql_,
    const unsigned short* __restrict__ klh, const unsigned short* __restrict__ kll,
    const unsigned short* __restrict__ t2Th, const unsigned short* __restrict__ t2Tl,
    const unsigned short* __restrict__ vTh, const unsigned short* __restrict__ vTl,
    const float* __restrict__ wres,
    unsigned short* __restrict__ OHh, unsigned short* __restrict__ OHl) {
    __shared__ __align__(16) unsigned short SH[27648];   // 55296 B
    unsigned short* Qh = SH;
    unsigned short* Ql = SH + 4608;
    unsigned short* Kh = SH + 9216;
    unsigned short* Kl = SH + 13824;
    unsigned short* Eh = SH + 18432;
    unsigned short* El = SH + 23040;
    __shared__ float Ws[33];
    const int t = threadIdx.x;
    const int wave = t >> 6, lane = t & 63, lm = lane & 15, lq = lane >> 4;
    const int bz = blockIdx.y, m0 = blockIdx.x * 64;
    if (t < 33) Ws[t] = wres[(bz & 7) * 33 + t];
    const unsigned short* qhb = qh_ + (size_t)bz * 262144;
    const unsigned short* qlb = ql_ + (size_t)bz * 262144;
    const unsigned short* khb = klh + (size_t)bz * 16384;
    const unsigned short* klb = kll + (size_t)bz * 16384;
    const unsigned short* t2h = t2Th + (size_t)bz * 16384;
    const unsigned short* t2l = t2Tl + (size_t)bz * 16384;
#pragma unroll
    for (int r = 0; r < 2; ++r) {
        int id = t + r * 256, row = id >> 3, ko = (id & 7) * 8;
        *(uint4*)&Qh[row * 72 + ko] =
            *(const uint4*)(qhb + (size_t)(m0 + row) * 64 + ko);
        *(uint4*)&Ql[row * 72 + ko] =
            *(const uint4*)(qlb + (size_t)(m0 + row) * 64 + ko);
    }
    f32x4 acc[4];
#pragma unroll
    for (int j = 0; j < 4; ++j) acc[j] = (f32x4){0.f, 0.f, 0.f, 0.f};
    float rsum[4] = {0.f, 0.f, 0.f, 0.f};
    __syncthreads();

    for (int lc = 0; lc < 4; ++lc) {
        const int l0 = lc * 64;
#pragma unroll
        for (int r = 0; r < 2; ++r) {
            int id = t + r * 256, row = id >> 3, ko = (id & 7) * 8;
            *(uint4*)&Kh[row * 72 + ko] =
                *(const uint4*)(khb + (size_t)(l0 + row) * 64 + ko);
            *(uint4*)&Kl[row * 72 + ko] =
                *(const uint4*)(klb + (size_t)(l0 + row) * 64 + ko);
        }
        __syncthreads();
        bf16x8 a0  = *(const bf16x8*)&Qh[(wave * 16 + lm) * 72 + lq * 8];
        bf16x8 a0l = *(const bf16x8*)&Ql[(wave * 16 + lm) * 72 + lq * 8];
        bf16x8 a1  = *(const bf16x8*)&Qh[(wave * 16 + lm) * 72 + 32 + lq * 8];
        bf16x8 a1l = *(const bf16x8*)&Ql[(wave * 16 + lm) * 72 + 32 + lq * 8];
        f32x4 s[4];
#pragma unroll
        for (int j = 0; j < 4; ++j) s[j] = (f32x4){0.f, 0.f, 0.f, 0.f};
#pragma unroll
        for (int j = 0; j < 4; ++j) {
            bf16x8 b0  = *(const bf16x8*)&Kh[(j * 16 + lm) * 72 + lq * 8];
            bf16x8 b0l = *(const bf16x8*)&Kl[(j * 16 + lm) * 72 + lq * 8];
            bf16x8 b1  = *(const bf16x8*)&Kh[(j * 16 + lm) * 72 + 32 + lq * 8];
            bf16x8 b1l = *(const bf16x8*)&Kl[(j * 16 + lm) * 72 + 32 + lq * 8];
            s[j] = mfma3(a0, a0l, b0, b0l, s[j]);
            s[j] = mfma3(a1, a1l, b1, b1l, s[j]);
        }
        __syncthreads();
#pragma unroll
        for (int j = 0; j < 4; ++j)
#pragma unroll
            for (int e = 0; e < 4; ++e) {
                float ev = __expf(s[j][e]);
                rsum[e] += ev;
                unsigned short h, l;
                split2(ev, h, l);
                int off = (wave * 16 + lq * 4 + e) * 72 + j * 16 + lm;
                Eh[off] = h;
                El[off] = l;
            }
#pragma unroll
        for (int r = 0; r < 2; ++r) {
            int id = t + r * 256, dh = id >> 3, t8 = (id & 7) * 8;
            *(uint4*)&Kh[dh * 72 + t8] =
                *(const uint4*)(t2h + (size_t)dh * 256 + l0 + t8);
            *(uint4*)&Kl[dh * 72 + t8] =
                *(const uint4*)(t2l + (size_t)dh * 256 + l0 + t8);
        }
        __syncthreads();
        bf16x8 e0  = *(const bf16x8*)&Eh[(wave * 16 + lm) * 72 + lq * 8];
        bf16x8 e0l = *(const bf16x8*)&El[(wave * 16 + lm) * 72 + lq * 8];
        bf16x8 e1  = *(const bf16x8*)&Eh[(wave * 16 + lm) * 72 + 32 + lq * 8];
        bf16x8 e1l = *(const bf16x8*)&El[(wave * 16 + lm) * 72 + 32 + lq * 8];
#pragma unroll
        for (int j = 0; j < 4; ++j) {
            bf16x8 v0  = *(const bf16x8*)&Kh[(j * 16 + lm) * 72 + lq * 8];
            bf16x8 v0l = *(const bf16x8*)&Kl[(j * 16 + lm) * 72 + lq * 8];
            bf16x8 v1  = *(const bf16x8*)&Kh[(j * 16 + lm) * 72 + 32 + lq * 8];
            bf16x8 v1l = *(const bf16x8*)&Kl[(j * 16 + lm) * 72 + 32 + lq * 8];
            acc[j] = mfma3(e0, e0l, v0, v0l, acc[j]);
            acc[j] = mfma3(e1, e1l, v1, v1l, acc[j]);
        }
        __syncthreads();
    }
    float rinv[4];
#pragma unroll
    for (int e = 0; e < 4; ++e) {
        float vs = rsum[e];
        for (int mm = 1; mm < 16; mm <<= 1) vs += __shfl_xor(vs, mm);
        rinv[e] = 1.0f / vs;
    }

    // ---- fused conv: stage v window [m0-16, m0+80) into dead Q/K LDS ----
    __syncthreads();
    float* Vs = (float*)SH;                      // 96 x 65 fp32 = 24960 B
    const unsigned short* vhb = vTh + (size_t)bz * 262144;
    const unsigned short* vlb = vTl + (size_t)bz * 262144;
#pragma unroll
    for (int r = 0; r < 3; ++r) {
        int id = t + r * 256;                    // 0..767 = 64 dh x 12 chunks
        int d = id / 12, ch = id - d * 12;
        int n = m0 - 16 + ch * 8;
        uint4 h4 = make_uint4(0u, 0u, 0u, 0u);
        uint4 l4 = make_uint4(0u, 0u, 0u, 0u);
        if ((unsigned)n < 4096u) {
            h4 = *(const uint4*)(vhb + (size_t)d * 4096 + n);
            l4 = *(const uint4*)(vlb + (size_t)d * 4096 + n);
        }
        const unsigned short* hp = (const unsigned short*)&h4;
        const unsigned short* lp = (const unsigned short*)&l4;
#pragma unroll
        for (int i = 0; i < 8; ++i)
            Vs[(ch * 8 + i) * 65 + d] = b2f(hp[i]) + b2f(lp[i]);
    }
    __syncthreads();
    unsigned short* Hh = OHh + (size_t)bz * 262144;
    unsigned short* Hl = OHl + (size_t)bz * 262144;
    const int rbase = wave * 16 + lq * 4;
#pragma unroll
    for (int j = 0; j < 4; ++j) {
        int cc = j * 16 + lm;
        float w[36];
#pragma unroll
        for (int u = 0; u < 36; ++u) w[u] = Vs[(rbase + u) * 65 + cc];
#pragma unroll
        for (int e = 0; e < 4; ++e) {
            float cv = 0.f;
#pragma unroll
            for (int tt = 0; tt < 33; ++tt) cv += w[e + tt] * Ws[tt];
            float o = acc[j][e] * rinv[e] + cv;
            unsigned short hh, ll;
            split2(o, hh, ll);
            size_t off = (size_t)(m0 + rbase + e) * 64 + cc;
            Hh[off] = hh;
            Hl[off] = ll;
        }
    }
}

// ---------------------------------------------------------------------------
// fp32 gemm for attn2 scores
// ---------------------------------------------------------------------------
__global__ __launch_bounds__(256) void gemm_a2(
    const float* __restrict__ A, const float* __restrict__ B,
    float* __restrict__ C) {
    __shared__ float As[16 * 68];
    __shared__ float Bs[16 * 68];
    const int t  = threadIdx.x;
    const int z  = blockIdx.z;
    const int m0 = blockIdx.y * 64;
    const int n0 = blockIdx.x * 64;
    const float* Ab = A + (size_t)z * 16384;
    const float* Bb = B + (size_t)z * 16384;
    float*       Cb = C + (size_t)z * 65536;
    const int tx4 = (t & 15) * 4;
    const int ty4 = (t >> 4) * 4;
    const int ar  = t >> 2, ak = (t & 3) * 4;
    float acc[4][4] = {};
    for (int kt = 0; kt < 64; kt += 16) {
        float4 av = *(const float4*)(Ab + (size_t)(m0 + ar) * 64 + kt + ak);
        float4 bv = *(const float4*)(Bb + (size_t)(n0 + ar) * 64 + kt + ak);
        As[(ak + 0) * 68 + ar] = av.x;
        As[(ak + 1) * 68 + ar] = av.y;
        As[(ak + 2) * 68 + ar] = av.z;
        As[(ak + 3) * 68 + ar] = av.w;
        Bs[(ak + 0) * 68 + ar] = bv.x;
        Bs[(ak + 1) * 68 + ar] = bv.y;
        Bs[(ak + 2) * 68 + ar] = bv.z;
        Bs[(ak + 3) * 68 + ar] = bv.w;
        __syncthreads();
        mt16(As, Bs, ty4, tx4, acc);
        __syncthreads();
    }
#pragma unroll
    for (int u = 0; u < 4; ++u) {
        int row = m0 + ty4 + u;
        *(float4*)(Cb + (size_t)row * 256 + n0 + tx4) =
            make_float4(acc[u][0], acc[u][1], acc[u][2], acc[u][3]);
    }
}

// ---------------------------------------------------------------------------
// small kernels
// ---------------------------------------------------------------------------
__global__ void zero_f(float* __restrict__ p, int n) {
    int i = blockIdx.x * 256 + threadIdx.x;
    if (i < n) p[i] = 0.f;
}

// both landmark means in one dispatch. grid 4096.
__global__ void landmark_mean2(
    const unsigned short* __restrict__ qh, const unsigned short* __restrict__ ql,
    const unsigned short* __restrict__ kh, const unsigned short* __restrict__ kl,
    float* __restrict__ qland, float* __restrict__ kland,
    unsigned short* __restrict__ qlh, unsigned short* __restrict__ qll,
    unsigned short* __restrict__ klh, unsigned short* __restrict__ kll) {
    int o = blockIdx.x * 256 + threadIdx.x;
    bool isq = o < 524288;
    int oo = isq ? o : o - 524288;
    const unsigned short* sh = isq ? qh : kh;
    const unsigned short* sl = isq ? ql : kl;
    float* dst = isq ? qland : kland;
    unsigned short* dh = isq ? qlh : klh;
    unsigned short* dl = isq ? qll : kll;
    int d = oo & 63, m = (oo >> 6) & 255, bh = oo >> 14;
    size_t base = (size_t)bh * 262144 + (size_t)m * 1024 + d;
    float acc = 0.f;
#pragma unroll
    for (int j = 0; j < 16; ++j)
        acc += b2f(sh[base + j * 64]) + b2f(sl[base + j * 64]);
    float v = acc * (1.0f / 16.0f);
    dst[oo] = v;
    unsigned short h, l;
    split2(v, h, l);
    dh[oo] = h;
    dl[oo] = l;
}

// softmax + emit a2 normal/transposed planes + colsum atomics. grid 8192.
__global__ void softmax_fused(const float* __restrict__ a,
                              unsigned short* __restrict__ A2Ph,
                              unsigned short* __restrict__ A2Pl,
                              unsigned short* __restrict__ A2Th,
                              unsigned short* __restrict__ A2Tl,
                              float* __restrict__ colsum) {
    __shared__ float red[256];
    int row = blockIdx.x, t = threadIdx.x;
    float v = a[(size_t)row * 256 + t];
    red[t] = v;
    __syncthreads();
    for (int s = 128; s > 0; s >>= 1) {
        if (t < s) red[t] = fmaxf(red[t], red[t + s]);
        __syncthreads();
    }
    float mx = red[0];
    __syncthreads();
    float e = __expf(v - mx);
    red[t] = e;
    __syncthreads();
    for (int s = 128; s > 0; s >>= 1) {
        if (t < s) red[t] += red[t + s];
        __syncthreads();
    }
    float val = e / red[0];
    int z = row >> 8, r = row & 255;
    atomicAdd(&colsum[z * 256 + t], val);
    unsigned short h, l;
    split2(val, h, l);
    size_t zo = (size_t)z * 65536;
    A2Ph[zo + (size_t)r * 256 + t] = h;
    A2Pl[zo + (size_t)r * 256 + t] = l;
    A2Th[zo + (size_t)t * 256 + r] = h;
    A2Tl[zo + (size_t)t * 256 + r] = l;
}

// global max over colsum -> scal[0]. grid 32.
__global__ void scal_max(const float* __restrict__ colsum,
                         float* __restrict__ scal) {
    __shared__ float red[256];
    int t = threadIdx.x;
    red[t] = colsum[blockIdx.x * 256 + t];
    __syncthreads();
    for (int s = 128; s > 0; s >>= 1) {
        if (t < s) red[t] = fmaxf(red[t], red[t + s]);
        __syncthreads();
    }
    if (t == 0) atomicMax((unsigned int*)&scal[0], __float_as_uint(red[0]));
}

// ---------------------------------------------------------------------------
extern "C" void kernel_launch(void* const* d_in, const int* in_sizes, int n_in,
                              void* d_out, int out_size, void* d_ws, size_t ws_size,
                              hipStream_t stream) {
    const float* x     = (const float*)d_in[0];
    const float* w_qkv = (const float*)d_in[1];
    const float* w_out = (const float*)d_in[2];
    const float* w_res = (const float*)d_in[3];
    float* out = (float*)d_out;
    float* ws  = (float*)d_ws;

    // planes (ushort units)
    unsigned short* Xh  = (unsigned short*)(ws + O_XP);
    unsigned short* Xl  = Xh + 8388608;
    unsigned short* qh  = (unsigned short*)(ws + O_QP);
    unsigned short* ql  = qh + 8388608;
    unsigned short* kh  = (unsigned short*)(ws + O_KP);
    unsigned short* kl  = kh + 8388608;
    unsigned short* vTh = (unsigned short*)(ws + O_VT);
    unsigned short* vTl = vTh + 8388608;
    unsigned short* qlh = (unsigned short*)(ws + O_QLP);
    unsigned short* qll = qlh + 524288;
    unsigned short* klh = (unsigned short*)(ws + O_KLP);
    unsigned short* kll = klh + 524288;

    float* qland = ws + O_QL;
    float* kland = ws + O_KL;
    float* attn2 = ws + O_A2;
    float* t1    = ws + O_T1;
    float* rs3   = ws + O_RS3;
    float* scal  = ws + O_SCAL;
    float* colsum= ws + O_CS;

    // pinv plane pool A: k-plane region (dead after attn3v)
    unsigned short* PBu  = (unsigned short*)(ws + O_KP);
    unsigned short* A2Ph = PBu + 0;
    unsigned short* A2Pl = PBu + 2097152;
    unsigned short* XZNh = PBu + 4194304;
    unsigned short* XZNl = PBu + 6291456;
    unsigned short* XZTh = PBu + 8388608;
    unsigned short* XZTl = PBu + 10485760;
    unsigned short* Y1Th = PBu + 12582912;
    unsigned short* Y1Tl = PBu + 14680064;
    // pinv plane pool B: X-plane region (dead after qkv)
    unsigned short* XRu  = (unsigned short*)(ws + O_XP);
    unsigned short* ZNah = XRu + 0;            // also hosts A2T (pre-iter2)
    unsigned short* ZNal = XRu + 2097152;
    unsigned short* ZNbh = XRu + 4194304;
    unsigned short* ZNbl = XRu + 6291456;
    unsigned short* ZTh_ = XRu + 8388608;
    unsigned short* ZTl_ = XRu + 10485760;
    unsigned short* Y2Th = XRu + 12582912;
    unsigned short* Y2Tl = XRu + 14680064;
    unsigned short* A2Th = ZNah;               // a2^T planes (z0 * denom)
    unsigned short* A2Tl = ZNal;
    // post-pinv aliases
    unsigned short* t2Th = (unsigned short*)(ws + O_QL);   // qland dead
    unsigned short* t2Tl = t2Th + 524288;
    unsigned short* OHh = PBu;                 // pool A dead after pinv
    unsigned short* OHl = PBu + 8388608;

    unsigned short* WQTh = (unsigned short*)(ws + O_WQT);
    unsigned short* WQTl = WQTh + 786432;
    unsigned short* WOTh = (unsigned short*)(ws + O_WOT);
    unsigned short* WOTl = WOTh + 262144;

    zero_f<<<2113, 256, 0, stream>>>(t1, 540688);   // t1+rs3+scal+colsum
    wtrans2<<<4096, 256, 0, stream>>>(w_qkv, w_out, WQTh, WQTl, WOTh, WOTl);
    xsplit<<<8192, 256, 0, stream>>>(x, Xh, Xl);

    mfma_qkv<<<dim3(12, 128), 256, 0, stream>>>(Xh, Xl, WQTh, WQTl,
                                                qh, ql, kh, kl, vTh, vTl);

    landmark_mean2<<<4096, 256, 0, stream>>>(qh, ql, kh, kl, qland, kland,
                                             qlh, qll, klh, kll);

    // F3 first: consumes k planes (pool A overwritten by softmax_fused next)
    attn3v_mfma<<<dim3(8, 4, 32), 256, 0, stream>>>(qlh, qll, kh, kl,
                                                    vTh, vTl, t1, rs3);

    gemm_a2<<<dim3(4, 4, 32), 256, 0, stream>>>(qland, kland, attn2);
    softmax_fused<<<8192, 256, 0, stream>>>(attn2, A2Ph, A2Pl, A2Th, A2Tl,
                                            colsum);
    scal_max<<<32, 256, 0, stream>>>(colsum, scal);

    // pinv: 6x4 all-plane stages (zinit folded into SC modes)
    unsigned short* ZNh[2] = {ZNah, ZNbh};
    unsigned short* ZNl[2] = {ZNal, ZNbl};
    int cur = 0;
    const dim3 pg(4, 4, 32);
    for (int it = 0; it < 6; ++it) {
        if (it == 0) {
            // xz = (1/denom) * (a2 @ a2^T)
            mfma_gemm_p<0, 1, true, true><<<pg, 256, 0, stream>>>(
                A2Ph, A2Pl, A2Ph, A2Pl, XZNh, XZNl, XZTh, XZTl,
                0.f, 0.f, scal);
        } else {
            mfma_gemm_p<0, 0, true, true><<<pg, 256, 0, stream>>>(
                A2Ph, A2Pl, ZTh_, ZTl_, XZNh, XZNl, XZTh, XZTl,
                1.f, 0.f, scal);
        }
        // Y1 = -xz@xz + 7*xz
        mfma_gemm_p<1, 0, false, true><<<pg, 256, 0, stream>>>(
            XZNh, XZNl, XZTh, XZTl, nullptr, nullptr, Y1Th, Y1Tl,
            -1.f, 7.f, scal);
        // Y2 = -xz@Y1 + 15*xz
        mfma_gemm_p<1, 0, false, true><<<pg, 256, 0, stream>>>(
            XZNh, XZNl, Y1Th, Y1Tl, nullptr, nullptr, Y2Th, Y2Tl,
            -1.f, 15.f, scal);
        // z' = -0.25*z@Y2 + 3.25*z
        if (it == 0) {
            // z = a2^T/denom: A = A2T, whole result scaled by 1/denom (SC=2)
            mfma_gemm_p<1, 2, true, true><<<pg, 256, 0, stream>>>(
                A2Th, A2Tl, Y2Th, Y2Tl, ZNbh, ZNbl, ZTh_, ZTl_,
                -0.25f, 3.25f, scal);
            cur = 1;
        } else {
            mfma_gemm_p<1, 0, true, true><<<pg, 256, 0, stream>>>(
                ZNh[cur], ZNl[cur], Y2Th, Y2Tl, ZNh[1 - cur], ZNl[1 - cur],
                ZTh_, ZTl_, -0.25f, 3.25f, scal);
            cur = 1 - cur;
        }
    }
    // zfin = ZN[0] (it1:->0, it2:->1, it3:->0, it4:->1, it5:->0)

    // t2 = zfin @ (t1 / rs3); t2^T planes into dead qland region
    t2_gemm<<<dim3(1, 4, 32), 256, 0, stream>>>(ZNh[0], ZNl[0], t1, rs3,
                                                t2Th, t2Tl);

    // F1 + conv fused -> OH planes (pool A, fully dead now)
    attn1t2_conv<<<dim3(64, 32), 256, 0, stream>>>(qh, ql, klh, kll,
                                                   t2Th, t2Tl, vTh, vTl,
                                                   w_res, OHh, OHl);

    mfma_final<<<dim3(4, 128), 256, 0, stream>>>(OHh, OHl, WOTh, WOTl, out);

    (void)in_sizes; (void)n_in; (void)out_size; (void)ws_size;
}

// Round 7
// 765.327 us; speedup vs baseline: 1.6329x; 1.0160x over previous
//
#include <hip/hip_runtime.h>

// ---------------------------------------------------------------------------
// Nystrom attention: split-bf16 (hi/lo, 3xMFMA) everywhere.
// R12: minimum 2-phase double-buffered LDS (T3 recipe) on mfma_qkv,
// mfma_final, and all pinv stages. Per K-step: issue next-tile
// global_load_lds into buf^1 BEFORE computing buf, single __syncthreads
// per tile (its vmcnt(0) drain = the post-compute prefetch drain).
// Standard barriers only -> worst case neutral, never wrong.
// LDS: qkv/final 64 KB, pinv 32 KB. Everything else as R11.
// B=4, N=4096, DIM=512, H=8, DH=64, M=256, l=16, 6 pinv iters, conv K=33.
// ---------------------------------------------------------------------------

typedef __attribute__((ext_vector_type(8))) short bf16x8;
typedef __attribute__((ext_vector_type(4))) float f32x4;

// workspace layout (float units)
constexpr size_t O_XP  = 0;          // Xh/Xl planes; later pool B (ZN/ZT/Y2T, A2T)
constexpr size_t O_QP  = 8388608;    // q planes (hi/lo)
constexpr size_t O_KP  = 16777216;   // k planes; later pool A (A2P/XZN/XZT/Y1T); later OH planes
constexpr size_t O_VT  = 25165824;   // vT planes
constexpr size_t O_QL  = 33554432;   // qland fp32; later t2T planes
constexpr size_t O_KL  = 34078720;   // kland fp32
constexpr size_t O_QLP = 34603008;   // qland planes
constexpr size_t O_KLP = 35127296;   // kland planes
constexpr size_t O_A2  = 35651584;   // attn2 fp32 (pre-softmax scores)
constexpr size_t O_T1  = 37748736;
constexpr size_t O_RS3 = 38273024;
constexpr size_t O_SCAL= 38281216;
constexpr size_t O_CS  = 38281232;   // colsum [32][256]
constexpr size_t O_WQT = 38805520;
constexpr size_t O_WOT = 39591952;
constexpr size_t O_END = 39854096;   // ~159.4 MB

// ---------------------------------------------------------------------------
__device__ __forceinline__ void split2(float x, unsigned short& h,
                                       unsigned short& l) {
    unsigned u  = __float_as_uint(x);
    unsigned hb = (u + 0x7FFFu + ((u >> 16) & 1u)) & 0xFFFF0000u;  // RNE hi
    h = (unsigned short)(hb >> 16);
    float d = x - __uint_as_float(hb);
    l = (unsigned short)(__float_as_uint(d) >> 16);
}

__device__ __forceinline__ float b2f(unsigned short s) {
    return __uint_as_float((unsigned)s << 16);
}

__device__ __forceinline__ f32x4 mfma3(bf16x8 ah, bf16x8 al, bf16x8 bh,
                                       bf16x8 bl, f32x4 c) {
    c = __builtin_amdgcn_mfma_f32_16x16x32_bf16(ah, bh, c, 0, 0, 0);
    c = __builtin_amdgcn_mfma_f32_16x16x32_bf16(ah, bl, c, 0, 0, 0);
    c = __builtin_amdgcn_mfma_f32_16x16x32_bf16(al, bh, c, 0, 0, 0);
    return c;
}

// async global->LDS, 16 B per lane (gfx950). LDS dest = uniform base + lane*16.
__device__ __forceinline__ void g2l16(const unsigned short* g,
                                      unsigned short* l) {
    __builtin_amdgcn_global_load_lds(
        (const __attribute__((address_space(1))) void*)g,
        (__attribute__((address_space(3))) void*)l, 16, 0, 0);
}

// split a float4 into hi/lo planes, write packed uint2 at H[off], L[off]
__device__ __forceinline__ void stage_split4(float4 av, unsigned short* H,
                                             unsigned short* L, int off) {
    unsigned short h0, h1, h2, h3, l0, l1, l2, l3;
    split2(av.x, h0, l0); split2(av.y, h1, l1);
    split2(av.z, h2, l2); split2(av.w, h3, l3);
    uint2 ph, pl;
    ph.x = (unsigned)h0 | ((unsigned)h1 << 16);
    ph.y = (unsigned)h2 | ((unsigned)h3 << 16);
    pl.x = (unsigned)l0 | ((unsigned)l1 << 16);
    pl.y = (unsigned)l2 | ((unsigned)l3 << 16);
    *(uint2*)&H[off] = ph;
    *(uint2*)&L[off] = pl;
}

// ---------------------------------------------------------------------------
// X -> split planes (one-time)
// ---------------------------------------------------------------------------
__global__ void xsplit(const float* __restrict__ X,
                       unsigned short* __restrict__ Xh,
                       unsigned short* __restrict__ Xl) {
    int idx = blockIdx.x * 256 + threadIdx.x;
    float4 v = *(const float4*)(X + (size_t)idx * 4);
    stage_split4(v, Xh, Xl, idx * 4);
}

// ---------------------------------------------------------------------------
// both weight transposes in one dispatch. grid 4096.
// ---------------------------------------------------------------------------
__global__ void wtrans2(const float* __restrict__ Wq,
                        const float* __restrict__ Wo,
                        unsigned short* __restrict__ QTh,
                        unsigned short* __restrict__ QTl,
                        unsigned short* __restrict__ OTh,
                        unsigned short* __restrict__ OTl) {
    int idx = blockIdx.x * 256 + threadIdx.x;
    unsigned short h, l;
    if (idx < 786432) {
        int n = idx >> 9, kk = idx & 511;
        split2(Wq[(size_t)kk * 1536 + n], h, l);
        QTh[idx] = h;
        QTl[idx] = l;
    } else {
        int j = idx - 786432;
        int n = j >> 9, kk = j & 511;
        split2(Wo[(size_t)kk * 512 + n], h, l);
        OTh[j] = h;
        OTl[j] = l;
    }
}

// ---------------------------------------------------------------------------
// All-plane pinv GEMM stage: C = alpha*(A@B) + beta*A_elem.
// SC=0: as-is. SC=1: alpha := 1/denom (EPI=0). SC=2: whole result *= 1/denom.
// A = normal planes AN[m][k]; B = transposed planes BT[n][k].
// 2-phase double-buffered global_load_lds staging. grid (4,4,32), 256 thr.
// ---------------------------------------------------------------------------
template <int EPI, int SC, bool WN, bool WTT>
__global__ __launch_bounds__(256) void mfma_gemm_p(
    const unsigned short* __restrict__ ANh, const unsigned short* __restrict__ ANl,
    const unsigned short* __restrict__ BTh, const unsigned short* __restrict__ BTl,
    unsigned short* __restrict__ CNh, unsigned short* __restrict__ CNl,
    unsigned short* __restrict__ CTh, unsigned short* __restrict__ CTl,
    float alpha, float beta, const float* __restrict__ scal) {
    __shared__ __align__(16) unsigned short Ah[2][2048], Al[2][2048];
    __shared__ __align__(16) unsigned short Bh[2][2048], Bl[2][2048];
    const int t = threadIdx.x;
    const int wave = t >> 6, lane = t & 63, lm = lane & 15, lq = lane >> 4;
    const int z = blockIdx.z;
    const int m0 = blockIdx.y * 64, n0 = blockIdx.x * 64;
    const size_t zo = (size_t)z * 65536;

    // staging role: wave 0->Ah, 1->Al, 2->Bh, 3->Bl
    const unsigned short* gsrc;
    unsigned short (*ldst)[2048];
    if (wave == 0)      { gsrc = ANh + zo + (size_t)m0 * 256; ldst = Ah; }
    else if (wave == 1) { gsrc = ANl + zo + (size_t)m0 * 256; ldst = Al; }
    else if (wave == 2) { gsrc = BTh + zo + (size_t)n0 * 256; ldst = Bh; }
    else                { gsrc = BTl + zo + (size_t)n0 * 256; ldst = Bl; }
    const int srow = lane >> 2, sko = (lane & 3) * 8;

    auto stage = [&](int b, int kt) {
#pragma unroll
        for (int c = 0; c < 4; ++c)
            g2l16(gsrc + (size_t)(c * 16 + srow) * 256 + kt + sko,
                  &ldst[b][c * 512]);
    };

    f32x4 acc[4];
#pragma unroll
    for (int j = 0; j < 4; ++j) acc[j] = (f32x4){0.f, 0.f, 0.f, 0.f};

    stage(0, 0);
    __syncthreads();
    int cur = 0;
    for (int kt = 0; kt < 256; kt += 32) {
        if (kt + 32 < 256) stage(cur ^ 1, kt + 32);
        bf16x8 ah = *(const bf16x8*)&Ah[cur][(wave * 16 + lm) * 32 + lq * 8];
        bf16x8 al = *(const bf16x8*)&Al[cur][(wave * 16 + lm) * 32 + lq * 8];
#pragma unroll
        for (int j = 0; j < 4; ++j) {
            bf16x8 bh = *(const bf16x8*)&Bh[cur][(j * 16 + lm) * 32 + lq * 8];
            bf16x8 bl = *(const bf16x8*)&Bl[cur][(j * 16 + lm) * 32 + lq * 8];
            acc[j] = mfma3(ah, al, bh, bl, acc[j]);
        }
        __syncthreads();
        cur ^= 1;
    }

    const float scv = (SC != 0) ? 1.0f / (scal[0] + 1e-8f) : 1.0f;
    const float a = (SC == 1) ? scv : alpha;
    const int r0 = m0 + wave * 16 + lq * 4;
#pragma unroll
    for (int j = 0; j < 4; ++j) {
        int c = n0 + j * 16 + lm;
        float vals[4];
#pragma unroll
        for (int e = 0; e < 4; ++e) {
            float v = a * acc[j][e];
            if (EPI == 1) {
                size_t ao = zo + (size_t)(r0 + e) * 256 + c;
                v += beta * (b2f(ANh[ao]) + b2f(ANl[ao]));
            }
            if (SC == 2) v *= scv;
            vals[e] = v;
        }
        unsigned short hh[4], ll[4];
#pragma unroll
        for (int e = 0; e < 4; ++e) split2(vals[e], hh[e], ll[e]);
        if (WN) {
#pragma unroll
            for (int e = 0; e < 4; ++e) {
                size_t o = zo + (size_t)(r0 + e) * 256 + c;
                CNh[o] = hh[e];
                CNl[o] = ll[e];
            }
        }
        if (WTT) {
            uint2 ph, pl;
            ph.x = (unsigned)hh[0] | ((unsigned)hh[1] << 16);
            ph.y = (unsigned)hh[2] | ((unsigned)hh[3] << 16);
            pl.x = (unsigned)ll[0] | ((unsigned)ll[1] << 16);
            pl.y = (unsigned)ll[2] | ((unsigned)ll[3] << 16);
            *(uint2*)&CTh[zo + (size_t)c * 256 + r0] = ph;
            *(uint2*)&CTl[zo + (size_t)c * 256 + r0] = pl;
        }
    }
}

// fp32 64x64 micro-kernel
__device__ __forceinline__ void mt16(const float* As, const float* Bs,
                                     int ty4, int tx4, float (&acc)[4][4]) {
#pragma unroll
    for (int kk = 0; kk < 16; ++kk) {
        float4 a4 = *(const float4*)(As + kk * 68 + ty4);
        float4 b4 = *(const float4*)(Bs + kk * 68 + tx4);
        float aa[4] = {a4.x, a4.y, a4.z, a4.w};
        float bb[4] = {b4.x, b4.y, b4.z, b4.w};
#pragma unroll
        for (int u = 0; u < 4; ++u)
#pragma unroll
            for (int w = 0; w < 4; ++w)
                acc[u][w] += aa[u] * bb[w];
    }
}

// ---------------------------------------------------------------------------
// t2 = z6 @ (t1/rs3): A from ZN planes (h+l recombine). grid (1,4,32).
// Emits t2^T planes only (stride 16384/z).
// ---------------------------------------------------------------------------
__global__ __launch_bounds__(256) void t2_gemm(
    const unsigned short* __restrict__ ANh, const unsigned short* __restrict__ ANl,
    const float* __restrict__ t1, const float* __restrict__ rs3,
    unsigned short* __restrict__ t2Th, unsigned short* __restrict__ t2Tl) {
    __shared__ float As[16 * 68];
    __shared__ float Bs[16 * 68];
    const int t  = threadIdx.x;
    const int z  = blockIdx.z;
    const int m0 = blockIdx.y * 64;
    const size_t zo = (size_t)z * 65536;
    const float* Bb = t1 + (size_t)z * 16384;
    const int tx4 = (t & 15) * 4;
    const int ty4 = (t >> 4) * 4;
    const int ar  = t >> 2, ak = (t & 3) * 4;
    const int bkr = t >> 4, bc4 = (t & 15) * 4;
    float acc[4][4] = {};
    for (int kt = 0; kt < 256; kt += 16) {
        uint2 h2 = *(const uint2*)(ANh + zo + (size_t)(m0 + ar) * 256 + kt + ak);
        uint2 l2 = *(const uint2*)(ANl + zo + (size_t)(m0 + ar) * 256 + kt + ak);
        const unsigned short* hp = (const unsigned short*)&h2;
        const unsigned short* lp = (const unsigned short*)&l2;
        float4 av = make_float4(b2f(hp[0]) + b2f(lp[0]), b2f(hp[1]) + b2f(lp[1]),
                                b2f(hp[2]) + b2f(lp[2]), b2f(hp[3]) + b2f(lp[3]));
        float4 bv = *(const float4*)(Bb + (size_t)(kt + bkr) * 64 + bc4);
        float rr = 1.0f / rs3[z * 256 + kt + bkr];
        bv.x *= rr; bv.y *= rr; bv.z *= rr; bv.w *= rr;
        As[(ak + 0) * 68 + ar] = av.x;
        As[(ak + 1) * 68 + ar] = av.y;
        As[(ak + 2) * 68 + ar] = av.z;
        As[(ak + 3) * 68 + ar] = av.w;
        *(float4*)(Bs + bkr * 68 + bc4) = bv;
        __syncthreads();
        mt16(As, Bs, ty4, tx4, acc);
        __syncthreads();
    }
#pragma unroll
    for (int w = 0; w < 4; ++w) {
        unsigned short hh[4], ll[4];
#pragma unroll
        for (int u = 0; u < 4; ++u) split2(acc[u][w], hh[u], ll[u]);
        uint2 ph, pl;
        ph.x = (unsigned)hh[0] | ((unsigned)hh[1] << 16);
        ph.y = (unsigned)hh[2] | ((unsigned)hh[3] << 16);
        pl.x = (unsigned)ll[0] | ((unsigned)ll[1] << 16);
        pl.y = (unsigned)ll[2] | ((unsigned)ll[3] << 16);
        size_t off = (size_t)z * 16384 + (size_t)(tx4 + w) * 256 + m0 + ty4;
        *(uint2*)&t2Th[off] = ph;
        *(uint2*)&t2Tl[off] = pl;
    }
}

// ---------------------------------------------------------------------------
// qkv MFMA GEMM: X planes [16384,512] @ w_qkv planes; emits q/k planes
// ([bh][n][d], q scaled 0.125) and vT planes [bh][dh][4096]. grid (12,128).
// 2-phase double-buffered global_load_lds staging.
// ---------------------------------------------------------------------------
__global__ __launch_bounds__(256) void mfma_qkv(
    const unsigned short* __restrict__ Xh_, const unsigned short* __restrict__ Xl_,
    const unsigned short* __restrict__ WTh, const unsigned short* __restrict__ WTl,
    unsigned short* __restrict__ qh, unsigned short* __restrict__ ql,
    unsigned short* __restrict__ kh, unsigned short* __restrict__ kl,
    unsigned short* __restrict__ vTh, unsigned short* __restrict__ vTl) {
    __shared__ __align__(16) unsigned short Ah[2][4096], Al[2][4096];
    __shared__ __align__(16) unsigned short Bh[2][4096], Bl[2][4096];
    const int t = threadIdx.x;
    const int wave = t >> 6, lane = t & 63, lm = lane & 15, lq = lane >> 4;
    // XCD-aware bijective swizzle: nwg=1536, 1536/8=192 per XCD
    int orig = blockIdx.y * 12 + blockIdx.x;
    int wg = (orig & 7) * 192 + (orig >> 3);
    const int m0 = (wg / 12) * 128, n0 = (wg % 12) * 128;
    const int mb = (wave >> 1) * 64, nb = (wave & 1) * 64;

    // staging role
    const unsigned short* gsrc;
    unsigned short (*ldst)[4096];
    if (wave == 0)      { gsrc = Xh_ + (size_t)m0 * 512; ldst = Ah; }
    else if (wave == 1) { gsrc = Xl_ + (size_t)m0 * 512; ldst = Al; }
    else if (wave == 2) { gsrc = WTh + (size_t)n0 * 512; ldst = Bh; }
    else                { gsrc = WTl + (size_t)n0 * 512; ldst = Bl; }
    const int srow = lane >> 2, sko = (lane & 3) * 8;

    auto stage = [&](int b, int kt) {
#pragma unroll
        for (int c = 0; c < 8; ++c)
            g2l16(gsrc + (size_t)(c * 16 + srow) * 512 + kt + sko,
                  &ldst[b][c * 512]);
    };

    f32x4 acc[4][4];
#pragma unroll
    for (int i = 0; i < 4; ++i)
#pragma unroll
        for (int j = 0; j < 4; ++j) acc[i][j] = (f32x4){0.f, 0.f, 0.f, 0.f};

    stage(0, 0);
    __syncthreads();
    int cur = 0;
    for (int kt = 0; kt < 512; kt += 32) {
        if (kt + 32 < 512) stage(cur ^ 1, kt + 32);
        bf16x8 ah[4], al[4], bh[4], bl[4];
#pragma unroll
        for (int i = 0; i < 4; ++i) {
            ah[i] = *(const bf16x8*)&Ah[cur][(mb + i * 16 + lm) * 32 + lq * 8];
            al[i] = *(const bf16x8*)&Al[cur][(mb + i * 16 + lm) * 32 + lq * 8];
        }
#pragma unroll
        for (int j = 0; j < 4; ++j) {
            bh[j] = *(const bf16x8*)&Bh[cur][(nb + j * 16 + lm) * 32 + lq * 8];
            bl[j] = *(const bf16x8*)&Bl[cur][(nb + j * 16 + lm) * 32 + lq * 8];
        }
#pragma unroll
        for (int i = 0; i < 4; ++i)
#pragma unroll
            for (int j = 0; j < 4; ++j)
                acc[i][j] = mfma3(ah[i], al[i], bh[j], bl[j], acc[i][j]);
        __syncthreads();
        cur ^= 1;
    }
#pragma unroll
    for (int i = 0; i < 4; ++i)
#pragma unroll
        for (int j = 0; j < 4; ++j) {
            int r0 = m0 + mb + i * 16 + lq * 4;
            int c  = n0 + nb + j * 16 + lm;
            int which = c >> 9, h = (c >> 6) & 7, d = c & 63;
            int b = r0 >> 12, nbase = r0 & 4095;
            if (which == 2) {
                unsigned short hh[4], ll[4];
#pragma unroll
                for (int e = 0; e < 4; ++e) split2(acc[i][j][e], hh[e], ll[e]);
                uint2 ph, pl;
                ph.x = (unsigned)hh[0] | ((unsigned)hh[1] << 16);
                ph.y = (unsigned)hh[2] | ((unsigned)hh[3] << 16);
                pl.x = (unsigned)ll[0] | ((unsigned)ll[1] << 16);
                pl.y = (unsigned)ll[2] | ((unsigned)ll[3] << 16);
                size_t off = ((size_t)(b * 8 + h) * 64 + d) * 4096 + nbase;
                *(uint2*)&vTh[off] = ph;
                *(uint2*)&vTl[off] = pl;
            } else {
                unsigned short* Ph = which ? kh : qh;
                unsigned short* Pl = which ? kl : ql;
                float sc = which ? 1.0f : 0.125f;
#pragma unroll
                for (int e = 0; e < 4; ++e) {
                    unsigned short hh, ll;
                    split2(acc[i][j][e] * sc, hh, ll);
                    size_t off = (size_t)(b * 8 + h) * 262144 +
                                 (size_t)(nbase + e) * 64 + d;
                    Ph[off] = hh;
                    Pl[off] = ll;
                }
            }
        }
}

// ---------------------------------------------------------------------------
// final MFMA GEMM: out[16384,512] = OH planes (gathered) @ w_out planes.
// grid (4,128). 2-phase double-buffered global_load_lds (A via gather).
// ---------------------------------------------------------------------------
__global__ __launch_bounds__(256) void mfma_final(
    const unsigned short* __restrict__ OHh, const unsigned short* __restrict__ OHl,
    const unsigned short* __restrict__ WTh, const unsigned short* __restrict__ WTl,
    float* __restrict__ out) {
    __shared__ __align__(16) unsigned short Ah[2][4096], Al[2][4096];
    __shared__ __align__(16) unsigned short Bh[2][4096], Bl[2][4096];
    const int t = threadIdx.x;
    const int wave = t >> 6, lane = t & 63, lm = lane & 15, lq = lane >> 4;
    // XCD-aware bijective swizzle: nwg=512, 512/8=64 per XCD
    int orig = blockIdx.y * 4 + blockIdx.x;
    int wg = (orig & 7) * 64 + (orig >> 3);
    const int m0 = (wg >> 2) * 128, n0 = (wg & 3) * 128;
    const int mb = (wave >> 1) * 64, nb = (wave & 1) * 64;

    const bool isA = wave < 2;
    const unsigned short* gA = (wave == 0) ? OHh : OHl;
    const unsigned short* gB = (wave == 2) ? WTh : WTl;
    unsigned short (*ldst)[4096] = (wave == 0) ? Ah : (wave == 1) ? Al
                                 : (wave == 2) ? Bh : Bl;
    const int srow = lane >> 2, sko = (lane & 3) * 8;
    // A-gather constants per chunk
    int gb[8], gn[8];
#pragma unroll
    for (int c = 0; c < 8; ++c) {
        int gr = m0 + c * 16 + srow;
        gb[c] = gr >> 12;
        gn[c] = gr & 4095;
    }

    auto stage = [&](int b, int kt) {
        if (isA) {
            int kk = kt + sko;
            size_t koff = (size_t)(kk >> 6) * 262144 + (kk & 63);
#pragma unroll
            for (int c = 0; c < 8; ++c)
                g2l16(gA + (size_t)gb[c] * 2097152 + koff +
                          (size_t)gn[c] * 64,
                      &ldst[b][c * 512]);
        } else {
#pragma unroll
            for (int c = 0; c < 8; ++c)
                g2l16(gB + (size_t)(n0 + c * 16 + srow) * 512 + kt + sko,
                      &ldst[b][c * 512]);
        }
    };

    f32x4 acc[4][4];
#pragma unroll
    for (int i = 0; i < 4; ++i)
#pragma unroll
        for (int j = 0; j < 4; ++j) acc[i][j] = (f32x4){0.f, 0.f, 0.f, 0.f};

    stage(0, 0);
    __syncthreads();
    int cur = 0;
    for (int kt = 0; kt < 512; kt += 32) {
        if (kt + 32 < 512) stage(cur ^ 1, kt + 32);
        bf16x8 ah[4], al[4], bh[4], bl[4];
#pragma unroll
        for (int i = 0; i < 4; ++i) {
            ah[i] = *(const bf16x8*)&Ah[cur][(mb + i * 16 + lm) * 32 + lq * 8];
            al[i] = *(const bf16x8*)&Al[cur][(mb + i * 16 + lm) * 32 + lq * 8];
        }
#pragma unroll
        for (int j = 0; j < 4; ++j) {
            bh[j] = *(const bf16x8*)&Bh[cur][(nb + j * 16 + lm) * 32 + lq * 8];
            bl[j] = *(const bf16x8*)&Bl[cur][(nb + j * 16 + lm) * 32 + lq * 8];
        }
#pragma unroll
        for (int i = 0; i < 4; ++i)
#pragma unroll
            for (int j = 0; j < 4; ++j)
                acc[i][j] = mfma3(ah[i], al[i], bh[j], bl[j], acc[i][j]);
        __syncthreads();
        cur ^= 1;
    }
#pragma unroll
    for (int i = 0; i < 4; ++i)
#pragma unroll
        for (int j = 0; j < 4; ++j) {
            int r0 = m0 + mb + i * 16 + lq * 4;
            int c  = n0 + nb + j * 16 + lm;
#pragma unroll
            for (int e = 0; e < 4; ++e)
                out[(size_t)(r0 + e) * 512 + c] = acc[i][j][e];
        }
}

// ---------------------------------------------------------------------------
// F3 MFMA: t1 += exp(qland@k^T)@v, rs3 += rowsums. grid (8, 4, 32).
// ---------------------------------------------------------------------------
__global__ __launch_bounds__(256) void attn3v_mfma(
    const unsigned short* __restrict__ qlh, const unsigned short* __restrict__ qll,
    const unsigned short* __restrict__ kh_, const unsigned short* __restrict__ kl_,
    const unsigned short* __restrict__ vTh, const unsigned short* __restrict__ vTl,
    float* __restrict__ t1, float* __restrict__ rs3) {
    __shared__ unsigned short Qh[4608], Ql[4608];
    __shared__ unsigned short Kh[4608], Kl[4608];
    __shared__ unsigned short Eh[4608], El[4608];
    const int t = threadIdx.x;
    const int wave = t >> 6, lane = t & 63, lm = lane & 15, lq = lane >> 4;
    const int bz = blockIdx.z, m0 = blockIdx.y * 64, c0 = blockIdx.x * 8;
    const unsigned short* qhb = qlh + (size_t)bz * 16384;
    const unsigned short* qlb = qll + (size_t)bz * 16384;
    const unsigned short* khb = kh_ + (size_t)bz * 262144;
    const unsigned short* klb = kl_ + (size_t)bz * 262144;
    const unsigned short* vhb = vTh + (size_t)bz * 262144;
    const unsigned short* vlb = vTl + (size_t)bz * 262144;
#pragma unroll
    for (int r = 0; r < 2; ++r) {
        int id = t + r * 256, row = id >> 3, ko = (id & 7) * 8;
        *(uint4*)&Qh[row * 72 + ko] =
            *(const uint4*)(qhb + (size_t)(m0 + row) * 64 + ko);
        *(uint4*)&Ql[row * 72 + ko] =
            *(const uint4*)(qlb + (size_t)(m0 + row) * 64 + ko);
    }
    f32x4 acc[4];
#pragma unroll
    for (int j = 0; j < 4; ++j) acc[j] = (f32x4){0.f, 0.f, 0.f, 0.f};
    float rsum[4] = {0.f, 0.f, 0.f, 0.f};
    __syncthreads();

    for (int c = c0; c < c0 + 8; ++c) {
        const int tok0 = c * 64;
#pragma unroll
        for (int r = 0; r < 2; ++r) {
            int id = t + r * 256, row = id >> 3, ko = (id & 7) * 8;
            *(uint4*)&Kh[row * 72 + ko] =
                *(const uint4*)(khb + (size_t)(tok0 + row) * 64 + ko);
            *(uint4*)&Kl[row * 72 + ko] =
                *(const uint4*)(klb + (size_t)(tok0 + row) * 64 + ko);
        }
        __syncthreads();
        bf16x8 a0  = *(const bf16x8*)&Qh[(wave * 16 + lm) * 72 + lq * 8];
        bf16x8 a0l = *(const bf16x8*)&Ql[(wave * 16 + lm) * 72 + lq * 8];
        bf16x8 a1  = *(const bf16x8*)&Qh[(wave * 16 + lm) * 72 + 32 + lq * 8];
        bf16x8 a1l = *(const bf16x8*)&Ql[(wave * 16 + lm) * 72 + 32 + lq * 8];
        f32x4 s[4];
#pragma unroll
        for (int j = 0; j < 4; ++j) s[j] = (f32x4){0.f, 0.f, 0.f, 0.f};
#pragma unroll
        for (int j = 0; j < 4; ++j) {
            bf16x8 b0  = *(const bf16x8*)&Kh[(j * 16 + lm) * 72 + lq * 8];
            bf16x8 b0l = *(const bf16x8*)&Kl[(j * 16 + lm) * 72 + lq * 8];
            bf16x8 b1  = *(const bf16x8*)&Kh[(j * 16 + lm) * 72 + 32 + lq * 8];
            bf16x8 b1l = *(const bf16x8*)&Kl[(j * 16 + lm) * 72 + 32 + lq * 8];
            s[j] = mfma3(a0, a0l, b0, b0l, s[j]);
            s[j] = mfma3(a1, a1l, b1, b1l, s[j]);
        }
        __syncthreads();
#pragma unroll
        for (int j = 0; j < 4; ++j)
#pragma unroll
            for (int e = 0; e < 4; ++e) {
                float ev = __expf(s[j][e]);
                rsum[e] += ev;
                unsigned short h, l;
                split2(ev, h, l);
                int off = (wave * 16 + lq * 4 + e) * 72 + j * 16 + lm;
                Eh[off] = h;
                El[off] = l;
            }
#pragma unroll
        for (int r = 0; r < 2; ++r) {
            int id = t + r * 256, dh = id >> 3, t8 = (id & 7) * 8;
            *(uint4*)&Kh[dh * 72 + t8] =
                *(const uint4*)(vhb + (size_t)dh * 4096 + tok0 + t8);
            *(uint4*)&Kl[dh * 72 + t8] =
                *(const uint4*)(vlb + (size_t)dh * 4096 + tok0 + t8);
        }
        __syncthreads();
        bf16x8 e0  = *(const bf16x8*)&Eh[(wave * 16 + lm) * 72 + lq * 8];
        bf16x8 e0l = *(const bf16x8*)&El[(wave * 16 + lm) * 72 + lq * 8];
        bf16x8 e1  = *(const bf16x8*)&Eh[(wave * 16 + lm) * 72 + 32 + lq * 8];
        bf16x8 e1l = *(const bf16x8*)&El[(wave * 16 + lm) * 72 + 32 + lq * 8];
#pragma unroll
        for (int j = 0; j < 4; ++j) {
            bf16x8 v0  = *(const bf16x8*)&Kh[(j * 16 + lm) * 72 + lq * 8];
            bf16x8 v0l = *(const bf16x8*)&Kl[(j * 16 + lm) * 72 + lq * 8];
            bf16x8 v1  = *(const bf16x8*)&Kh[(j * 16 + lm) * 72 + 32 + lq * 8];
            bf16x8 v1l = *(const bf16x8*)&Kl[(j * 16 + lm) * 72 + 32 + lq * 8];
            acc[j] = mfma3(e0, e0l, v0, v0l, acc[j]);
            acc[j] = mfma3(e1, e1l, v1, v1l, acc[j]);
        }
        __syncthreads();
    }
    float* t1b = t1 + (size_t)bz * 16384;
#pragma unroll
    for (int j = 0; j < 4; ++j)
#pragma unroll
        for (int e = 0; e < 4; ++e)
            atomicAdd(t1b + (size_t)(m0 + wave * 16 + lq * 4 + e) * 64 +
                          j * 16 + lm,
                      acc[j][e]);
#pragma unroll
    for (int e = 0; e < 4; ++e) {
        float vs = rsum[e];
        for (int mm = 1; mm < 16; mm <<= 1) vs += __shfl_xor(vs, mm);
        if (lm == 0)
            atomicAdd(rs3 + bz * 256 + m0 + wave * 16 + lq * 4 + e, vs);
    }
}

// ---------------------------------------------------------------------------
// F1 MFMA + fused depthwise conv: OH planes = softmax(q@kland^T)@t2 + conv(v).
// After the PV loop the Q/K LDS region is dead -> re-used as the fp32 v
// window Vs[96][65]. grid (64, 32).
// ---------------------------------------------------------------------------
__global__ __launch_bounds__(256) void attn1t2_conv(
    const unsigned short* __restrict__ qh_, const unsigned short* __restrict__ ql_,
    const unsigned short* __restrict__ klh, const unsigned short* __restrict__ kll,
    const unsigned short* __restrict__ t2Th, const unsigned short* __restrict__ t2Tl,
    const unsigned short* __restrict__ vTh, const unsigned short* __restrict__ vTl,
    const float* __restrict__ wres,
    unsigned short* __restrict__ OHh, unsigned short* __restrict__ OHl) {
    __shared__ __align__(16) unsigned short SH[27648];   // 55296 B
    unsigned short* Qh = SH;
    unsigned short* Ql = SH + 4608;
    unsigned short* Kh = SH + 9216;
    unsigned short* Kl = SH + 13824;
    unsigned short* Eh = SH + 18432;
    unsigned short* El = SH + 23040;
    __shared__ float Ws[33];
    const int t = threadIdx.x;
    const int wave = t >> 6, lane = t & 63, lm = lane & 15, lq = lane >> 4;
    const int bz = blockIdx.y, m0 = blockIdx.x * 64;
    if (t < 33) Ws[t] = wres[(bz & 7) * 33 + t];
    const unsigned short* qhb = qh_ + (size_t)bz * 262144;
    const unsigned short* qlb = ql_ + (size_t)bz * 262144;
    const unsigned short* khb = klh + (size_t)bz * 16384;
    const unsigned short* klb = kll + (size_t)bz * 16384;
    const unsigned short* t2h = t2Th + (size_t)bz * 16384;
    const unsigned short* t2l = t2Tl + (size_t)bz * 16384;
#pragma unroll
    for (int r = 0; r < 2; ++r) {
        int id = t + r * 256, row = id >> 3, ko = (id & 7) * 8;
        *(uint4*)&Qh[row * 72 + ko] =
            *(const uint4*)(qhb + (size_t)(m0 + row) * 64 + ko);
        *(uint4*)&Ql[row * 72 + ko] =
            *(const uint4*)(qlb + (size_t)(m0 + row) * 64 + ko);
    }
    f32x4 acc[4];
#pragma unroll
    for (int j = 0; j < 4; ++j) acc[j] = (f32x4){0.f, 0.f, 0.f, 0.f};
    float rsum[4] = {0.f, 0.f, 0.f, 0.f};
    __syncthreads();

    for (int lc = 0; lc < 4; ++lc) {
        const int l0 = lc * 64;
#pragma unroll
        for (int r = 0; r < 2; ++r) {
            int id = t + r * 256, row = id >> 3, ko = (id & 7) * 8;
            *(uint4*)&Kh[row * 72 + ko] =
                *(const uint4*)(khb + (size_t)(l0 + row) * 64 + ko);
            *(uint4*)&Kl[row * 72 + ko] =
                *(const uint4*)(klb + (size_t)(l0 + row) * 64 + ko);
        }
        __syncthreads();
        bf16x8 a0  = *(const bf16x8*)&Qh[(wave * 16 + lm) * 72 + lq * 8];
        bf16x8 a0l = *(const bf16x8*)&Ql[(wave * 16 + lm) * 72 + lq * 8];
        bf16x8 a1  = *(const bf16x8*)&Qh[(wave * 16 + lm) * 72 + 32 + lq * 8];
        bf16x8 a1l = *(const bf16x8*)&Ql[(wave * 16 + lm) * 72 + 32 + lq * 8];
        f32x4 s[4];
#pragma unroll
        for (int j = 0; j < 4; ++j) s[j] = (f32x4){0.f, 0.f, 0.f, 0.f};
#pragma unroll
        for (int j = 0; j < 4; ++j) {
            bf16x8 b0  = *(const bf16x8*)&Kh[(j * 16 + lm) * 72 + lq * 8];
            bf16x8 b0l = *(const bf16x8*)&Kl[(j * 16 + lm) * 72 + lq * 8];
            bf16x8 b1  = *(const bf16x8*)&Kh[(j * 16 + lm) * 72 + 32 + lq * 8];
            bf16x8 b1l = *(const bf16x8*)&Kl[(j * 16 + lm) * 72 + 32 + lq * 8];
            s[j] = mfma3(a0, a0l, b0, b0l, s[j]);
            s[j] = mfma3(a1, a1l, b1, b1l, s[j]);
        }
        __syncthreads();
#pragma unroll
        for (int j = 0; j < 4; ++j)
#pragma unroll
            for (int e = 0; e < 4; ++e) {
                float ev = __expf(s[j][e]);
                rsum[e] += ev;
                unsigned short h, l;
                split2(ev, h, l);
                int off = (wave * 16 + lq * 4 + e) * 72 + j * 16 + lm;
                Eh[off] = h;
                El[off] = l;
            }
#pragma unroll
        for (int r = 0; r < 2; ++r) {
            int id = t + r * 256, dh = id >> 3, t8 = (id & 7) * 8;
            *(uint4*)&Kh[dh * 72 + t8] =
                *(const uint4*)(t2h + (size_t)dh * 256 + l0 + t8);
            *(uint4*)&Kl[dh * 72 + t8] =
                *(const uint4*)(t2l + (size_t)dh * 256 + l0 + t8);
        }
        __syncthreads();
        bf16x8 e0  = *(const bf16x8*)&Eh[(wave * 16 + lm) * 72 + lq * 8];
        bf16x8 e0l = *(const bf16x8*)&El[(wave * 16 + lm) * 72 + lq * 8];
        bf16x8 e1  = *(const bf16x8*)&Eh[(wave * 16 + lm) * 72 + 32 + lq * 8];
        bf16x8 e1l = *(const bf16x8*)&El[(wave * 16 + lm) * 72 + 32 + lq * 8];
#pragma unroll
        for (int j = 0; j < 4; ++j) {
            bf16x8 v0  = *(const bf16x8*)&Kh[(j * 16 + lm) * 72 + lq * 8];
            bf16x8 v0l = *(const bf16x8*)&Kl[(j * 16 + lm) * 72 + lq * 8];
            bf16x8 v1  = *(const bf16x8*)&Kh[(j * 16 + lm) * 72 + 32 + lq * 8];
            bf16x8 v1l = *(const bf16x8*)&Kl[(j * 16 + lm) * 72 + 32 + lq * 8];
            acc[j] = mfma3(e0, e0l, v0, v0l, acc[j]);
            acc[j] = mfma3(e1, e1l, v1, v1l, acc[j]);
        }
        __syncthreads();
    }
    float rinv[4];
#pragma unroll
    for (int e = 0; e < 4; ++e) {
        float vs = rsum[e];
        for (int mm = 1; mm < 16; mm <<= 1) vs += __shfl_xor(vs, mm);
        rinv[e] = 1.0f / vs;
    }

    // ---- fused conv: stage v window [m0-16, m0+80) into dead Q/K LDS ----
    __syncthreads();
    float* Vs = (float*)SH;                      // 96 x 65 fp32 = 24960 B
    const unsigned short* vhb = vTh + (size_t)bz * 262144;
    const unsigned short* vlb = vTl + (size_t)bz * 262144;
#pragma unroll
    for (int r = 0; r < 3; ++r) {
        int id = t + r * 256;                    // 0..767 = 64 dh x 12 chunks
        int d = id / 12, ch = id - d * 12;
        int n = m0 - 16 + ch * 8;
        uint4 h4 = make_uint4(0u, 0u, 0u, 0u);
        uint4 l4 = make_uint4(0u, 0u, 0u, 0u);
        if ((unsigned)n < 4096u) {
            h4 = *(const uint4*)(vhb + (size_t)d * 4096 + n);
            l4 = *(const uint4*)(vlb + (size_t)d * 4096 + n);
        }
        const unsigned short* hp = (const unsigned short*)&h4;
        const unsigned short* lp = (const unsigned short*)&l4;
#pragma unroll
        for (int i = 0; i < 8; ++i)
            Vs[(ch * 8 + i) * 65 + d] = b2f(hp[i]) + b2f(lp[i]);
    }
    __syncthreads();
    unsigned short* Hh = OHh + (size_t)bz * 262144;
    unsigned short* Hl = OHl + (size_t)bz * 262144;
    const int rbase = wave * 16 + lq * 4;
#pragma unroll
    for (int j = 0; j < 4; ++j) {
        int cc = j * 16 + lm;
        float w[36];
#pragma unroll
        for (int u = 0; u < 36; ++u) w[u] = Vs[(rbase + u) * 65 + cc];
#pragma unroll
        for (int e = 0; e < 4; ++e) {
            float cv = 0.f;
#pragma unroll
            for (int tt = 0; tt < 33; ++tt) cv += w[e + tt] * Ws[tt];
            float o = acc[j][e] * rinv[e] + cv;
            unsigned short hh, ll;
            split2(o, hh, ll);
            size_t off = (size_t)(m0 + rbase + e) * 64 + cc;
            Hh[off] = hh;
            Hl[off] = ll;
        }
    }
}

// ---------------------------------------------------------------------------
// fp32 gemm for attn2 scores
// ---------------------------------------------------------------------------
__global__ __launch_bounds__(256) void gemm_a2(
    const float* __restrict__ A, const float* __restrict__ B,
    float* __restrict__ C) {
    __shared__ float As[16 * 68];
    __shared__ float Bs[16 * 68];
    const int t  = threadIdx.x;
    const int z  = blockIdx.z;
    const int m0 = blockIdx.y * 64;
    const int n0 = blockIdx.x * 64;
    const float* Ab = A + (size_t)z * 16384;
    const float* Bb = B + (size_t)z * 16384;
    float*       Cb = C + (size_t)z * 65536;
    const int tx4 = (t & 15) * 4;
    const int ty4 = (t >> 4) * 4;
    const int ar  = t >> 2, ak = (t & 3) * 4;
    float acc[4][4] = {};
    for (int kt = 0; kt < 64; kt += 16) {
        float4 av = *(const float4*)(Ab + (size_t)(m0 + ar) * 64 + kt + ak);
        float4 bv = *(const float4*)(Bb + (size_t)(n0 + ar) * 64 + kt + ak);
        As[(ak + 0) * 68 + ar] = av.x;
        As[(ak + 1) * 68 + ar] = av.y;
        As[(ak + 2) * 68 + ar] = av.z;
        As[(ak + 3) * 68 + ar] = av.w;
        Bs[(ak + 0) * 68 + ar] = bv.x;
        Bs[(ak + 1) * 68 + ar] = bv.y;
        Bs[(ak + 2) * 68 + ar] = bv.z;
        Bs[(ak + 3) * 68 + ar] = bv.w;
        __syncthreads();
        mt16(As, Bs, ty4, tx4, acc);
        __syncthreads();
    }
#pragma unroll
    for (int u = 0; u < 4; ++u) {
        int row = m0 + ty4 + u;
        *(float4*)(Cb + (size_t)row * 256 + n0 + tx4) =
            make_float4(acc[u][0], acc[u][1], acc[u][2], acc[u][3]);
    }
}

// ---------------------------------------------------------------------------
// small kernels
// ---------------------------------------------------------------------------
__global__ void zero_f(float* __restrict__ p, int n) {
    int i = blockIdx.x * 256 + threadIdx.x;
    if (i < n) p[i] = 0.f;
}

// both landmark means in one dispatch. grid 4096.
__global__ void landmark_mean2(
    const unsigned short* __restrict__ qh, const unsigned short* __restrict__ ql,
    const unsigned short* __restrict__ kh, const unsigned short* __restrict__ kl,
    float* __restrict__ qland, float* __restrict__ kland,
    unsigned short* __restrict__ qlh, unsigned short* __restrict__ qll,
    unsigned short* __restrict__ klh, unsigned short* __restrict__ kll) {
    int o = blockIdx.x * 256 + threadIdx.x;
    bool isq = o < 524288;
    int oo = isq ? o : o - 524288;
    const unsigned short* sh = isq ? qh : kh;
    const unsigned short* sl = isq ? ql : kl;
    float* dst = isq ? qland : kland;
    unsigned short* dh = isq ? qlh : klh;
    unsigned short* dl = isq ? qll : kll;
    int d = oo & 63, m = (oo >> 6) & 255, bh = oo >> 14;
    size_t base = (size_t)bh * 262144 + (size_t)m * 1024 + d;
    float acc = 0.f;
#pragma unroll
    for (int j = 0; j < 16; ++j)
        acc += b2f(sh[base + j * 64]) + b2f(sl[base + j * 64]);
    float v = acc * (1.0f / 16.0f);
    dst[oo] = v;
    unsigned short h, l;
    split2(v, h, l);
    dh[oo] = h;
    dl[oo] = l;
}

// softmax + emit a2 normal/transposed planes + colsum atomics. grid 8192.
__global__ void softmax_fused(const float* __restrict__ a,
                              unsigned short* __restrict__ A2Ph,
                              unsigned short* __restrict__ A2Pl,
                              unsigned short* __restrict__ A2Th,
                              unsigned short* __restrict__ A2Tl,
                              float* __restrict__ colsum) {
    __shared__ float red[256];
    int row = blockIdx.x, t = threadIdx.x;
    float v = a[(size_t)row * 256 + t];
    red[t] = v;
    __syncthreads();
    for (int s = 128; s > 0; s >>= 1) {
        if (t < s) red[t] = fmaxf(red[t], red[t + s]);
        __syncthreads();
    }
    float mx = red[0];
    __syncthreads();
    float e = __expf(v - mx);
    red[t] = e;
    __syncthreads();
    for (int s = 128; s > 0; s >>= 1) {
        if (t < s) red[t] += red[t + s];
        __syncthreads();
    }
    float val = e / red[0];
    int z = row >> 8, r = row & 255;
    atomicAdd(&colsum[z * 256 + t], val);
    unsigned short h, l;
    split2(val, h, l);
    size_t zo = (size_t)z * 65536;
    A2Ph[zo + (size_t)r * 256 + t] = h;
    A2Pl[zo + (size_t)r * 256 + t] = l;
    A2Th[zo + (size_t)t * 256 + r] = h;
    A2Tl[zo + (size_t)t * 256 + r] = l;
}

// global max over colsum -> scal[0]. grid 32.
__global__ void scal_max(const float* __restrict__ colsum,
                         float* __restrict__ scal) {
    __shared__ float red[256];
    int t = threadIdx.x;
    red[t] = colsum[blockIdx.x * 256 + t];
    __syncthreads();
    for (int s = 128; s > 0; s >>= 1) {
        if (t < s) red[t] = fmaxf(red[t], red[t + s]);
        __syncthreads();
    }
    if (t == 0) atomicMax((unsigned int*)&scal[0], __float_as_uint(red[0]));
}

// ---------------------------------------------------------------------------
extern "C" void kernel_launch(void* const* d_in, const int* in_sizes, int n_in,
                              void* d_out, int out_size, void* d_ws, size_t ws_size,
                              hipStream_t stream) {
    const float* x     = (const float*)d_in[0];
    const float* w_qkv = (const float*)d_in[1];
    const float* w_out = (const float*)d_in[2];
    const float* w_res = (const float*)d_in[3];
    float* out = (float*)d_out;
    float* ws  = (float*)d_ws;

    // planes (ushort units)
    unsigned short* Xh  = (unsigned short*)(ws + O_XP);
    unsigned short* Xl  = Xh + 8388608;
    unsigned short* qh  = (unsigned short*)(ws + O_QP);
    unsigned short* ql  = qh + 8388608;
    unsigned short* kh  = (unsigned short*)(ws + O_KP);
    unsigned short* kl  = kh + 8388608;
    unsigned short* vTh = (unsigned short*)(ws + O_VT);
    unsigned short* vTl = vTh + 8388608;
    unsigned short* qlh = (unsigned short*)(ws + O_QLP);
    unsigned short* qll = qlh + 524288;
    unsigned short* klh = (unsigned short*)(ws + O_KLP);
    unsigned short* kll = klh + 524288;

    float* qland = ws + O_QL;
    float* kland = ws + O_KL;
    float* attn2 = ws + O_A2;
    float* t1    = ws + O_T1;
    float* rs3   = ws + O_RS3;
    float* scal  = ws + O_SCAL;
    float* colsum= ws + O_CS;

    // pinv plane pool A: k-plane region (dead after attn3v)
    unsigned short* PBu  = (unsigned short*)(ws + O_KP);
    unsigned short* A2Ph = PBu + 0;
    unsigned short* A2Pl = PBu + 2097152;
    unsigned short* XZNh = PBu + 4194304;
    unsigned short* XZNl = PBu + 6291456;
    unsigned short* XZTh = PBu + 8388608;
    unsigned short* XZTl = PBu + 10485760;
    unsigned short* Y1Th = PBu + 12582912;
    unsigned short* Y1Tl = PBu + 14680064;
    // pinv plane pool B: X-plane region (dead after qkv)
    unsigned short* XRu  = (unsigned short*)(ws + O_XP);
    unsigned short* ZNah = XRu + 0;            // also hosts A2T (pre-iter2)
    unsigned short* ZNal = XRu + 2097152;
    unsigned short* ZNbh = XRu + 4194304;
    unsigned short* ZNbl = XRu + 6291456;
    unsigned short* ZTh_ = XRu + 8388608;
    unsigned short* ZTl_ = XRu + 10485760;
    unsigned short* Y2Th = XRu + 12582912;
    unsigned short* Y2Tl = XRu + 14680064;
    unsigned short* A2Th = ZNah;               // a2^T planes (z0 * denom)
    unsigned short* A2Tl = ZNal;
    // post-pinv aliases
    unsigned short* t2Th = (unsigned short*)(ws + O_QL);   // qland dead
    unsigned short* t2Tl = t2Th + 524288;
    unsigned short* OHh = PBu;                 // pool A dead after pinv
    unsigned short* OHl = PBu + 8388608;

    unsigned short* WQTh = (unsigned short*)(ws + O_WQT);
    unsigned short* WQTl = WQTh + 786432;
    unsigned short* WOTh = (unsigned short*)(ws + O_WOT);
    unsigned short* WOTl = WOTh + 262144;

    zero_f<<<2113, 256, 0, stream>>>(t1, 540688);   // t1+rs3+scal+colsum
    wtrans2<<<4096, 256, 0, stream>>>(w_qkv, w_out, WQTh, WQTl, WOTh, WOTl);
    xsplit<<<8192, 256, 0, stream>>>(x, Xh, Xl);

    mfma_qkv<<<dim3(12, 128), 256, 0, stream>>>(Xh, Xl, WQTh, WQTl,
                                                qh, ql, kh, kl, vTh, vTl);

    landmark_mean2<<<4096, 256, 0, stream>>>(qh, ql, kh, kl, qland, kland,
                                             qlh, qll, klh, kll);

    // F3 first: consumes k planes (pool A overwritten by softmax_fused next)
    attn3v_mfma<<<dim3(8, 4, 32), 256, 0, stream>>>(qlh, qll, kh, kl,
                                                    vTh, vTl, t1, rs3);

    gemm_a2<<<dim3(4, 4, 32), 256, 0, stream>>>(qland, kland, attn2);
    softmax_fused<<<8192, 256, 0, stream>>>(attn2, A2Ph, A2Pl, A2Th, A2Tl,
                                            colsum);
    scal_max<<<32, 256, 0, stream>>>(colsum, scal);

    // pinv: 6x4 all-plane stages (zinit folded into SC modes)
    unsigned short* ZNh[2] = {ZNah, ZNbh};
    unsigned short* ZNl[2] = {ZNal, ZNbl};
    int cur = 0;
    const dim3 pg(4, 4, 32);
    for (int it = 0; it < 6; ++it) {
        if (it == 0) {
            // xz = (1/denom) * (a2 @ a2^T)
            mfma_gemm_p<0, 1, true, true><<<pg, 256, 0, stream>>>(
                A2Ph, A2Pl, A2Ph, A2Pl, XZNh, XZNl, XZTh, XZTl,
                0.f, 0.f, scal);
        } else {
            mfma_gemm_p<0, 0, true, true><<<pg, 256, 0, stream>>>(
                A2Ph, A2Pl, ZTh_, ZTl_, XZNh, XZNl, XZTh, XZTl,
                1.f, 0.f, scal);
        }
        // Y1 = -xz@xz + 7*xz
        mfma_gemm_p<1, 0, false, true><<<pg, 256, 0, stream>>>(
            XZNh, XZNl, XZTh, XZTl, nullptr, nullptr, Y1Th, Y1Tl,
            -1.f, 7.f, scal);
        // Y2 = -xz@Y1 + 15*xz
        mfma_gemm_p<1, 0, false, true><<<pg, 256, 0, stream>>>(
            XZNh, XZNl, Y1Th, Y1Tl, nullptr, nullptr, Y2Th, Y2Tl,
            -1.f, 15.f, scal);
        // z' = -0.25*z@Y2 + 3.25*z
        if (it == 0) {
            // z = a2^T/denom: A = A2T, whole result scaled by 1/denom (SC=2)
            mfma_gemm_p<1, 2, true, true><<<pg, 256, 0, stream>>>(
                A2Th, A2Tl, Y2Th, Y2Tl, ZNbh, ZNbl, ZTh_, ZTl_,
                -0.25f, 3.25f, scal);
            cur = 1;
        } else {
            mfma_gemm_p<1, 0, true, true><<<pg, 256, 0, stream>>>(
                ZNh[cur], ZNl[cur], Y2Th, Y2Tl, ZNh[1 - cur], ZNl[1 - cur],
                ZTh_, ZTl_, -0.25f, 3.25f, scal);
            cur = 1 - cur;
        }
    }
    // zfin = ZN[0] (it1:->0, it2:->1, it3:->0, it4:->1, it5:->0)

    // t2 = zfin @ (t1 / rs3); t2^T planes into dead qland region
    t2_gemm<<<dim3(1, 4, 32), 256, 0, stream>>>(ZNh[0], ZNl[0], t1, rs3,
                                                t2Th, t2Tl);

    // F1 + conv fused -> OH planes (pool A, fully dead now)
    attn1t2_conv<<<dim3(64, 32), 256, 0, stream>>>(qh, ql, klh, kll,
                                                   t2Th, t2Tl, vTh, vTl,
                                                   w_res, OHh, OHl);

    mfma_final<<<dim3(4, 128), 256, 0, stream>>>(OHh, OHl, WOTh, WOTl, out);

    (void)in_sizes; (void)n_in; (void)out_size; (void)ws_size;
}